// Round 1
// baseline (1185.282 us; speedup 1.0000x reference)
//
#include <hip/hip_runtime.h>
#include <hip/hip_bf16.h>
#include <stdint.h>

typedef short s8b __attribute__((ext_vector_type(8)));
typedef float f4 __attribute__((ext_vector_type(4)));
typedef unsigned short u16t;
typedef unsigned int u32t;

#define AS1 __attribute__((address_space(1)))
#define AS3 __attribute__((address_space(3)))
#define DEVFN static __device__ __forceinline__

DEVFN u16t f2b(float f){ union{ __hip_bfloat16 h; u16t u; } c; c.h = __float2bfloat16(f); return c.u; }

DEVFN float geluf(float x){
  float t = 0.7978845608028654f*(x + 0.044715f*x*x*x);
  t = fminf(fmaxf(t, -15.0f), 15.0f);
  float e = __expf(2.0f*t);
  return 0.5f*x*(1.0f + (e-1.0f)/(e+1.0f));
}
DEVFN float softcapf(float x){
  float t = x*0.02f;
  t = fminf(fmaxf(t, -15.0f), 15.0f);
  float e = __expf(2.0f*t);
  return 50.0f*(e-1.0f)/(e+1.0f);
}

// ---------------- weight packing (fp32 -> bf16, transposed to [N][K]) ----------------
__global__ void pack_qkv_k(u16t* dst, const float* qw, const float* kvw){
  int i = blockIdx.x*256 + threadIdx.x;
  if(i >= 1280*1024) return;
  int row = i >> 10, d = i & 1023;
  float v;
  if(row < 1024){ int n = row >> 7, h = row & 127; v = qw[(n*1024 + d)*128 + h]; }
  else if(row < 1152){ v = kvw[d*128 + (row-1024)]; }
  else { v = kvw[131072 + d*128 + (row-1152)]; }
  dst[i] = f2b(v);
}
__global__ void pack_ot_k(u16t* dst, const float* ow){
  int i = blockIdx.x*256 + threadIdx.x;
  if(i >= 1024*1024) return;
  int dd = i >> 10, nh = i & 1023;
  dst[i] = f2b(ow[nh*1024 + dd]);
}
// gate rows interleaved: row r -> gate[r&1][:, r>>1]
__global__ void pack_gate_k(u16t* dst, const float* gate, int F, int total){
  int i = blockIdx.x*256 + threadIdx.x;
  if(i >= total) return;
  int r = i >> 10, dd = i & 1023;
  dst[i] = f2b(gate[(r&1)*(1024*F) + dd*F + (r>>1)]);
}
__global__ void pack_lin_k(u16t* dst, const float* lin, int lf, int total){
  int i = blockIdx.x*256 + threadIdx.x;
  if(i >= total) return;
  int dd = i >> lf, f = i & ((1<<lf)-1);
  dst[i] = f2b(lin[f*1024 + dd]);
}

// ---------------- RMSNorm (one block per row of 1024) ----------------
__global__ __launch_bounds__(256) void rmsnorm_k(const float* __restrict__ x, const float* __restrict__ sc,
                                                 u16t* __restrict__ out){
  int row = blockIdx.x;
  int tid = threadIdx.x;
  const float* xr = x + (size_t)row*1024;
  float4 v = *(const float4*)(xr + tid*4);
  float s = v.x*v.x + v.y*v.y + v.z*v.z + v.w*v.w;
  #pragma unroll
  for(int off=32; off>=1; off>>=1) s += __shfl_down(s, off);
  __shared__ float ws4[4];
  if((tid & 63) == 0) ws4[tid>>6] = s;
  __syncthreads();
  float tot = ws4[0]+ws4[1]+ws4[2]+ws4[3];
  float r = rsqrtf(tot*(1.0f/1024.0f) + 1e-6f);
  float4 scv = *(const float4*)(sc + tid*4);
  u16t o0 = f2b(v.x*r*(1.0f+scv.x)), o1 = f2b(v.y*r*(1.0f+scv.y));
  u16t o2 = f2b(v.z*r*(1.0f+scv.z)), o3 = f2b(v.w*r*(1.0f+scv.w));
  uint2 pk; pk.x = (u32t)o0 | ((u32t)o1<<16); pk.y = (u32t)o2 | ((u32t)o3<<16);
  *(uint2*)(out + (size_t)row*1024 + tid*4) = pk;
}

// ---------------- RoPE + convert; K/V stored pre-swizzled for LDS ----------------
__global__ __launch_bounds__(256) void rope_k(const float* __restrict__ qkv, u16t* __restrict__ qb,
                                              u16t* __restrict__ kswz, u16t* __restrict__ vswz){
  int row = blockIdx.x;
  int b = row >> 11, t = row & 2047;
  float pos = (float)(t + (t >= 1792 ? 1 : 0));
  const float* src = qkv + (size_t)row*1280;
  size_t kvbase = ((size_t)b*2048 + t)*128;
  int swz = ((t&7)<<3) ^ (((t>>3)&3)<<4);
  for(int idx = threadIdx.x; idx < 704; idx += 256){
    if(idx < 512){
      int n = idx >> 6, i = idx & 63;
      float inv = powf(10000.0f, -(float)i*(1.0f/64.0f));
      float sn, cs; sincosf(pos*inv, &sn, &cs);
      float x1 = src[n*128+i], x2 = src[n*128+i+64];
      const float qs = 0.08838834764831845f; // 1/sqrt(128)
      qb[(size_t)row*1024 + n*128 + i]      = f2b((x1*cs - x2*sn)*qs);
      qb[(size_t)row*1024 + n*128 + i + 64] = f2b((x2*cs + x1*sn)*qs);
    } else if(idx < 576){
      int i = idx - 512;
      float inv = powf(10000.0f, -(float)i*(1.0f/64.0f));
      float sn, cs; sincosf(pos*inv, &sn, &cs);
      float x1 = src[1024+i], x2 = src[1024+i+64];
      kswz[kvbase + (i ^ swz)]        = f2b(x1*cs - x2*sn);
      kswz[kvbase + ((i+64) ^ swz)]   = f2b(x2*cs + x1*sn);
    } else {
      int h = idx - 576;
      vswz[kvbase + (h ^ swz)] = f2b(src[1152+h]);
    }
  }
}

// ---------------- generic bf16 MFMA GEMM, 128x128 tile, BK=32, 4 waves ----------------
struct GemmArgs {
  const u16t* A; int lda;
  const u16t* Bg; const u16t* Ba;
  int K; int ntN; int mode; int amap; int omap; int ep;
  float* outf; u16t* outb; int ldo;
  const float* res;
};

__global__ __launch_bounds__(256) void gemm_k(GemmArgs g){
  __shared__ __align__(16) u16t As[128*32];
  __shared__ __align__(16) u16t Bs[128*32];
  int bid = blockIdx.x;
  int mt = bid / g.ntN, nt = bid % g.ntN;
  int c0 = mt*128, g0;
  const u16t* B;
  if(g.mode == 0){
    g0 = c0;
    B = ((mt & 15) < 14) ? g.Bg : g.Ba;   // t<1792 -> g weights
  } else if(g.mode == 1){                  // g-half compact rows: 14 tiles per batch
    int bb = mt/14, t = (mt - bb*14)*128;
    g0 = bb*2048 + t; B = g.Bg;
  } else {                                 // a-half compact rows: 2 tiles per batch
    int bb = mt>>1, t = 1792 + (mt&1)*128;
    g0 = bb*2048 + t; B = g.Bg;
  }
  int arow = g.amap ? g0 : c0;
  int orow = g.omap ? g0 : c0;
  int tid = threadIdx.x, lane = tid & 63, w = tid >> 6, l15 = lane & 15, lg = lane >> 4;
  int wr = w >> 1, wc = w & 1;

  const u16t* Ap = g.A + (size_t)(arow + (tid>>2))*g.lda + (tid&3)*8;
  const u16t* Bp = B   + (size_t)(nt*128 + (tid>>2))*g.K + (tid&3)*8;
  size_t lda64 = (size_t)64*g.lda, ldb64 = (size_t)64*g.K;
  u32t le = tid*8;

  f4 acc[4][4];
  #pragma unroll
  for(int mi=0;mi<4;mi++)
    #pragma unroll
    for(int ni=0;ni<4;ni++){ f4 z = {0.0f,0.0f,0.0f,0.0f}; acc[mi][ni]=z; }

  for(int k0=0; k0 < g.K; k0 += 32){
    __syncthreads();
    __builtin_amdgcn_global_load_lds((const AS1 u32t*)(Ap + k0),          (AS3 u32t*)&As[le],        16,0,0);
    __builtin_amdgcn_global_load_lds((const AS1 u32t*)(Ap + k0 + lda64),  (AS3 u32t*)&As[le + 2048], 16,0,0);
    __builtin_amdgcn_global_load_lds((const AS1 u32t*)(Bp + k0),          (AS3 u32t*)&Bs[le],        16,0,0);
    __builtin_amdgcn_global_load_lds((const AS1 u32t*)(Bp + k0 + ldb64),  (AS3 u32t*)&Bs[le + 2048], 16,0,0);
    __syncthreads();
    s8b af[4], bf[4];
    #pragma unroll
    for(int mi=0;mi<4;mi++) af[mi] = *(const s8b*)&As[(wr*64 + mi*16 + l15)*32 + lg*8];
    #pragma unroll
    for(int ni=0;ni<4;ni++) bf[ni] = *(const s8b*)&Bs[(wc*64 + ni*16 + l15)*32 + lg*8];
    #pragma unroll
    for(int mi=0;mi<4;mi++)
      #pragma unroll
      for(int ni=0;ni<4;ni++)
        acc[mi][ni] = __builtin_amdgcn_mfma_f32_16x16x32_bf16(af[mi], bf[ni], acc[mi][ni], 0,0,0);
  }

  #pragma unroll
  for(int mi=0;mi<4;mi++){
    #pragma unroll
    for(int ni=0;ni<4;ni++){
      int rowb = wr*64 + mi*16 + lg*4;
      int col = nt*128 + wc*64 + ni*16 + l15;
      #pragma unroll
      for(int r=0;r<4;r++){
        float v = acc[mi][ni][r];
        size_t ro = (size_t)(orow + rowb + r);
        if(g.ep == 0){
          g.outf[ro*(size_t)g.ldo + col] = v;
        } else if(g.ep == 1){
          g.outf[ro*(size_t)g.ldo + col] = v + g.res[ro*1024 + col];
        } else { // gelu-pair: even col = g1, odd col = g2
          float other = __shfl_xor(v, 1);
          if((lane & 1) == 0){
            g.outb[ro*(size_t)g.ldo + (col>>1)] = f2b(geluf(v)*other);
          }
        }
      }
    }
  }
}

// ---------------- flash attention: block = (b, head, 64 q rows), S-tiles of 64 ----------------
__global__ __launch_bounds__(256) void attn_k(const u16t* __restrict__ qb, const u16t* __restrict__ kswz,
                                              const u16t* __restrict__ vswz, u16t* __restrict__ attnb){
  __shared__ __align__(16) u16t Ks[64*128];
  __shared__ __align__(16) u16t Vs[64*128];
  __shared__ __align__(16) u16t Ps[4*16*72];
  int bid = blockIdx.x;
  int qt = bid & 31, n = (bid>>5)&7, b = bid>>8;
  int tid = threadIdx.x, lane = tid&63, w = tid>>6, l15 = lane&15, lg = lane>>4;
  int q0 = qt*64 + w*16;

  s8b qf[4];
  const u16t* qrow = qb + ((size_t)(b*2048 + q0 + l15)*8 + n)*128;
  #pragma unroll
  for(int kc=0;kc<4;kc++) qf[kc] = *(const s8b*)(qrow + kc*32 + lg*8);

  float m[4], lsum[4];
  f4 oacc[8];
  #pragma unroll
  for(int r=0;r<4;r++){ m[r] = -3.0e38f; lsum[r] = 0.0f; }
  #pragma unroll
  for(int db=0;db<8;db++){ f4 z = {0.0f,0.0f,0.0f,0.0f}; oacc[db]=z; }

  const u16t* kbase = kswz + (size_t)b*2048*128;
  const u16t* vbase = vswz + (size_t)b*2048*128;
  u16t* psw = Ps + w*1152;

  for(int st=0; st<32; ++st){
    const u16t* kt = kbase + st*64*128;
    const u16t* vt = vbase + st*64*128;
    __syncthreads();
    #pragma unroll
    for(int it=0; it<4; ++it){
      int e = it*2048 + tid*8;
      __builtin_amdgcn_global_load_lds((const AS1 u32t*)(kt + e), (AS3 u32t*)&Ks[e], 16,0,0);
      __builtin_amdgcn_global_load_lds((const AS1 u32t*)(vt + e), (AS3 u32t*)&Vs[e], 16,0,0);
    }
    __syncthreads();

    f4 sf[4];
    #pragma unroll
    for(int kb=0;kb<4;kb++){ f4 z = {0.0f,0.0f,0.0f,0.0f}; sf[kb]=z; }
    #pragma unroll
    for(int kb=0;kb<4;kb++){
      int key = kb*16 + l15;
      int swz = ((key&7)<<3) ^ (((key>>3)&3)<<4);
      #pragma unroll
      for(int kc=0;kc<4;kc++){
        s8b kf = *(const s8b*)&Ks[key*128 + ((kc*32 + lg*8) ^ swz)];
        sf[kb] = __builtin_amdgcn_mfma_f32_16x16x32_bf16(qf[kc], kf, sf[kb], 0,0,0);
      }
    }
    // softcap + online softmax (row = lg*4+r, reduce across l15)
    #pragma unroll
    for(int r=0;r<4;r++){
      float pv[4], mx = -3.0e38f;
      #pragma unroll
      for(int kb=0;kb<4;kb++){ pv[kb] = softcapf(sf[kb][r]); mx = fmaxf(mx, pv[kb]); }
      #pragma unroll
      for(int off=1; off<16; off<<=1) mx = fmaxf(mx, __shfl_xor(mx, off));
      float mnew = fmaxf(m[r], mx);
      float alpha = __expf(m[r] - mnew);
      m[r] = mnew;
      float srow = 0.0f;
      #pragma unroll
      for(int kb=0;kb<4;kb++){ pv[kb] = __expf(pv[kb] - mnew); srow += pv[kb]; }
      #pragma unroll
      for(int off=1; off<16; off<<=1) srow += __shfl_xor(srow, off);
      lsum[r] = lsum[r]*alpha + srow;
      #pragma unroll
      for(int db=0;db<8;db++) oacc[db][r] *= alpha;
      int prow = lg*4 + r;
      #pragma unroll
      for(int kb=0;kb<4;kb++) psw[prow*72 + kb*16 + l15] = f2b(pv[kb]);
    }
    // PV: A = P (from LDS), B = V (swizzled scalar reads)
    #pragma unroll
    for(int kc2=0;kc2<2;kc2++){
      s8b pa = *(const s8b*)&psw[l15*72 + kc2*32 + lg*8];
      #pragma unroll
      for(int db=0;db<8;db++){
        s8b vf;
        #pragma unroll
        for(int e=0;e<8;e++){
          int key = kc2*32 + lg*8 + e;
          int d = db*16 + l15;
          vf[e] = (short)Vs[key*128 + (d ^ ((key&7)<<3) ^ (((key>>3)&3)<<4))];
        }
        oacc[db] = __builtin_amdgcn_mfma_f32_16x16x32_bf16(pa, vf, oacc[db], 0,0,0);
      }
    }
  }
  #pragma unroll
  for(int db=0;db<8;db++){
    #pragma unroll
    for(int r=0;r<4;r++){
      int qrowi = q0 + lg*4 + r;
      int d = db*16 + l15;
      attnb[(size_t)(b*2048 + qrowi)*1024 + n*128 + d] = f2b(oacc[db][r] / lsum[r]);
    }
  }
}

// ---------------- host launch ----------------
extern "C" void kernel_launch(void* const* d_in, const int* in_sizes, int n_in,
                              void* d_out, int out_size, void* d_ws, size_t ws_size,
                              hipStream_t stream){
  const float* x        = (const float*)d_in[0];
  const float* pre_attn = (const float*)d_in[4];
  const float* pre_ffw  = (const float*)d_in[5];
  const float* g_qw  = (const float*)d_in[6];
  const float* g_kvw = (const float*)d_in[7];
  const float* g_ow  = (const float*)d_in[8];
  const float* a_qw  = (const float*)d_in[9];
  const float* a_kvw = (const float*)d_in[10];
  const float* a_ow  = (const float*)d_in[11];
  const float* g_gate= (const float*)d_in[12];
  const float* g_lin = (const float*)d_in[13];
  const float* a_gate= (const float*)d_in[14];
  const float* a_lin = (const float*)d_in[15];
  float* out = (float*)d_out;
  (void)in_sizes; (void)n_in; (void)out_size; (void)ws_size;

  char* wsp = (char*)d_ws; size_t off = 0;
  auto alloc = [&](size_t b){ void* p = wsp + off; off += (b + 255) & ~(size_t)255; return p; };
  u16t* wqkv_g = (u16t*)alloc((size_t)1280*1024*2);
  u16t* wqkv_a = (u16t*)alloc((size_t)1280*1024*2);
  u16t* wo_g   = (u16t*)alloc((size_t)1024*1024*2);
  u16t* wo_a   = (u16t*)alloc((size_t)1024*1024*2);
  u16t* wg_g   = (u16t*)alloc((size_t)8192*1024*2);
  u16t* wg_a   = (u16t*)alloc((size_t)4096*1024*2);
  u16t* wl_g   = (u16t*)alloc((size_t)1024*4096*2);
  u16t* wl_a   = (u16t*)alloc((size_t)1024*2048*2);
  u16t* xn     = (u16t*)alloc((size_t)8192*1024*2);
  float* qkv   = (float*)alloc((size_t)8192*1280*4);
  u16t* qb     = (u16t*)alloc((size_t)8192*1024*2);
  u16t* kswz   = (u16t*)alloc((size_t)4*2048*128*2);
  u16t* vswz   = (u16t*)alloc((size_t)4*2048*128*2);
  u16t* attnb  = (u16t*)alloc((size_t)8192*1024*2);
  float* t1    = (float*)alloc((size_t)8192*1024*4);
  u16t* xn2    = (u16t*)alloc((size_t)8192*1024*2);
  u16t* hid_g  = (u16t*)alloc((size_t)7168*4096*2);
  u16t* hid_a  = (u16t*)alloc((size_t)1024*2048*2);

  pack_qkv_k<<<(1280*1024+255)/256,256,0,stream>>>(wqkv_g, g_qw, g_kvw);
  pack_qkv_k<<<(1280*1024+255)/256,256,0,stream>>>(wqkv_a, a_qw, a_kvw);
  pack_ot_k <<<(1024*1024+255)/256,256,0,stream>>>(wo_g, g_ow);
  pack_ot_k <<<(1024*1024+255)/256,256,0,stream>>>(wo_a, a_ow);
  pack_gate_k<<<(8192*1024+255)/256,256,0,stream>>>(wg_g, g_gate, 4096, 8192*1024);
  pack_gate_k<<<(4096*1024+255)/256,256,0,stream>>>(wg_a, a_gate, 2048, 4096*1024);
  pack_lin_k<<<(1024*4096+255)/256,256,0,stream>>>(wl_g, g_lin, 12, 1024*4096);
  pack_lin_k<<<(1024*2048+255)/256,256,0,stream>>>(wl_a, a_lin, 11, 1024*2048);
  rmsnorm_k<<<8192,256,0,stream>>>(x, pre_attn, xn);

  { GemmArgs ga = {xn, 1024, wqkv_g, wqkv_a, 1024, 10, 0,0,0, 0, qkv, nullptr, 1280, nullptr};
    gemm_k<<<64*10,256,0,stream>>>(ga); }
  rope_k<<<8192,256,0,stream>>>(qkv, qb, kswz, vswz);
  attn_k<<<1024,256,0,stream>>>(qb, kswz, vswz, attnb);
  { GemmArgs ga = {attnb, 1024, wo_g, wo_a, 1024, 8, 0,0,0, 1, t1, nullptr, 1024, x};
    gemm_k<<<64*8,256,0,stream>>>(ga); }
  rmsnorm_k<<<8192,256,0,stream>>>(t1, pre_ffw, xn2);
  { GemmArgs ga = {xn2, 1024, wg_g, nullptr, 1024, 64, 1,1,0, 3, nullptr, hid_g, 4096, nullptr};
    gemm_k<<<56*64,256,0,stream>>>(ga); }
  { GemmArgs ga = {xn2, 1024, wg_a, nullptr, 1024, 32, 2,1,0, 3, nullptr, hid_a, 2048, nullptr};
    gemm_k<<<8*32,256,0,stream>>>(ga); }
  { GemmArgs ga = {hid_g, 4096, wl_g, nullptr, 4096, 8, 1,0,1, 1, out, nullptr, 1024, x};
    gemm_k<<<56*8,256,0,stream>>>(ga); }
  { GemmArgs ga = {hid_a, 2048, wl_a, nullptr, 2048, 8, 2,0,1, 1, out, nullptr, 1024, x};
    gemm_k<<<8*8,256,0,stream>>>(ga); }
}

// Round 3
// 1063.013 us; speedup vs baseline: 1.1150x; 1.1150x over previous
//
#include <hip/hip_runtime.h>
#include <hip/hip_bf16.h>
#include <stdint.h>

typedef short s8b __attribute__((ext_vector_type(8)));
typedef float f4 __attribute__((ext_vector_type(4)));
typedef unsigned short u16t;
typedef unsigned int u32t;

#define AS1 __attribute__((address_space(1)))
#define AS3 __attribute__((address_space(3)))
#define DEVFN static __device__ __forceinline__

DEVFN u16t f2b(float f){ union{ __hip_bfloat16 h; u16t u; } c; c.h = __float2bfloat16(f); return c.u; }

DEVFN float geluf(float x){
  float t = 0.7978845608028654f*(x + 0.044715f*x*x*x);
  t = fminf(fmaxf(t, -15.0f), 15.0f);
  float e = __expf(2.0f*t);
  return 0.5f*x*(1.0f + (e-1.0f)/(e+1.0f));
}
DEVFN float softcapf(float x){
  float t = x*0.02f;
  t = fminf(fmaxf(t, -15.0f), 15.0f);
  float e = __expf(2.0f*t);
  return 50.0f*(e-1.0f)/(e+1.0f);
}

// ---------------- weight packing (fp32 -> bf16, transposed to [N][K]) ----------------
__global__ void pack_qkv_k(u16t* dst, const float* qw, const float* kvw){
  int i = blockIdx.x*256 + threadIdx.x;
  if(i >= 1280*1024) return;
  int row = i >> 10, d = i & 1023;
  float v;
  if(row < 1024){ int n = row >> 7, h = row & 127; v = qw[(n*1024 + d)*128 + h]; }
  else if(row < 1152){ v = kvw[d*128 + (row-1024)]; }
  else { v = kvw[131072 + d*128 + (row-1152)]; }
  dst[i] = f2b(v);
}
__global__ void pack_ot_k(u16t* dst, const float* ow){
  int i = blockIdx.x*256 + threadIdx.x;
  if(i >= 1024*1024) return;
  int dd = i >> 10, nh = i & 1023;
  dst[i] = f2b(ow[nh*1024 + dd]);
}
// gate rows interleaved: row r -> gate[r&1][:, r>>1]
__global__ void pack_gate_k(u16t* dst, const float* gate, int F, int total){
  int i = blockIdx.x*256 + threadIdx.x;
  if(i >= total) return;
  int r = i >> 10, dd = i & 1023;
  dst[i] = f2b(gate[(r&1)*(1024*F) + dd*F + (r>>1)]);
}
__global__ void pack_lin_k(u16t* dst, const float* lin, int lf, int total){
  int i = blockIdx.x*256 + threadIdx.x;
  if(i >= total) return;
  int dd = i >> lf, f = i & ((1<<lf)-1);
  dst[i] = f2b(lin[f*1024 + dd]);
}

// ---------------- RMSNorm (one block per row of 1024) ----------------
__global__ __launch_bounds__(256) void rmsnorm_k(const float* __restrict__ x, const float* __restrict__ sc,
                                                 u16t* __restrict__ out){
  int row = blockIdx.x;
  int tid = threadIdx.x;
  const float* xr = x + (size_t)row*1024;
  float4 v = *(const float4*)(xr + tid*4);
  float s = v.x*v.x + v.y*v.y + v.z*v.z + v.w*v.w;
  #pragma unroll
  for(int off=32; off>=1; off>>=1) s += __shfl_down(s, off);
  __shared__ float ws4[4];
  if((tid & 63) == 0) ws4[tid>>6] = s;
  __syncthreads();
  float tot = ws4[0]+ws4[1]+ws4[2]+ws4[3];
  float r = rsqrtf(tot*(1.0f/1024.0f) + 1e-6f);
  float4 scv = *(const float4*)(sc + tid*4);
  u16t o0 = f2b(v.x*r*(1.0f+scv.x)), o1 = f2b(v.y*r*(1.0f+scv.y));
  u16t o2 = f2b(v.z*r*(1.0f+scv.z)), o3 = f2b(v.w*r*(1.0f+scv.w));
  uint2 pk; pk.x = (u32t)o0 | ((u32t)o1<<16); pk.y = (u32t)o2 | ((u32t)o3<<16);
  *(uint2*)(out + (size_t)row*1024 + tid*4) = pk;
}

// ---------------- RoPE + convert; K stored pre-swizzled, V row-major ----------------
__global__ __launch_bounds__(256) void rope_k(const float* __restrict__ qkv, u16t* __restrict__ qb,
                                              u16t* __restrict__ kswz, u16t* __restrict__ vrow){
  int row = blockIdx.x;
  int b = row >> 11, t = row & 2047;
  float pos = (float)(t + (t >= 1792 ? 1 : 0));
  const float* src = qkv + (size_t)row*1280;
  size_t kvbase = ((size_t)b*2048 + t)*128;
  int swz = ((t&7)<<3) ^ (((t>>3)&3)<<4);
  for(int idx = threadIdx.x; idx < 704; idx += 256){
    if(idx < 512){
      int n = idx >> 6, i = idx & 63;
      float inv = exp2f((float)i * -0.20762050593046f); // 10000^{-i/64}
      float sn, cs; sincosf(pos*inv, &sn, &cs);
      float x1 = src[n*128+i], x2 = src[n*128+i+64];
      const float qs = 0.08838834764831845f; // 1/sqrt(128)
      qb[(size_t)row*1024 + n*128 + i]      = f2b((x1*cs - x2*sn)*qs);
      qb[(size_t)row*1024 + n*128 + i + 64] = f2b((x2*cs + x1*sn)*qs);
    } else if(idx < 576){
      int i = idx - 512;
      float inv = exp2f((float)i * -0.20762050593046f);
      float sn, cs; sincosf(pos*inv, &sn, &cs);
      float x1 = src[1024+i], x2 = src[1024+i+64];
      kswz[kvbase + (i ^ swz)]        = f2b(x1*cs - x2*sn);
      kswz[kvbase + ((i+64) ^ swz)]   = f2b(x2*cs + x1*sn);
    } else {
      int h = idx - 576;
      vrow[kvbase + h] = f2b(src[1152+h]);
    }
  }
}

// ---------------- V transpose pack: vrow[b][t][h] -> vtswz[b][d][key ^ ((d&7)<<3)] ----
__global__ __launch_bounds__(256) void vt_pack_k(const u16t* __restrict__ vrow, u16t* __restrict__ vtswz){
  int blk = blockIdx.x;            // b*32 + kt
  int b = blk >> 5, kt = blk & 31;
  int tid = threadIdx.x;
  const u16t* src = vrow + ((size_t)b*2048 + kt*64)*128;
  #pragma unroll
  for(int it=0; it<4; ++it){
    int o = it*2048 + tid*8;
    int d = o >> 6, kg = o & 63;   // kg is a multiple of 8
    u16t tmp[8];
    #pragma unroll
    for(int j=0;j<8;j++) tmp[j] = src[(size_t)(kg+j)*128 + d];
    *(uint4*)&vtswz[((size_t)b*128 + d)*2048 + kt*64 + (kg ^ ((d&7)<<3))] = *(const uint4*)tmp;
  }
}

// ---------------- generic bf16 MFMA GEMM, 128x128 tile, BK=32, 4 waves ----------------
struct GemmArgs {
  const u16t* A; int lda;
  const u16t* Bg; const u16t* Ba;
  int K; int ntN; int mode; int amap; int omap; int ep;
  float* outf; u16t* outb; int ldo;
  const float* res;
};

__global__ __launch_bounds__(256) void gemm_k(GemmArgs g){
  __shared__ __align__(16) u16t As[128*32];
  __shared__ __align__(16) u16t Bs[128*32];
  int bid = blockIdx.x;
  int mt = bid / g.ntN, nt = bid % g.ntN;
  int c0 = mt*128, g0;
  const u16t* B;
  if(g.mode == 0){
    g0 = c0;
    B = ((mt & 15) < 14) ? g.Bg : g.Ba;   // t<1792 -> g weights
  } else if(g.mode == 1){                  // g-half compact rows: 14 tiles per batch
    int bb = mt/14, t = (mt - bb*14)*128;
    g0 = bb*2048 + t; B = g.Bg;
  } else {                                 // a-half compact rows: 2 tiles per batch
    int bb = mt>>1, t = 1792 + (mt&1)*128;
    g0 = bb*2048 + t; B = g.Bg;
  }
  int arow = g.amap ? g0 : c0;
  int orow = g.omap ? g0 : c0;
  int tid = threadIdx.x, lane = tid & 63, w = tid >> 6, l15 = lane & 15, lg = lane >> 4;
  int wr = w >> 1, wc = w & 1;

  const u16t* Ap = g.A + (size_t)(arow + (tid>>2))*g.lda + (tid&3)*8;
  const u16t* Bp = B   + (size_t)(nt*128 + (tid>>2))*g.K + (tid&3)*8;
  size_t lda64 = (size_t)64*g.lda, ldb64 = (size_t)64*g.K;
  u32t le = tid*8;

  f4 acc[4][4];
  #pragma unroll
  for(int mi=0;mi<4;mi++)
    #pragma unroll
    for(int ni=0;ni<4;ni++){ f4 z = {0.0f,0.0f,0.0f,0.0f}; acc[mi][ni]=z; }

  for(int k0=0; k0 < g.K; k0 += 32){
    __syncthreads();
    __builtin_amdgcn_global_load_lds((const AS1 u32t*)(Ap + k0),          (AS3 u32t*)&As[le],        16,0,0);
    __builtin_amdgcn_global_load_lds((const AS1 u32t*)(Ap + k0 + lda64),  (AS3 u32t*)&As[le + 2048], 16,0,0);
    __builtin_amdgcn_global_load_lds((const AS1 u32t*)(Bp + k0),          (AS3 u32t*)&Bs[le],        16,0,0);
    __builtin_amdgcn_global_load_lds((const AS1 u32t*)(Bp + k0 + ldb64),  (AS3 u32t*)&Bs[le + 2048], 16,0,0);
    __syncthreads();
    s8b af[4], bf[4];
    #pragma unroll
    for(int mi=0;mi<4;mi++) af[mi] = *(const s8b*)&As[(wr*64 + mi*16 + l15)*32 + lg*8];
    #pragma unroll
    for(int ni=0;ni<4;ni++) bf[ni] = *(const s8b*)&Bs[(wc*64 + ni*16 + l15)*32 + lg*8];
    #pragma unroll
    for(int mi=0;mi<4;mi++)
      #pragma unroll
      for(int ni=0;ni<4;ni++)
        acc[mi][ni] = __builtin_amdgcn_mfma_f32_16x16x32_bf16(af[mi], bf[ni], acc[mi][ni], 0,0,0);
  }

  #pragma unroll
  for(int mi=0;mi<4;mi++){
    #pragma unroll
    for(int ni=0;ni<4;ni++){
      int rowb = wr*64 + mi*16 + lg*4;
      int col = nt*128 + wc*64 + ni*16 + l15;
      #pragma unroll
      for(int r=0;r<4;r++){
        float v = acc[mi][ni][r];
        size_t ro = (size_t)(orow + rowb + r);
        if(g.ep == 0){
          g.outf[ro*(size_t)g.ldo + col] = v;
        } else if(g.ep == 1){
          g.outf[ro*(size_t)g.ldo + col] = v + g.res[ro*1024 + col];
        } else { // gelu-pair: even col = g1, odd col = g2
          float other = __shfl_xor(v, 1);
          if((lane & 1) == 0){
            g.outb[ro*(size_t)g.ldo + (col>>1)] = f2b(geluf(v)*other);
          }
        }
      }
    }
  }
}

// ---------------- flash attention: block = (b, head, 64 q rows), S-tiles of 64 ----------------
// R1-proven sync structure (barrier -> global_load_lds -> barrier -> compute);
// V staged as V^T with granule swizzle so PV B-fragments are single ds_read_b128.
__global__ __launch_bounds__(256) void attn_k(const u16t* __restrict__ qb, const u16t* __restrict__ kswz,
                                              const u16t* __restrict__ vtswz, u16t* __restrict__ attnb){
  __shared__ __align__(16) u16t Ks[64*128];   // [key][h ^ swz(key)]
  __shared__ __align__(16) u16t Vt[128*64];   // [d][key-granule ^ ((d&7)<<3)]
  __shared__ __align__(16) u16t Ps[4*16*72];
  int bid = blockIdx.x;
  int qt = bid & 31, n = (bid>>5)&7, b = bid>>8;
  int tid = threadIdx.x, lane = tid&63, w = tid>>6, l15 = lane&15, lg = lane>>4;
  int q0 = qt*64 + w*16;

  s8b qf[4];
  const u16t* qrow = qb + ((size_t)(b*2048 + q0 + l15)*8 + n)*128;
  #pragma unroll
  for(int kc=0;kc<4;kc++) qf[kc] = *(const s8b*)(qrow + kc*32 + lg*8);

  float m[4], lsum[4];
  f4 oacc[8];
  #pragma unroll
  for(int r=0;r<4;r++){ m[r] = -3.0e38f; lsum[r] = 0.0f; }
  #pragma unroll
  for(int db=0;db<8;db++){ f4 z = {0.0f,0.0f,0.0f,0.0f}; oacc[db]=z; }

  const u16t* kbase  = kswz  + (size_t)b*2048*128;
  const u16t* vtbase = vtswz + (size_t)b*128*2048;
  u16t* psw = Ps + w*1152;

  for(int st=0; st<32; ++st){
    const u16t* kt  = kbase  + (size_t)st*64*128;
    const u16t* vtb = vtbase + st*64;
    __syncthreads();
    #pragma unroll
    for(int it=0; it<4; ++it){
      int e = it*2048 + tid*8;
      __builtin_amdgcn_global_load_lds((const AS1 u32t*)(kt + e), (AS3 u32t*)&Ks[e], 16,0,0);
    }
    #pragma unroll
    for(int it=0; it<4; ++it){
      int e = it*2048 + tid*8;
      int d = e >> 6, ko = e & 63;      // d = it*32 + (tid>>3), ko = (tid&7)*8
      __builtin_amdgcn_global_load_lds((const AS1 u32t*)(vtb + (size_t)d*2048 + ko), (AS3 u32t*)&Vt[e], 16,0,0);
    }
    __syncthreads();

    // ---- QK^T ----
    f4 sf[4];
    #pragma unroll
    for(int kb=0;kb<4;kb++){ f4 z = {0.0f,0.0f,0.0f,0.0f}; sf[kb]=z; }
    #pragma unroll
    for(int kb=0;kb<4;kb++){
      int key = kb*16 + l15;
      int swz = ((key&7)<<3) ^ (((key>>3)&3)<<4);
      #pragma unroll
      for(int kc=0;kc<4;kc++){
        s8b kf = *(const s8b*)&Ks[key*128 + ((kc*32 + lg*8) ^ swz)];
        sf[kb] = __builtin_amdgcn_mfma_f32_16x16x32_bf16(qf[kc], kf, sf[kb], 0,0,0);
      }
    }
    // ---- softcap + online softmax (row = lg*4+r, reduce across l15) ----
    #pragma unroll
    for(int r=0;r<4;r++){
      float pv[4], mx = -3.0e38f;
      #pragma unroll
      for(int kb=0;kb<4;kb++){ pv[kb] = softcapf(sf[kb][r]); mx = fmaxf(mx, pv[kb]); }
      #pragma unroll
      for(int off=1; off<16; off<<=1) mx = fmaxf(mx, __shfl_xor(mx, off));
      float mnew = fmaxf(m[r], mx);
      float alpha = __expf(m[r] - mnew);
      m[r] = mnew;
      float srow = 0.0f;
      #pragma unroll
      for(int kb=0;kb<4;kb++){ pv[kb] = __expf(pv[kb] - mnew); srow += pv[kb]; }
      #pragma unroll
      for(int off=1; off<16; off<<=1) srow += __shfl_xor(srow, off);
      lsum[r] = lsum[r]*alpha + srow;
      #pragma unroll
      for(int db=0;db<8;db++) oacc[db][r] *= alpha;
      int prow = lg*4 + r;
      #pragma unroll
      for(int kb=0;kb<4;kb++) psw[prow*72 + kb*16 + l15] = f2b(pv[kb]);
    }
    // ---- PV: A = P (LDS), B = V^T (vector LDS reads, swizzled) ----
    #pragma unroll
    for(int kc2=0;kc2<2;kc2++){
      s8b pa = *(const s8b*)&psw[l15*72 + kc2*32 + lg*8];
      int koff = (kc2*32 + lg*8) ^ ((l15&7)<<3);
      #pragma unroll
      for(int db=0;db<8;db++){
        s8b vf = *(const s8b*)&Vt[(db*16 + l15)*64 + koff];
        oacc[db] = __builtin_amdgcn_mfma_f32_16x16x32_bf16(pa, vf, oacc[db], 0,0,0);
      }
    }
  }

  #pragma unroll
  for(int db=0;db<8;db++){
    #pragma unroll
    for(int r=0;r<4;r++){
      int qrowi = q0 + lg*4 + r;
      int d = db*16 + l15;
      attnb[(size_t)(b*2048 + qrowi)*1024 + n*128 + d] = f2b(oacc[db][r] / lsum[r]);
    }
  }
}

// ---------------- host launch ----------------
extern "C" void kernel_launch(void* const* d_in, const int* in_sizes, int n_in,
                              void* d_out, int out_size, void* d_ws, size_t ws_size,
                              hipStream_t stream){
  const float* x        = (const float*)d_in[0];
  const float* pre_attn = (const float*)d_in[4];
  const float* pre_ffw  = (const float*)d_in[5];
  const float* g_qw  = (const float*)d_in[6];
  const float* g_kvw = (const float*)d_in[7];
  const float* g_ow  = (const float*)d_in[8];
  const float* a_qw  = (const float*)d_in[9];
  const float* a_kvw = (const float*)d_in[10];
  const float* a_ow  = (const float*)d_in[11];
  const float* g_gate= (const float*)d_in[12];
  const float* g_lin = (const float*)d_in[13];
  const float* a_gate= (const float*)d_in[14];
  const float* a_lin = (const float*)d_in[15];
  float* out = (float*)d_out;
  (void)in_sizes; (void)n_in; (void)out_size; (void)ws_size;

  char* wsp = (char*)d_ws; size_t off = 0;
  auto alloc = [&](size_t b){ void* p = wsp + off; off += (b + 255) & ~(size_t)255; return p; };
  // weights (persistent within a call)
  u16t* wqkv_g = (u16t*)alloc((size_t)1280*1024*2);
  u16t* wqkv_a = (u16t*)alloc((size_t)1280*1024*2);
  u16t* wo_g   = (u16t*)alloc((size_t)1024*1024*2);
  u16t* wo_a   = (u16t*)alloc((size_t)1024*1024*2);
  u16t* wg_g   = (u16t*)alloc((size_t)8192*1024*2);
  u16t* wg_a   = (u16t*)alloc((size_t)4096*1024*2);
  u16t* wl_g   = (u16t*)alloc((size_t)1024*4096*2);
  u16t* wl_a   = (u16t*)alloc((size_t)1024*2048*2);
  // xn region reused by xn2 (xn dead after QKV GEMM; xn2 written later)
  u16t* xn     = (u16t*)alloc((size_t)8192*1024*2);
  u16t* xn2    = xn;
  // big region shared by qkv (fp32) -> t1 (fp32) -> hid_g (bf16); lifetimes disjoint
  char* big    = (char*)alloc((size_t)7168*4096*2);   // 58.7 MB >= qkv 41.9 MB >= t1 33.5 MB
  float* qkv   = (float*)big;
  float* t1    = (float*)big;
  u16t* hid_g  = (u16t*)big;
  u16t* qb     = (u16t*)alloc((size_t)8192*1024*2);
  u16t* kswz   = (u16t*)alloc((size_t)4*2048*128*2);
  u16t* vrow   = (u16t*)alloc((size_t)4*2048*128*2);
  u16t* vtswz  = (u16t*)alloc((size_t)4*128*2048*2);
  u16t* attnb  = (u16t*)alloc((size_t)8192*1024*2);
  u16t* hid_a  = (u16t*)alloc((size_t)1024*2048*2);

  pack_qkv_k<<<(1280*1024+255)/256,256,0,stream>>>(wqkv_g, g_qw, g_kvw);
  pack_qkv_k<<<(1280*1024+255)/256,256,0,stream>>>(wqkv_a, a_qw, a_kvw);
  pack_ot_k <<<(1024*1024+255)/256,256,0,stream>>>(wo_g, g_ow);
  pack_ot_k <<<(1024*1024+255)/256,256,0,stream>>>(wo_a, a_ow);
  pack_gate_k<<<(8192*1024+255)/256,256,0,stream>>>(wg_g, g_gate, 4096, 8192*1024);
  pack_gate_k<<<(4096*1024+255)/256,256,0,stream>>>(wg_a, a_gate, 2048, 4096*1024);
  pack_lin_k<<<(1024*4096+255)/256,256,0,stream>>>(wl_g, g_lin, 12, 1024*4096);
  pack_lin_k<<<(1024*2048+255)/256,256,0,stream>>>(wl_a, a_lin, 11, 1024*2048);
  rmsnorm_k<<<8192,256,0,stream>>>(x, pre_attn, xn);

  { GemmArgs ga = {xn, 1024, wqkv_g, wqkv_a, 1024, 10, 0,0,0, 0, qkv, nullptr, 1280, nullptr};
    gemm_k<<<64*10,256,0,stream>>>(ga); }
  rope_k<<<8192,256,0,stream>>>(qkv, qb, kswz, vrow);
  vt_pack_k<<<128,256,0,stream>>>(vrow, vtswz);
  attn_k<<<1024,256,0,stream>>>(qb, kswz, vtswz, attnb);
  { GemmArgs ga = {attnb, 1024, wo_g, wo_a, 1024, 8, 0,0,0, 1, t1, nullptr, 1024, x};
    gemm_k<<<64*8,256,0,stream>>>(ga); }
  rmsnorm_k<<<8192,256,0,stream>>>(t1, pre_ffw, xn2);
  { GemmArgs ga = {xn2, 1024, wg_g, nullptr, 1024, 64, 1,1,0, 3, nullptr, hid_g, 4096, nullptr};
    gemm_k<<<56*64,256,0,stream>>>(ga); }
  { GemmArgs ga = {xn2, 1024, wg_a, nullptr, 1024, 32, 2,1,0, 3, nullptr, hid_a, 2048, nullptr};
    gemm_k<<<8*32,256,0,stream>>>(ga); }
  { GemmArgs ga = {hid_g, 4096, wl_g, nullptr, 4096, 8, 1,0,1, 1, out, nullptr, 1024, x};
    gemm_k<<<56*8,256,0,stream>>>(ga); }
  { GemmArgs ga = {hid_a, 2048, wl_a, nullptr, 2048, 8, 2,0,1, 1, out, nullptr, 1024, x};
    gemm_k<<<8*8,256,0,stream>>>(ga); }
}

// Round 4
// 955.077 us; speedup vs baseline: 1.2410x; 1.1130x over previous
//
#include <hip/hip_runtime.h>
#include <hip/hip_bf16.h>
#include <stdint.h>

typedef short s8b __attribute__((ext_vector_type(8)));
typedef float f4 __attribute__((ext_vector_type(4)));
typedef unsigned short u16t;
typedef unsigned int u32t;

#define AS1 __attribute__((address_space(1)))
#define AS3 __attribute__((address_space(3)))
#define DEVFN static __device__ __forceinline__

DEVFN u16t f2b(float f){ union{ __hip_bfloat16 h; u16t u; } c; c.h = __float2bfloat16(f); return c.u; }

DEVFN float geluf(float x){
  float t = 0.7978845608028654f*(x + 0.044715f*x*x*x);
  t = fminf(fmaxf(t, -15.0f), 15.0f);
  float e = __expf(2.0f*t);
  return 0.5f*x*(1.0f + (e-1.0f)/(e+1.0f));
}
DEVFN float softcapf(float x){
  float t = x*0.02f;
  t = fminf(fmaxf(t, -15.0f), 15.0f);
  float e = __expf(2.0f*t);
  return 50.0f*(e-1.0f)/(e+1.0f);
}

// ---------------- weight packing (fp32 -> bf16, transposed to [N][K]) ----------------
__global__ void pack_qkv_k(u16t* dst, const float* qw, const float* kvw){
  int i = blockIdx.x*256 + threadIdx.x;
  if(i >= 1280*1024) return;
  int row = i >> 10, d = i & 1023;
  float v;
  if(row < 1024){ int n = row >> 7, h = row & 127; v = qw[(n*1024 + d)*128 + h]; }
  else if(row < 1152){ v = kvw[d*128 + (row-1024)]; }
  else { v = kvw[131072 + d*128 + (row-1152)]; }
  dst[i] = f2b(v);
}
__global__ void pack_ot_k(u16t* dst, const float* ow){
  int i = blockIdx.x*256 + threadIdx.x;
  if(i >= 1024*1024) return;
  int dd = i >> 10, nh = i & 1023;
  dst[i] = f2b(ow[nh*1024 + dd]);
}
// gate rows interleaved: row r -> gate[r&1][:, r>>1]
__global__ void pack_gate_k(u16t* dst, const float* gate, int F, int total){
  int i = blockIdx.x*256 + threadIdx.x;
  if(i >= total) return;
  int r = i >> 10, dd = i & 1023;
  dst[i] = f2b(gate[(r&1)*(1024*F) + dd*F + (r>>1)]);
}
__global__ void pack_lin_k(u16t* dst, const float* lin, int lf, int total){
  int i = blockIdx.x*256 + threadIdx.x;
  if(i >= total) return;
  int dd = i >> lf, f = i & ((1<<lf)-1);
  dst[i] = f2b(lin[f*1024 + dd]);
}

// ---------------- RMSNorm (one block per row of 1024) ----------------
__global__ __launch_bounds__(256) void rmsnorm_k(const float* __restrict__ x, const float* __restrict__ sc,
                                                 u16t* __restrict__ out){
  int row = blockIdx.x;
  int tid = threadIdx.x;
  const float* xr = x + (size_t)row*1024;
  float4 v = *(const float4*)(xr + tid*4);
  float s = v.x*v.x + v.y*v.y + v.z*v.z + v.w*v.w;
  #pragma unroll
  for(int off=32; off>=1; off>>=1) s += __shfl_down(s, off);
  __shared__ float ws4[4];
  if((tid & 63) == 0) ws4[tid>>6] = s;
  __syncthreads();
  float tot = ws4[0]+ws4[1]+ws4[2]+ws4[3];
  float r = rsqrtf(tot*(1.0f/1024.0f) + 1e-6f);
  float4 scv = *(const float4*)(sc + tid*4);
  u16t o0 = f2b(v.x*r*(1.0f+scv.x)), o1 = f2b(v.y*r*(1.0f+scv.y));
  u16t o2 = f2b(v.z*r*(1.0f+scv.z)), o3 = f2b(v.w*r*(1.0f+scv.w));
  uint2 pk; pk.x = (u32t)o0 | ((u32t)o1<<16); pk.y = (u32t)o2 | ((u32t)o3<<16);
  *(uint2*)(out + (size_t)row*1024 + tid*4) = pk;
}

// ---------------- RoPE + convert; K stored pre-swizzled, V row-major ----------------
__global__ __launch_bounds__(256) void rope_k(const float* __restrict__ qkv, u16t* __restrict__ qb,
                                              u16t* __restrict__ kswz, u16t* __restrict__ vrow){
  int row = blockIdx.x;
  int b = row >> 11, t = row & 2047;
  float pos = (float)(t + (t >= 1792 ? 1 : 0));
  const float* src = qkv + (size_t)row*1280;
  size_t kvbase = ((size_t)b*2048 + t)*128;
  int swz = ((t&7)<<3) ^ (((t>>3)&3)<<4);
  for(int idx = threadIdx.x; idx < 704; idx += 256){
    if(idx < 512){
      int n = idx >> 6, i = idx & 63;
      float inv = exp2f((float)i * -0.20762050593046f); // 10000^{-i/64}
      float sn, cs; sincosf(pos*inv, &sn, &cs);
      float x1 = src[n*128+i], x2 = src[n*128+i+64];
      const float qs = 0.08838834764831845f; // 1/sqrt(128)
      qb[(size_t)row*1024 + n*128 + i]      = f2b((x1*cs - x2*sn)*qs);
      qb[(size_t)row*1024 + n*128 + i + 64] = f2b((x2*cs + x1*sn)*qs);
    } else if(idx < 576){
      int i = idx - 512;
      float inv = exp2f((float)i * -0.20762050593046f);
      float sn, cs; sincosf(pos*inv, &sn, &cs);
      float x1 = src[1024+i], x2 = src[1024+i+64];
      kswz[kvbase + (i ^ swz)]        = f2b(x1*cs - x2*sn);
      kswz[kvbase + ((i+64) ^ swz)]   = f2b(x2*cs + x1*sn);
    } else {
      int h = idx - 576;
      vrow[kvbase + h] = f2b(src[1152+h]);
    }
  }
}

// ---------------- V transpose pack: vrow[b][t][h] -> vtswz[b][d][key ^ ((d&7)<<3)] ----
__global__ __launch_bounds__(256) void vt_pack_k(const u16t* __restrict__ vrow, u16t* __restrict__ vtswz){
  int blk = blockIdx.x;            // b*32 + kt
  int b = blk >> 5, kt = blk & 31;
  int tid = threadIdx.x;
  const u16t* src = vrow + ((size_t)b*2048 + kt*64)*128;
  #pragma unroll
  for(int it=0; it<4; ++it){
    int o = it*2048 + tid*8;
    int d = o >> 6, kg = o & 63;   // kg is a multiple of 8
    u16t tmp[8];
    #pragma unroll
    for(int j=0;j<8;j++) tmp[j] = src[(size_t)(kg+j)*128 + d];
    *(uint4*)&vtswz[((size_t)b*128 + d)*2048 + kt*64 + (kg ^ ((d&7)<<3))] = *(const uint4*)tmp;
  }
}

// ---------------- generic bf16 MFMA GEMM, 128x128 tile, BK=32, 4 waves ----------------
// Double-buffered LDS, single barrier per K-step; STAGE issued before compute so
// global_load_lds latency hides under ds_read+MFMA (catalog T3 minimum-2-phase).
struct GemmArgs {
  const u16t* A; int lda;
  const u16t* Bg; const u16t* Ba;
  int K; int ntN; int mode; int amap; int omap; int ep;
  float* outf; u16t* outb; int ldo;
  const float* res;
};

__global__ __launch_bounds__(256) void gemm_k(GemmArgs g){
  __shared__ __align__(16) u16t As[2*128*32];
  __shared__ __align__(16) u16t Bs[2*128*32];
  int bid = blockIdx.x;
  int mt = bid / g.ntN, nt = bid % g.ntN;
  int c0 = mt*128, g0;
  const u16t* B;
  if(g.mode == 0){
    g0 = c0;
    B = ((mt & 15) < 14) ? g.Bg : g.Ba;   // t<1792 -> g weights
  } else if(g.mode == 1){                  // g-half compact rows: 14 tiles per batch
    int bb = mt/14, t = (mt - bb*14)*128;
    g0 = bb*2048 + t; B = g.Bg;
  } else {                                 // a-half compact rows: 2 tiles per batch
    int bb = mt>>1, t = 1792 + (mt&1)*128;
    g0 = bb*2048 + t; B = g.Bg;
  }
  int arow = g.amap ? g0 : c0;
  int orow = g.omap ? g0 : c0;
  int tid = threadIdx.x, lane = tid & 63, w = tid >> 6, l15 = lane & 15, lg = lane >> 4;
  int wr = w >> 1, wc = w & 1;

  const u16t* Ap = g.A + (size_t)(arow + (tid>>2))*g.lda + (tid&3)*8;
  const u16t* Bp = B   + (size_t)(nt*128 + (tid>>2))*g.K + (tid&3)*8;
  size_t lda64 = (size_t)64*g.lda, ldb64 = (size_t)64*g.K;
  u32t le = tid*8;

  f4 acc[4][4];
  #pragma unroll
  for(int mi=0;mi<4;mi++)
    #pragma unroll
    for(int ni=0;ni<4;ni++){ f4 z = {0.0f,0.0f,0.0f,0.0f}; acc[mi][ni]=z; }

  auto stagef = [&](int buf, int k0){
    u16t* a = As + buf*4096;
    u16t* b = Bs + buf*4096;
    __builtin_amdgcn_global_load_lds((const AS1 u32t*)(Ap + k0),          (AS3 u32t*)&a[le],        16,0,0);
    __builtin_amdgcn_global_load_lds((const AS1 u32t*)(Ap + k0 + lda64),  (AS3 u32t*)&a[le + 2048], 16,0,0);
    __builtin_amdgcn_global_load_lds((const AS1 u32t*)(Bp + k0),          (AS3 u32t*)&b[le],        16,0,0);
    __builtin_amdgcn_global_load_lds((const AS1 u32t*)(Bp + k0 + ldb64),  (AS3 u32t*)&b[le + 2048], 16,0,0);
  };

  stagef(0, 0);
  __syncthreads();          // drains vmcnt(0) (compiler) -> buf0 ready
  int cur = 0;
  for(int k0=0; k0 < g.K; k0 += 32){
    if(k0 + 32 < g.K) stagef(cur^1, k0+32);   // in-flight during compute
    const u16t* as = As + cur*4096;
    const u16t* bs = Bs + cur*4096;
    s8b af[4], bf[4];
    #pragma unroll
    for(int mi=0;mi<4;mi++) af[mi] = *(const s8b*)&as[(wr*64 + mi*16 + l15)*32 + lg*8];
    #pragma unroll
    for(int ni=0;ni<4;ni++) bf[ni] = *(const s8b*)&bs[(wc*64 + ni*16 + l15)*32 + lg*8];
    #pragma unroll
    for(int mi=0;mi<4;mi++)
      #pragma unroll
      for(int ni=0;ni<4;ni++)
        acc[mi][ni] = __builtin_amdgcn_mfma_f32_16x16x32_bf16(af[mi], bf[ni], acc[mi][ni], 0,0,0);
    __syncthreads();        // next buf staged + everyone done reading cur
    cur ^= 1;
  }

  #pragma unroll
  for(int mi=0;mi<4;mi++){
    #pragma unroll
    for(int ni=0;ni<4;ni++){
      int rowb = wr*64 + mi*16 + lg*4;
      int col = nt*128 + wc*64 + ni*16 + l15;
      #pragma unroll
      for(int r=0;r<4;r++){
        float v = acc[mi][ni][r];
        size_t ro = (size_t)(orow + rowb + r);
        if(g.ep == 0){
          g.outf[ro*(size_t)g.ldo + col] = v;
        } else if(g.ep == 1){
          g.outf[ro*(size_t)g.ldo + col] = v + g.res[ro*1024 + col];
        } else { // gelu-pair: even col = g1, odd col = g2
          float other = __shfl_xor(v, 1);
          if((lane & 1) == 0){
            g.outb[ro*(size_t)g.ldo + (col>>1)] = f2b(geluf(v)*other);
          }
        }
      }
    }
  }
}

// ---------------- flash attention: block = (b, head, 64 q rows), S-tiles of 64 ----------------
// Softcap bounds |logit| <= 50, so exp() can't overflow/underflow-to-zero-sum:
// static-max softmax (no running max, no rescale); lsum accumulated per-lane,
// reduced across the 16-lane group once after the K-loop.
__global__ __launch_bounds__(256) void attn_k(const u16t* __restrict__ qb, const u16t* __restrict__ kswz,
                                              const u16t* __restrict__ vtswz, u16t* __restrict__ attnb){
  __shared__ __align__(16) u16t Ks[64*128];   // [key][h ^ swz(key)]
  __shared__ __align__(16) u16t Vt[128*64];   // [d][key-granule ^ ((d&7)<<3)]
  __shared__ __align__(16) u16t Ps[4*16*72];
  int bid = blockIdx.x;
  int qt = bid & 31, n = (bid>>5)&7, b = bid>>8;
  int tid = threadIdx.x, lane = tid&63, w = tid>>6, l15 = lane&15, lg = lane>>4;
  int q0 = qt*64 + w*16;

  s8b qf[4];
  const u16t* qrow = qb + ((size_t)(b*2048 + q0 + l15)*8 + n)*128;
  #pragma unroll
  for(int kc=0;kc<4;kc++) qf[kc] = *(const s8b*)(qrow + kc*32 + lg*8);

  float lsum[4];
  f4 oacc[8];
  #pragma unroll
  for(int r=0;r<4;r++) lsum[r] = 0.0f;
  #pragma unroll
  for(int db=0;db<8;db++){ f4 z = {0.0f,0.0f,0.0f,0.0f}; oacc[db]=z; }

  const u16t* kbase  = kswz  + (size_t)b*2048*128;
  const u16t* vtbase = vtswz + (size_t)b*128*2048;
  u16t* psw = Ps + w*1152;

  for(int st=0; st<32; ++st){
    const u16t* kt  = kbase  + (size_t)st*64*128;
    const u16t* vtb = vtbase + st*64;
    __syncthreads();
    #pragma unroll
    for(int it=0; it<4; ++it){
      int e = it*2048 + tid*8;
      __builtin_amdgcn_global_load_lds((const AS1 u32t*)(kt + e), (AS3 u32t*)&Ks[e], 16,0,0);
    }
    #pragma unroll
    for(int it=0; it<4; ++it){
      int e = it*2048 + tid*8;
      int d = e >> 6, ko = e & 63;
      __builtin_amdgcn_global_load_lds((const AS1 u32t*)(vtb + (size_t)d*2048 + ko), (AS3 u32t*)&Vt[e], 16,0,0);
    }
    __syncthreads();

    // ---- QK^T ----
    f4 sf[4];
    #pragma unroll
    for(int kb=0;kb<4;kb++){ f4 z = {0.0f,0.0f,0.0f,0.0f}; sf[kb]=z; }
    #pragma unroll
    for(int kb=0;kb<4;kb++){
      int key = kb*16 + l15;
      int swz = ((key&7)<<3) ^ (((key>>3)&3)<<4);
      #pragma unroll
      for(int kc=0;kc<4;kc++){
        s8b kf = *(const s8b*)&Ks[key*128 + ((kc*32 + lg*8) ^ swz)];
        sf[kb] = __builtin_amdgcn_mfma_f32_16x16x32_bf16(qf[kc], kf, sf[kb], 0,0,0);
      }
    }
    // ---- softcap + exp, per-lane lsum accumulate (no max tracking) ----
    #pragma unroll
    for(int r=0;r<4;r++){
      int prow = lg*4 + r;
      #pragma unroll
      for(int kb=0;kb<4;kb++){
        float pv = __expf(softcapf(sf[kb][r]));
        lsum[r] += pv;
        psw[prow*72 + kb*16 + l15] = f2b(pv);
      }
    }
    // ---- PV: A = P (LDS), B = V^T (vector LDS reads, swizzled) ----
    #pragma unroll
    for(int kc2=0;kc2<2;kc2++){
      s8b pa = *(const s8b*)&psw[l15*72 + kc2*32 + lg*8];
      int koff = (kc2*32 + lg*8) ^ ((l15&7)<<3);
      #pragma unroll
      for(int db=0;db<8;db++){
        s8b vf = *(const s8b*)&Vt[(db*16 + l15)*64 + koff];
        oacc[db] = __builtin_amdgcn_mfma_f32_16x16x32_bf16(pa, vf, oacc[db], 0,0,0);
      }
    }
  }

  float linv[4];
  #pragma unroll
  for(int r=0;r<4;r++){
    float s = lsum[r];
    #pragma unroll
    for(int off=1; off<16; off<<=1) s += __shfl_xor(s, off);
    linv[r] = 1.0f / s;
  }

  #pragma unroll
  for(int db=0;db<8;db++){
    #pragma unroll
    for(int r=0;r<4;r++){
      int qrowi = q0 + lg*4 + r;
      int d = db*16 + l15;
      attnb[(size_t)(b*2048 + qrowi)*1024 + n*128 + d] = f2b(oacc[db][r] * linv[r]);
    }
  }
}

// ---------------- host launch ----------------
extern "C" void kernel_launch(void* const* d_in, const int* in_sizes, int n_in,
                              void* d_out, int out_size, void* d_ws, size_t ws_size,
                              hipStream_t stream){
  const float* x        = (const float*)d_in[0];
  const float* pre_attn = (const float*)d_in[4];
  const float* pre_ffw  = (const float*)d_in[5];
  const float* g_qw  = (const float*)d_in[6];
  const float* g_kvw = (const float*)d_in[7];
  const float* g_ow  = (const float*)d_in[8];
  const float* a_qw  = (const float*)d_in[9];
  const float* a_kvw = (const float*)d_in[10];
  const float* a_ow  = (const float*)d_in[11];
  const float* g_gate= (const float*)d_in[12];
  const float* g_lin = (const float*)d_in[13];
  const float* a_gate= (const float*)d_in[14];
  const float* a_lin = (const float*)d_in[15];
  float* out = (float*)d_out;
  (void)in_sizes; (void)n_in; (void)out_size; (void)ws_size;

  char* wsp = (char*)d_ws; size_t off = 0;
  auto alloc = [&](size_t b){ void* p = wsp + off; off += (b + 255) & ~(size_t)255; return p; };
  // weights (persistent within a call)
  u16t* wqkv_g = (u16t*)alloc((size_t)1280*1024*2);
  u16t* wqkv_a = (u16t*)alloc((size_t)1280*1024*2);
  u16t* wo_g   = (u16t*)alloc((size_t)1024*1024*2);
  u16t* wo_a   = (u16t*)alloc((size_t)1024*1024*2);
  u16t* wg_g   = (u16t*)alloc((size_t)8192*1024*2);
  u16t* wg_a   = (u16t*)alloc((size_t)4096*1024*2);
  u16t* wl_g   = (u16t*)alloc((size_t)1024*4096*2);
  u16t* wl_a   = (u16t*)alloc((size_t)1024*2048*2);
  // xn region reused by xn2 (xn dead after QKV GEMM; xn2 written later)
  u16t* xn     = (u16t*)alloc((size_t)8192*1024*2);
  u16t* xn2    = xn;
  // big region shared by qkv (fp32) -> t1 (fp32) -> hid_g (bf16); lifetimes disjoint
  char* big    = (char*)alloc((size_t)7168*4096*2);   // 58.7 MB >= qkv 41.9 MB >= t1 33.5 MB
  float* qkv   = (float*)big;
  float* t1    = (float*)big;
  u16t* hid_g  = (u16t*)big;
  u16t* qb     = (u16t*)alloc((size_t)8192*1024*2);
  u16t* kswz   = (u16t*)alloc((size_t)4*2048*128*2);
  u16t* vrow   = (u16t*)alloc((size_t)4*2048*128*2);
  u16t* vtswz  = (u16t*)alloc((size_t)4*128*2048*2);
  u16t* attnb  = (u16t*)alloc((size_t)8192*1024*2);
  u16t* hid_a  = (u16t*)alloc((size_t)1024*2048*2);

  pack_qkv_k<<<(1280*1024+255)/256,256,0,stream>>>(wqkv_g, g_qw, g_kvw);
  pack_qkv_k<<<(1280*1024+255)/256,256,0,stream>>>(wqkv_a, a_qw, a_kvw);
  pack_ot_k <<<(1024*1024+255)/256,256,0,stream>>>(wo_g, g_ow);
  pack_ot_k <<<(1024*1024+255)/256,256,0,stream>>>(wo_a, a_ow);
  pack_gate_k<<<(8192*1024+255)/256,256,0,stream>>>(wg_g, g_gate, 4096, 8192*1024);
  pack_gate_k<<<(4096*1024+255)/256,256,0,stream>>>(wg_a, a_gate, 2048, 4096*1024);
  pack_lin_k<<<(1024*4096+255)/256,256,0,stream>>>(wl_g, g_lin, 12, 1024*4096);
  pack_lin_k<<<(1024*2048+255)/256,256,0,stream>>>(wl_a, a_lin, 11, 1024*2048);
  rmsnorm_k<<<8192,256,0,stream>>>(x, pre_attn, xn);

  { GemmArgs ga = {xn, 1024, wqkv_g, wqkv_a, 1024, 10, 0,0,0, 0, qkv, nullptr, 1280, nullptr};
    gemm_k<<<64*10,256,0,stream>>>(ga); }
  rope_k<<<8192,256,0,stream>>>(qkv, qb, kswz, vrow);
  vt_pack_k<<<128,256,0,stream>>>(vrow, vtswz);
  attn_k<<<1024,256,0,stream>>>(qb, kswz, vtswz, attnb);
  { GemmArgs ga = {attnb, 1024, wo_g, wo_a, 1024, 8, 0,0,0, 1, t1, nullptr, 1024, x};
    gemm_k<<<64*8,256,0,stream>>>(ga); }
  rmsnorm_k<<<8192,256,0,stream>>>(t1, pre_ffw, xn2);
  { GemmArgs ga = {xn2, 1024, wg_g, nullptr, 1024, 64, 1,1,0, 3, nullptr, hid_g, 4096, nullptr};
    gemm_k<<<56*64,256,0,stream>>>(ga); }
  { GemmArgs ga = {xn2, 1024, wg_a, nullptr, 1024, 32, 2,1,0, 3, nullptr, hid_a, 2048, nullptr};
    gemm_k<<<8*32,256,0,stream>>>(ga); }
  { GemmArgs ga = {hid_g, 4096, wl_g, nullptr, 4096, 8, 1,0,1, 1, out, nullptr, 1024, x};
    gemm_k<<<56*8,256,0,stream>>>(ga); }
  { GemmArgs ga = {hid_a, 2048, wl_a, nullptr, 2048, 8, 2,0,1, 1, out, nullptr, 1024, x};
    gemm_k<<<8*8,256,0,stream>>>(ga); }
}

// Round 5
// 875.318 us; speedup vs baseline: 1.3541x; 1.0911x over previous
//
#include <hip/hip_runtime.h>
#include <hip/hip_bf16.h>
#include <stdint.h>

typedef short s8b __attribute__((ext_vector_type(8)));
typedef float f4 __attribute__((ext_vector_type(4)));
typedef unsigned short u16t;
typedef unsigned int u32t;

#define AS1 __attribute__((address_space(1)))
#define AS3 __attribute__((address_space(3)))
#define DEVFN static __device__ __forceinline__

DEVFN u16t f2b(float f){ union{ __hip_bfloat16 h; u16t u; } c; c.h = __float2bfloat16(f); return c.u; }

DEVFN float geluf(float x){
  float t = 0.7978845608028654f*(x + 0.044715f*x*x*x);
  t = fminf(fmaxf(t, -15.0f), 15.0f);
  float e = __expf(2.0f*t);
  return 0.5f*x*(1.0f + (e-1.0f)/(e+1.0f));
}
DEVFN float softcapf(float x){
  float t = x*0.02f;
  t = fminf(fmaxf(t, -15.0f), 15.0f);
  float e = __expf(2.0f*t);
  return 50.0f*(e-1.0f)/(e+1.0f);
}

// ---------------- generic LDS-tiled transpose-pack (fp32 -> bf16) ----------------
// dst[(f*rmul + roff + z*prow)*lddst + d] = f2b(src[z*pstride + d*ldsrc + f])
// grid.x = NF/32 (f tiles), grid.y = ND/32 (d tiles), grid.z = planes. block 256.
__global__ __launch_bounds__(256) void tpack_k(u16t* __restrict__ dst, const float* __restrict__ src,
                                               int ldsrc, int lddst, int rmul, int roff, int prow,
                                               size_t pstride){
  __shared__ float tile[32][33];
  int z = blockIdx.z;
  const float* s = src + (size_t)z*pstride;
  int f0 = blockIdx.x*32, d0 = blockIdx.y*32;
  int t = threadIdx.x, r = t>>5, c = t&31;
  #pragma unroll
  for(int i=0;i<4;i++)
    tile[r + i*8][c] = s[(size_t)(d0 + r + i*8)*ldsrc + f0 + c];
  __syncthreads();
  int rbase = roff + z*prow;
  #pragma unroll
  for(int i=0;i<4;i++){
    int f = f0 + r + i*8;
    dst[(size_t)(f*rmul + rbase)*lddst + d0 + c] = f2b(tile[c][r + i*8]);
  }
}

// ---------------- RMSNorm (one block per row of 1024) ----------------
__global__ __launch_bounds__(256) void rmsnorm_k(const float* __restrict__ x, const float* __restrict__ sc,
                                                 u16t* __restrict__ out){
  int row = blockIdx.x;
  int tid = threadIdx.x;
  const float* xr = x + (size_t)row*1024;
  float4 v = *(const float4*)(xr + tid*4);
  float s = v.x*v.x + v.y*v.y + v.z*v.z + v.w*v.w;
  #pragma unroll
  for(int off=32; off>=1; off>>=1) s += __shfl_down(s, off);
  __shared__ float ws4[4];
  if((tid & 63) == 0) ws4[tid>>6] = s;
  __syncthreads();
  float tot = ws4[0]+ws4[1]+ws4[2]+ws4[3];
  float r = rsqrtf(tot*(1.0f/1024.0f) + 1e-6f);
  float4 scv = *(const float4*)(sc + tid*4);
  u16t o0 = f2b(v.x*r*(1.0f+scv.x)), o1 = f2b(v.y*r*(1.0f+scv.y));
  u16t o2 = f2b(v.z*r*(1.0f+scv.z)), o3 = f2b(v.w*r*(1.0f+scv.w));
  uint2 pk; pk.x = (u32t)o0 | ((u32t)o1<<16); pk.y = (u32t)o2 | ((u32t)o3<<16);
  *(uint2*)(out + (size_t)row*1024 + tid*4) = pk;
}

// ---------------- RoPE + convert; K stored pre-swizzled, V row-major ----------------
__global__ __launch_bounds__(256) void rope_k(const float* __restrict__ qkv, u16t* __restrict__ qb,
                                              u16t* __restrict__ kswz, u16t* __restrict__ vrow){
  int row = blockIdx.x;
  int b = row >> 11, t = row & 2047;
  float pos = (float)(t + (t >= 1792 ? 1 : 0));
  const float* src = qkv + (size_t)row*1280;
  size_t kvbase = ((size_t)b*2048 + t)*128;
  int swz = ((t&7)<<3) ^ (((t>>3)&3)<<4);
  for(int idx = threadIdx.x; idx < 704; idx += 256){
    if(idx < 512){
      int n = idx >> 6, i = idx & 63;
      float inv = exp2f((float)i * -0.20762050593046f); // 10000^{-i/64}
      float sn, cs; sincosf(pos*inv, &sn, &cs);
      float x1 = src[n*128+i], x2 = src[n*128+i+64];
      const float qs = 0.08838834764831845f; // 1/sqrt(128)
      qb[(size_t)row*1024 + n*128 + i]      = f2b((x1*cs - x2*sn)*qs);
      qb[(size_t)row*1024 + n*128 + i + 64] = f2b((x2*cs + x1*sn)*qs);
    } else if(idx < 576){
      int i = idx - 512;
      float inv = exp2f((float)i * -0.20762050593046f);
      float sn, cs; sincosf(pos*inv, &sn, &cs);
      float x1 = src[1024+i], x2 = src[1024+i+64];
      kswz[kvbase + (i ^ swz)]        = f2b(x1*cs - x2*sn);
      kswz[kvbase + ((i+64) ^ swz)]   = f2b(x2*cs + x1*sn);
    } else {
      int h = idx - 576;
      vrow[kvbase + h] = f2b(src[1152+h]);
    }
  }
}

// ---------------- V transpose pack: vrow[b][t][h] -> vtswz[b][d][key ^ ((d&7)<<3)] ----
__global__ __launch_bounds__(256) void vt_pack_k(const u16t* __restrict__ vrow, u16t* __restrict__ vtswz){
  int blk = blockIdx.x;            // b*32 + kt
  int b = blk >> 5, kt = blk & 31;
  int tid = threadIdx.x;
  const u16t* src = vrow + ((size_t)b*2048 + kt*64)*128;
  #pragma unroll
  for(int it=0; it<4; ++it){
    int o = it*2048 + tid*8;
    int d = o >> 6, kg = o & 63;   // kg is a multiple of 8
    u16t tmp[8];
    #pragma unroll
    for(int j=0;j<8;j++) tmp[j] = src[(size_t)(kg+j)*128 + d];
    *(uint4*)&vtswz[((size_t)b*128 + d)*2048 + kt*64 + (kg ^ ((d&7)<<3))] = *(const uint4*)tmp;
  }
}

// ---------------- generic bf16 MFMA GEMM, 128x128 tile, BK=32, 4 waves ----------------
// Double-buffered LDS, single barrier per K-step. LDS granule swizzle (both-sides
// involution, linear global_load_lds dest): phys granule q(row,g) = row*4 + (g ^ ((row>>1)&3)).
// Per-16-lane phase the fragment reads then hit all 8 bank-groups 2-way = conflict-free.
struct GemmArgs {
  const u16t* A; int lda;
  const u16t* Bg; const u16t* Ba;
  int K; int ntN; int mode; int amap; int omap; int ep;
  float* outf; u16t* outb; int ldo;
  const float* res;
};

__global__ __launch_bounds__(256) void gemm_k(GemmArgs g){
  __shared__ __align__(16) u16t As[2*128*32];
  __shared__ __align__(16) u16t Bs[2*128*32];
  int bid = blockIdx.x;
  int mt = bid / g.ntN, nt = bid % g.ntN;
  int c0 = mt*128, g0;
  const u16t* B;
  if(g.mode == 0){
    g0 = c0;
    B = ((mt & 15) < 14) ? g.Bg : g.Ba;   // t<1792 -> g weights
  } else if(g.mode == 1){                  // g-half compact rows: 14 tiles per batch
    int bb = mt/14, t = (mt - bb*14)*128;
    g0 = bb*2048 + t; B = g.Bg;
  } else {                                 // a-half compact rows: 2 tiles per batch
    int bb = mt>>1, t = 1792 + (mt&1)*128;
    g0 = bb*2048 + t; B = g.Bg;
  }
  int arow = g.amap ? g0 : c0;
  int orow = g.omap ? g0 : c0;
  int tid = threadIdx.x, lane = tid & 63, w = tid >> 6, l15 = lane & 15, lg = lane >> 4;
  int wr = w >> 1, wc = w & 1;

  // staging: thread s writes phys granule s (linear); fetch logical granule (s&3)^((s>>3)&3)
  int gsrc = ((tid&3) ^ ((tid>>3)&3))*8;
  const u16t* Ap = g.A + (size_t)(arow + (tid>>2))*g.lda + gsrc;
  const u16t* Bp = B   + (size_t)(nt*128 + (tid>>2))*g.K + gsrc;
  size_t lda64 = (size_t)64*g.lda, ldb64 = (size_t)64*g.K;
  u32t le = tid*8;

  // fragment read offsets (swizzled), constant across K-loop
  int xr = (lg ^ ((l15>>1)&3))*8;
  int aoff[4], boff[4];
  #pragma unroll
  for(int mi=0;mi<4;mi++) aoff[mi] = (wr*64 + mi*16 + l15)*32 + xr;
  #pragma unroll
  for(int ni=0;ni<4;ni++) boff[ni] = (wc*64 + ni*16 + l15)*32 + xr;

  f4 acc[4][4];
  #pragma unroll
  for(int mi=0;mi<4;mi++)
    #pragma unroll
    for(int ni=0;ni<4;ni++){ f4 z = {0.0f,0.0f,0.0f,0.0f}; acc[mi][ni]=z; }

  auto stagef = [&](int buf, int k0){
    u16t* a = As + buf*4096;
    u16t* b = Bs + buf*4096;
    __builtin_amdgcn_global_load_lds((const AS1 u32t*)(Ap + k0),          (AS3 u32t*)&a[le],        16,0,0);
    __builtin_amdgcn_global_load_lds((const AS1 u32t*)(Ap + k0 + lda64),  (AS3 u32t*)&a[le + 2048], 16,0,0);
    __builtin_amdgcn_global_load_lds((const AS1 u32t*)(Bp + k0),          (AS3 u32t*)&b[le],        16,0,0);
    __builtin_amdgcn_global_load_lds((const AS1 u32t*)(Bp + k0 + ldb64),  (AS3 u32t*)&b[le + 2048], 16,0,0);
  };

  stagef(0, 0);
  __syncthreads();          // drains vmcnt(0) (compiler) -> buf0 ready
  int cur = 0;
  for(int k0=0; k0 < g.K; k0 += 32){
    if(k0 + 32 < g.K) stagef(cur^1, k0+32);   // in-flight during compute
    const u16t* as = As + cur*4096;
    const u16t* bs = Bs + cur*4096;
    s8b af[4], bf[4];
    #pragma unroll
    for(int mi=0;mi<4;mi++) af[mi] = *(const s8b*)&as[aoff[mi]];
    #pragma unroll
    for(int ni=0;ni<4;ni++) bf[ni] = *(const s8b*)&bs[boff[ni]];
    #pragma unroll
    for(int mi=0;mi<4;mi++)
      #pragma unroll
      for(int ni=0;ni<4;ni++)
        acc[mi][ni] = __builtin_amdgcn_mfma_f32_16x16x32_bf16(af[mi], bf[ni], acc[mi][ni], 0,0,0);
    __syncthreads();        // next buf staged + everyone done reading cur
    cur ^= 1;
  }

  #pragma unroll
  for(int mi=0;mi<4;mi++){
    #pragma unroll
    for(int ni=0;ni<4;ni++){
      int rowb = wr*64 + mi*16 + lg*4;
      int col = nt*128 + wc*64 + ni*16 + l15;
      #pragma unroll
      for(int r=0;r<4;r++){
        float v = acc[mi][ni][r];
        size_t ro = (size_t)(orow + rowb + r);
        if(g.ep == 0){
          g.outf[ro*(size_t)g.ldo + col] = v;
        } else if(g.ep == 1){
          g.outf[ro*(size_t)g.ldo + col] = v + g.res[ro*1024 + col];
        } else { // gelu-pair: even col = g1, odd col = g2
          float other = __shfl_xor(v, 1);
          if((lane & 1) == 0){
            g.outb[ro*(size_t)g.ldo + (col>>1)] = f2b(geluf(v)*other);
          }
        }
      }
    }
  }
}

// ---------------- flash attention: block = (b, head, 64 q rows), S-tiles of 64 ----------------
// Softcap bounds |logit| <= 50 -> static-max softmax (no running max / rescale);
// lsum per-lane, one 16-lane reduce after the K-loop.
__global__ __launch_bounds__(256) void attn_k(const u16t* __restrict__ qb, const u16t* __restrict__ kswz,
                                              const u16t* __restrict__ vtswz, u16t* __restrict__ attnb){
  __shared__ __align__(16) u16t Ks[64*128];   // [key][h ^ swz(key)]
  __shared__ __align__(16) u16t Vt[128*64];   // [d][key-granule ^ ((d&7)<<3)]
  __shared__ __align__(16) u16t Ps[4*16*72];
  int bid = blockIdx.x;
  int qt = bid & 31, n = (bid>>5)&7, b = bid>>8;
  int tid = threadIdx.x, lane = tid&63, w = tid>>6, l15 = lane&15, lg = lane>>4;
  int q0 = qt*64 + w*16;

  s8b qf[4];
  const u16t* qrow = qb + ((size_t)(b*2048 + q0 + l15)*8 + n)*128;
  #pragma unroll
  for(int kc=0;kc<4;kc++) qf[kc] = *(const s8b*)(qrow + kc*32 + lg*8);

  float lsum[4];
  f4 oacc[8];
  #pragma unroll
  for(int r=0;r<4;r++) lsum[r] = 0.0f;
  #pragma unroll
  for(int db=0;db<8;db++){ f4 z = {0.0f,0.0f,0.0f,0.0f}; oacc[db]=z; }

  const u16t* kbase  = kswz  + (size_t)b*2048*128;
  const u16t* vtbase = vtswz + (size_t)b*128*2048;
  u16t* psw = Ps + w*1152;

  for(int st=0; st<32; ++st){
    const u16t* kt  = kbase  + (size_t)st*64*128;
    const u16t* vtb = vtbase + st*64;
    __syncthreads();
    #pragma unroll
    for(int it=0; it<4; ++it){
      int e = it*2048 + tid*8;
      __builtin_amdgcn_global_load_lds((const AS1 u32t*)(kt + e), (AS3 u32t*)&Ks[e], 16,0,0);
    }
    #pragma unroll
    for(int it=0; it<4; ++it){
      int e = it*2048 + tid*8;
      int d = e >> 6, ko = e & 63;
      __builtin_amdgcn_global_load_lds((const AS1 u32t*)(vtb + (size_t)d*2048 + ko), (AS3 u32t*)&Vt[e], 16,0,0);
    }
    __syncthreads();

    // ---- QK^T ----
    f4 sf[4];
    #pragma unroll
    for(int kb=0;kb<4;kb++){ f4 z = {0.0f,0.0f,0.0f,0.0f}; sf[kb]=z; }
    #pragma unroll
    for(int kb=0;kb<4;kb++){
      int key = kb*16 + l15;
      int swz = ((key&7)<<3) ^ (((key>>3)&3)<<4);
      #pragma unroll
      for(int kc=0;kc<4;kc++){
        s8b kf = *(const s8b*)&Ks[key*128 + ((kc*32 + lg*8) ^ swz)];
        sf[kb] = __builtin_amdgcn_mfma_f32_16x16x32_bf16(qf[kc], kf, sf[kb], 0,0,0);
      }
    }
    // ---- softcap + exp, per-lane lsum accumulate (no max tracking) ----
    #pragma unroll
    for(int r=0;r<4;r++){
      int prow = lg*4 + r;
      #pragma unroll
      for(int kb=0;kb<4;kb++){
        float pv = __expf(softcapf(sf[kb][r]));
        lsum[r] += pv;
        psw[prow*72 + kb*16 + l15] = f2b(pv);
      }
    }
    // ---- PV: A = P (LDS), B = V^T (vector LDS reads, swizzled) ----
    #pragma unroll
    for(int kc2=0;kc2<2;kc2++){
      s8b pa = *(const s8b*)&psw[l15*72 + kc2*32 + lg*8];
      int koff = (kc2*32 + lg*8) ^ ((l15&7)<<3);
      #pragma unroll
      for(int db=0;db<8;db++){
        s8b vf = *(const s8b*)&Vt[(db*16 + l15)*64 + koff];
        oacc[db] = __builtin_amdgcn_mfma_f32_16x16x32_bf16(pa, vf, oacc[db], 0,0,0);
      }
    }
  }

  float linv[4];
  #pragma unroll
  for(int r=0;r<4;r++){
    float s = lsum[r];
    #pragma unroll
    for(int off=1; off<16; off<<=1) s += __shfl_xor(s, off);
    linv[r] = 1.0f / s;
  }

  #pragma unroll
  for(int db=0;db<8;db++){
    #pragma unroll
    for(int r=0;r<4;r++){
      int qrowi = q0 + lg*4 + r;
      int d = db*16 + l15;
      attnb[(size_t)(b*2048 + qrowi)*1024 + n*128 + d] = f2b(oacc[db][r] * linv[r]);
    }
  }
}

// ---------------- host launch ----------------
extern "C" void kernel_launch(void* const* d_in, const int* in_sizes, int n_in,
                              void* d_out, int out_size, void* d_ws, size_t ws_size,
                              hipStream_t stream){
  const float* x        = (const float*)d_in[0];
  const float* pre_attn = (const float*)d_in[4];
  const float* pre_ffw  = (const float*)d_in[5];
  const float* g_qw  = (const float*)d_in[6];
  const float* g_kvw = (const float*)d_in[7];
  const float* g_ow  = (const float*)d_in[8];
  const float* a_qw  = (const float*)d_in[9];
  const float* a_kvw = (const float*)d_in[10];
  const float* a_ow  = (const float*)d_in[11];
  const float* g_gate= (const float*)d_in[12];
  const float* g_lin = (const float*)d_in[13];
  const float* a_gate= (const float*)d_in[14];
  const float* a_lin = (const float*)d_in[15];
  float* out = (float*)d_out;
  (void)in_sizes; (void)n_in; (void)out_size; (void)ws_size;

  char* wsp = (char*)d_ws; size_t off = 0;
  auto alloc = [&](size_t b){ void* p = wsp + off; off += (b + 255) & ~(size_t)255; return p; };
  // weights (persistent within a call)
  u16t* wqkv_g = (u16t*)alloc((size_t)1280*1024*2);
  u16t* wqkv_a = (u16t*)alloc((size_t)1280*1024*2);
  u16t* wo_g   = (u16t*)alloc((size_t)1024*1024*2);
  u16t* wo_a   = (u16t*)alloc((size_t)1024*1024*2);
  u16t* wg_g   = (u16t*)alloc((size_t)8192*1024*2);
  u16t* wg_a   = (u16t*)alloc((size_t)4096*1024*2);
  u16t* wl_g   = (u16t*)alloc((size_t)1024*4096*2);
  u16t* wl_a   = (u16t*)alloc((size_t)1024*2048*2);
  // xn region reused by xn2 (xn dead after QKV GEMM; xn2 written later)
  u16t* xn     = (u16t*)alloc((size_t)8192*1024*2);
  u16t* xn2    = xn;
  // big region shared by qkv (fp32) -> t1 (fp32) -> hid_g (bf16); lifetimes disjoint
  char* big    = (char*)alloc((size_t)7168*4096*2);   // 58.7 MB >= qkv 41.9 MB >= t1 33.5 MB
  float* qkv   = (float*)big;
  float* t1    = (float*)big;
  u16t* hid_g  = (u16t*)big;
  u16t* qb     = (u16t*)alloc((size_t)8192*1024*2);
  u16t* kswz   = (u16t*)alloc((size_t)4*2048*128*2);
  u16t* vrow   = (u16t*)alloc((size_t)4*2048*128*2);
  u16t* vtswz  = (u16t*)alloc((size_t)4*128*2048*2);
  u16t* attnb  = (u16t*)alloc((size_t)8192*1024*2);
  u16t* hid_a  = (u16t*)alloc((size_t)1024*2048*2);

  // ---- weight packs: coalesced LDS-tiled transposes ----
  // q: dst row n*128+h, col d  <- qw[n][d][h]
  tpack_k<<<dim3(4,32,8),256,0,stream>>>(wqkv_g, g_qw, 128, 1024, 1, 0, 128, 131072);
  tpack_k<<<dim3(4,32,1),256,0,stream>>>(wqkv_g, g_kvw, 128, 1024, 1, 1024, 0, 0);
  tpack_k<<<dim3(4,32,1),256,0,stream>>>(wqkv_g, g_kvw + 131072, 128, 1024, 1, 1152, 0, 0);
  tpack_k<<<dim3(4,32,8),256,0,stream>>>(wqkv_a, a_qw, 128, 1024, 1, 0, 128, 131072);
  tpack_k<<<dim3(4,32,1),256,0,stream>>>(wqkv_a, a_kvw, 128, 1024, 1, 1024, 0, 0);
  tpack_k<<<dim3(4,32,1),256,0,stream>>>(wqkv_a, a_kvw + 131072, 128, 1024, 1, 1152, 0, 0);
  // ot: dst row dd, col nh <- ow[nh][dd]
  tpack_k<<<dim3(32,32,1),256,0,stream>>>(wo_g, g_ow, 1024, 1024, 1, 0, 0, 0);
  tpack_k<<<dim3(32,32,1),256,0,stream>>>(wo_a, a_ow, 1024, 1024, 1, 0, 0, 0);
  // gate: dst row 2f+p, col dd <- gate[p][dd][f]
  tpack_k<<<dim3(128,32,2),256,0,stream>>>(wg_g, g_gate, 4096, 1024, 2, 0, 1, (size_t)1024*4096);
  tpack_k<<<dim3(64,32,2),256,0,stream>>>(wg_a, a_gate, 2048, 1024, 2, 0, 1, (size_t)1024*2048);
  // lin: dst row dd, col f (ldd=F) <- lin[f][dd]
  tpack_k<<<dim3(32,128,1),256,0,stream>>>(wl_g, g_lin, 1024, 4096, 1, 0, 0, 0);
  tpack_k<<<dim3(32,64,1),256,0,stream>>>(wl_a, a_lin, 1024, 2048, 1, 0, 0, 0);

  rmsnorm_k<<<8192,256,0,stream>>>(x, pre_attn, xn);

  { GemmArgs ga = {xn, 1024, wqkv_g, wqkv_a, 1024, 10, 0,0,0, 0, qkv, nullptr, 1280, nullptr};
    gemm_k<<<64*10,256,0,stream>>>(ga); }
  rope_k<<<8192,256,0,stream>>>(qkv, qb, kswz, vrow);
  vt_pack_k<<<128,256,0,stream>>>(vrow, vtswz);
  attn_k<<<1024,256,0,stream>>>(qb, kswz, vtswz, attnb);
  { GemmArgs ga = {attnb, 1024, wo_g, wo_a, 1024, 8, 0,0,0, 1, t1, nullptr, 1024, x};
    gemm_k<<<64*8,256,0,stream>>>(ga); }
  rmsnorm_k<<<8192,256,0,stream>>>(t1, pre_ffw, xn2);
  { GemmArgs ga = {xn2, 1024, wg_g, nullptr, 1024, 64, 1,1,0, 3, nullptr, hid_g, 4096, nullptr};
    gemm_k<<<56*64,256,0,stream>>>(ga); }
  { GemmArgs ga = {xn2, 1024, wg_a, nullptr, 1024, 32, 2,1,0, 3, nullptr, hid_a, 2048, nullptr};
    gemm_k<<<8*32,256,0,stream>>>(ga); }
  { GemmArgs ga = {hid_g, 4096, wl_g, nullptr, 4096, 8, 1,0,1, 1, out, nullptr, 1024, x};
    gemm_k<<<56*8,256,0,stream>>>(ga); }
  { GemmArgs ga = {hid_a, 2048, wl_a, nullptr, 2048, 8, 2,0,1, 1, out, nullptr, 1024, x};
    gemm_k<<<8*8,256,0,stream>>>(ga); }
}

// Round 7
// 873.110 us; speedup vs baseline: 1.3575x; 1.0025x over previous
//
#include <hip/hip_runtime.h>
#include <hip/hip_bf16.h>
#include <stdint.h>

typedef short s8b __attribute__((ext_vector_type(8)));
typedef float f4 __attribute__((ext_vector_type(4)));
typedef unsigned short u16t;
typedef unsigned int u32t;

#define AS1 __attribute__((address_space(1)))
#define AS3 __attribute__((address_space(3)))
#define DEVFN static __device__ __forceinline__

DEVFN u16t f2b(float f){ union{ __hip_bfloat16 h; u16t u; } c; c.h = __float2bfloat16(f); return c.u; }

DEVFN float geluf(float x){
  float t = 0.7978845608028654f*(x + 0.044715f*x*x*x);
  t = fminf(fmaxf(t, -15.0f), 15.0f);
  float e = __expf(2.0f*t);
  return 0.5f*x*(1.0f + (e-1.0f)/(e+1.0f));
}
DEVFN float softcapf(float x){
  float t = x*0.02f;
  t = fminf(fmaxf(t, -15.0f), 15.0f);
  float e = __expf(2.0f*t);
  return 50.0f*(e-1.0f)/(e+1.0f);
}

// ---------------- generic LDS-tiled transpose-pack (fp32 -> bf16) ----------------
__global__ __launch_bounds__(256) void tpack_k(u16t* __restrict__ dst, const float* __restrict__ src,
                                               int ldsrc, int lddst, int rmul, int roff, int prow,
                                               size_t pstride){
  __shared__ float tile[32][33];
  int z = blockIdx.z;
  const float* s = src + (size_t)z*pstride;
  int f0 = blockIdx.x*32, d0 = blockIdx.y*32;
  int t = threadIdx.x, r = t>>5, c = t&31;
  #pragma unroll
  for(int i=0;i<4;i++)
    tile[r + i*8][c] = s[(size_t)(d0 + r + i*8)*ldsrc + f0 + c];
  __syncthreads();
  int rbase = roff + z*prow;
  #pragma unroll
  for(int i=0;i<4;i++){
    int f = f0 + r + i*8;
    dst[(size_t)(f*rmul + rbase)*lddst + d0 + c] = f2b(tile[c][r + i*8]);
  }
}

// ---------------- RMSNorm (one block per row of 1024) ----------------
__global__ __launch_bounds__(256) void rmsnorm_k(const float* __restrict__ x, const float* __restrict__ sc,
                                                 u16t* __restrict__ out){
  int row = blockIdx.x;
  int tid = threadIdx.x;
  const float* xr = x + (size_t)row*1024;
  float4 v = *(const float4*)(xr + tid*4);
  float s = v.x*v.x + v.y*v.y + v.z*v.z + v.w*v.w;
  #pragma unroll
  for(int off=32; off>=1; off>>=1) s += __shfl_down(s, off);
  __shared__ float ws4[4];
  if((tid & 63) == 0) ws4[tid>>6] = s;
  __syncthreads();
  float tot = ws4[0]+ws4[1]+ws4[2]+ws4[3];
  float r = rsqrtf(tot*(1.0f/1024.0f) + 1e-6f);
  float4 scv = *(const float4*)(sc + tid*4);
  u16t o0 = f2b(v.x*r*(1.0f+scv.x)), o1 = f2b(v.y*r*(1.0f+scv.y));
  u16t o2 = f2b(v.z*r*(1.0f+scv.z)), o3 = f2b(v.w*r*(1.0f+scv.w));
  uint2 pk; pk.x = (u32t)o0 | ((u32t)o1<<16); pk.y = (u32t)o2 | ((u32t)o3<<16);
  *(uint2*)(out + (size_t)row*1024 + tid*4) = pk;
}

// ---------------- RoPE + convert; K stored pre-swizzled, V row-major ----------------
__global__ __launch_bounds__(256) void rope_k(const float* __restrict__ qkv, u16t* __restrict__ qb,
                                              u16t* __restrict__ kswz, u16t* __restrict__ vrow){
  int row = blockIdx.x;
  int b = row >> 11, t = row & 2047;
  float pos = (float)(t + (t >= 1792 ? 1 : 0));
  const float* src = qkv + (size_t)row*1280;
  size_t kvbase = ((size_t)b*2048 + t)*128;
  int swz = ((t&7)<<3) ^ (((t>>3)&3)<<4);
  for(int idx = threadIdx.x; idx < 704; idx += 256){
    if(idx < 512){
      int n = idx >> 6, i = idx & 63;
      float inv = exp2f((float)i * -0.20762050593046f); // 10000^{-i/64}
      float sn, cs; sincosf(pos*inv, &sn, &cs);
      float x1 = src[n*128+i], x2 = src[n*128+i+64];
      const float qs = 0.08838834764831845f; // 1/sqrt(128)
      qb[(size_t)row*1024 + n*128 + i]      = f2b((x1*cs - x2*sn)*qs);
      qb[(size_t)row*1024 + n*128 + i + 64] = f2b((x2*cs + x1*sn)*qs);
    } else if(idx < 576){
      int i = idx - 512;
      float inv = exp2f((float)i * -0.20762050593046f);
      float sn, cs; sincosf(pos*inv, &sn, &cs);
      float x1 = src[1024+i], x2 = src[1024+i+64];
      kswz[kvbase + (i ^ swz)]        = f2b(x1*cs - x2*sn);
      kswz[kvbase + ((i+64) ^ swz)]   = f2b(x2*cs + x1*sn);
    } else {
      int h = idx - 576;
      vrow[kvbase + h] = f2b(src[1152+h]);
    }
  }
}

// ---------------- V transpose pack: vrow[b][t][h] -> vtswz[b][d][key ^ ((d&7)<<3)] ----
__global__ __launch_bounds__(256) void vt_pack_k(const u16t* __restrict__ vrow, u16t* __restrict__ vtswz){
  int blk = blockIdx.x;            // b*32 + kt
  int b = blk >> 5, kt = blk & 31;
  int tid = threadIdx.x;
  const u16t* src = vrow + ((size_t)b*2048 + kt*64)*128;
  #pragma unroll
  for(int it=0; it<4; ++it){
    int o = it*2048 + tid*8;
    int d = o >> 6, kg = o & 63;   // kg is a multiple of 8
    u16t tmp[8];
    #pragma unroll
    for(int j=0;j<8;j++) tmp[j] = src[(size_t)(kg+j)*128 + d];
    *(uint4*)&vtswz[((size_t)b*128 + d)*2048 + kt*64 + (kg ^ ((d&7)<<3))] = *(const uint4*)tmp;
  }
}

// ---------------- generic bf16 MFMA GEMM, 128x128 tile, BK=32, 4 waves ----------------
struct GemmArgs {
  const u16t* A; int lda;
  const u16t* Bg; const u16t* Ba;
  int K; int ntN; int mode; int amap; int omap; int ep;
  float* outf; u16t* outb; int ldo;
  const float* res;
};

__global__ __launch_bounds__(256) void gemm_k(GemmArgs g){
  __shared__ __align__(16) u16t As[2*128*32];
  __shared__ __align__(16) u16t Bs[2*128*32];
  int bid = blockIdx.x;
  int mt = bid / g.ntN, nt = bid % g.ntN;
  int c0 = mt*128, g0;
  const u16t* B;
  if(g.mode == 0){
    g0 = c0;
    B = ((mt & 15) < 14) ? g.Bg : g.Ba;   // t<1792 -> g weights
  } else if(g.mode == 1){                  // g-half compact rows: 14 tiles per batch
    int bb = mt/14, t = (mt - bb*14)*128;
    g0 = bb*2048 + t; B = g.Bg;
  } else {                                 // a-half compact rows: 2 tiles per batch
    int bb = mt>>1, t = 1792 + (mt&1)*128;
    g0 = bb*2048 + t; B = g.Bg;
  }
  int arow = g.amap ? g0 : c0;
  int orow = g.omap ? g0 : c0;
  int tid = threadIdx.x, lane = tid & 63, w = tid >> 6, l15 = lane & 15, lg = lane >> 4;
  int wr = w >> 1, wc = w & 1;

  int gsrc = ((tid&3) ^ ((tid>>3)&3))*8;
  const u16t* Ap = g.A + (size_t)(arow + (tid>>2))*g.lda + gsrc;
  const u16t* Bp = B   + (size_t)(nt*128 + (tid>>2))*g.K + gsrc;
  size_t lda64 = (size_t)64*g.lda, ldb64 = (size_t)64*g.K;
  u32t le = tid*8;

  int xr = (lg ^ ((l15>>1)&3))*8;
  int aoff[4], boff[4];
  #pragma unroll
  for(int mi=0;mi<4;mi++) aoff[mi] = (wr*64 + mi*16 + l15)*32 + xr;
  #pragma unroll
  for(int ni=0;ni<4;ni++) boff[ni] = (wc*64 + ni*16 + l15)*32 + xr;

  f4 acc[4][4];
  #pragma unroll
  for(int mi=0;mi<4;mi++)
    #pragma unroll
    for(int ni=0;ni<4;ni++){ f4 z = {0.0f,0.0f,0.0f,0.0f}; acc[mi][ni]=z; }

  auto stagef = [&](int buf, int k0){
    u16t* a = As + buf*4096;
    u16t* b = Bs + buf*4096;
    __builtin_amdgcn_global_load_lds((const AS1 u32t*)(Ap + k0),          (AS3 u32t*)&a[le],        16,0,0);
    __builtin_amdgcn_global_load_lds((const AS1 u32t*)(Ap + k0 + lda64),  (AS3 u32t*)&a[le + 2048], 16,0,0);
    __builtin_amdgcn_global_load_lds((const AS1 u32t*)(Bp + k0),          (AS3 u32t*)&b[le],        16,0,0);
    __builtin_amdgcn_global_load_lds((const AS1 u32t*)(Bp + k0 + ldb64),  (AS3 u32t*)&b[le + 2048], 16,0,0);
  };

  stagef(0, 0);
  __syncthreads();
  int cur = 0;
  for(int k0=0; k0 < g.K; k0 += 32){
    if(k0 + 32 < g.K) stagef(cur^1, k0+32);
    const u16t* as = As + cur*4096;
    const u16t* bs = Bs + cur*4096;
    s8b af[4], bf[4];
    #pragma unroll
    for(int mi=0;mi<4;mi++) af[mi] = *(const s8b*)&as[aoff[mi]];
    #pragma unroll
    for(int ni=0;ni<4;ni++) bf[ni] = *(const s8b*)&bs[boff[ni]];
    #pragma unroll
    for(int mi=0;mi<4;mi++)
      #pragma unroll
      for(int ni=0;ni<4;ni++)
        acc[mi][ni] = __builtin_amdgcn_mfma_f32_16x16x32_bf16(af[mi], bf[ni], acc[mi][ni], 0,0,0);
    __syncthreads();
    cur ^= 1;
  }

  #pragma unroll
  for(int mi=0;mi<4;mi++){
    #pragma unroll
    for(int ni=0;ni<4;ni++){
      int rowb = wr*64 + mi*16 + lg*4;
      int col = nt*128 + wc*64 + ni*16 + l15;
      #pragma unroll
      for(int r=0;r<4;r++){
        float v = acc[mi][ni][r];
        size_t ro = (size_t)(orow + rowb + r);
        if(g.ep == 0){
          g.outf[ro*(size_t)g.ldo + col] = v;
        } else if(g.ep == 1){
          g.outf[ro*(size_t)g.ldo + col] = v + g.res[ro*1024 + col];
        } else {
          float other = __shfl_xor(v, 1);
          if((lane & 1) == 0){
            g.outb[ro*(size_t)g.ldo + (col>>1)] = f2b(geluf(v)*other);
          }
        }
      }
    }
  }
}

// ---------------- 256x256 8-phase GEMM (T2+T3+T4+T5), gate-g specialized ----------------
// BM=BN=256, BK=64, 8 waves (2Mx4N), 512 thr, 128KB LDS (2 K-tile slots).
// Iter = 2 K-tiles, 8 phases; quadrants (mh,nh); reads consumed in-phase;
// 1 half-tile stage per phase; counted vmcnt(4) at phases 3/7 only (vmcnt(0) last iter).
// LDS granule swizzle: phys = logical ^ (row&7), inverse-swizzled global source.
__global__ __launch_bounds__(512, 2) void gemm256_k(const u16t* __restrict__ A,
                                                    const u16t* __restrict__ Bw,
                                                    u16t* __restrict__ outb){
  __shared__ __align__(16) u16t LDS[65536];   // A: slot*16384 ; B: 32768 + slot*16384
  int bid = blockIdx.x;
  int wg = (bid & 7)*112 + (bid >> 3);        // XCD swizzle, 896 blocks % 8 == 0
  int mt = wg >> 5, nt = wg & 31;             // 28 x 32 tiles
  int bb = mt / 7;
  int g0 = bb*2048 + (mt - bb*7)*256;         // A source rows (full index)
  int orow0 = mt*256;                          // output rows (compact)
  int tid = threadIdx.x, lane = tid & 63, w = tid >> 6, l15 = lane & 15, lg = lane >> 4;
  int wr = w >> 2, wc = w & 3;

  // staging: thread covers rows (tid>>3) + {0,64}; phys granule tid&7,
  // logical granule cg = (tid&7) ^ ((tid>>3)&7)
  int cg = ((tid&7) ^ ((tid>>3)&7))*8;
  const u16t* aSrc = A  + (size_t)(g0 + (tid>>3))*1024 + cg;
  const u16t* bSrc = Bw + (size_t)(nt*256 + (tid>>3))*1024 + cg;
  u16t* ldsA = &LDS[w*512 + (lane&63)*8];
  u16t* ldsB = &LDS[32768 + w*512 + (lane&63)*8];

  auto STAGE_A = [&](int kt, int uh){
    if(kt >= 16) return;
    const u16t* s0 = aSrc + (size_t)(uh*128)*1024 + kt*64;
    u16t* d = ldsA + (kt&1)*16384 + uh*8192;
    __builtin_amdgcn_global_load_lds((const AS1 u32t*)s0,            (AS3 u32t*)d,          16,0,0);
    __builtin_amdgcn_global_load_lds((const AS1 u32t*)(s0 + 65536),  (AS3 u32t*)(d + 4096), 16,0,0);
  };
  auto STAGE_B = [&](int kt, int uh){
    if(kt >= 16) return;
    const u16t* s0 = bSrc + (size_t)(uh*128)*1024 + kt*64;
    u16t* d = ldsB + (kt&1)*16384 + uh*8192;
    __builtin_amdgcn_global_load_lds((const AS1 u32t*)s0,            (AS3 u32t*)d,          16,0,0);
    __builtin_amdgcn_global_load_lds((const AS1 u32t*)(s0 + 65536),  (AS3 u32t*)(d + 4096), 16,0,0);
  };

  // fragment-read constants: row&7 == l15&7 for all frag rows
  int px0 = ((lg)     ^ (l15&7))*8;    // kk=0 phys granule offset (elems)
  int px1 = ((4 + lg) ^ (l15&7))*8;    // kk=1
  int aRow = (wr*128 + l15)*64;
  int bRow = (wc*64  + l15)*64;

  f4 acc[8][4];
  #pragma unroll
  for(int m=0;m<8;m++)
    #pragma unroll
    for(int n=0;n<4;n++){ f4 z = {0.0f,0.0f,0.0f,0.0f}; acc[m][n]=z; }
  s8b afr[4][2], bfr[4][2];

  auto READ_A = [&](int s, int mh){
    const u16t* base = &LDS[s*16384 + aRow + mh*4096];
    #pragma unroll
    for(int m=0;m<4;m++){
      afr[m][0] = *(const s8b*)(base + m*1024 + px0);
      afr[m][1] = *(const s8b*)(base + m*1024 + px1);
    }
  };
  auto READ_B = [&](int s, int nh){
    const u16t* base = &LDS[32768 + s*16384 + bRow + nh*2048];
    #pragma unroll
    for(int n=0;n<2;n++){
      bfr[nh*2+n][0] = *(const s8b*)(base + n*1024 + px0);
      bfr[nh*2+n][1] = *(const s8b*)(base + n*1024 + px1);
    }
  };

  #define MFMAQ(mh, nh)                                                              \
    __builtin_amdgcn_s_barrier();                                                    \
    asm volatile("s_waitcnt lgkmcnt(0)" ::: "memory");                               \
    __builtin_amdgcn_sched_barrier(0);                                               \
    __builtin_amdgcn_s_setprio(1);                                                   \
    _Pragma("unroll")                                                                \
    for(int m=0;m<4;m++)                                                             \
      _Pragma("unroll")                                                              \
      for(int n=0;n<2;n++)                                                           \
        _Pragma("unroll")                                                            \
        for(int kk=0;kk<2;kk++)                                                      \
          acc[(mh)*4+m][(nh)*2+n] = __builtin_amdgcn_mfma_f32_16x16x32_bf16(         \
              afr[m][kk], bfr[(nh)*2+n][kk], acc[(mh)*4+m][(nh)*2+n], 0,0,0);        \
    __builtin_amdgcn_s_setprio(0);                                                   \
    __builtin_amdgcn_sched_barrier(0);

  // prologue: tile0 all 4 units + tile1 A units -> 12 loads/thread; wait first 8
  STAGE_A(0,0); STAGE_A(0,1); STAGE_B(0,0); STAGE_B(0,1);
  STAGE_A(1,0); STAGE_A(1,1);
  asm volatile("s_waitcnt vmcnt(4)" ::: "memory");
  __builtin_amdgcn_s_barrier();

  for(int it2=0; it2<8; ++it2){
    int t = it2*2;
    // ph0: quadrant (0,0) of tile t (slot0)
    READ_B(0,0); READ_A(0,0); STAGE_B(t+1, 0);
    MFMAQ(0,0)
    __builtin_amdgcn_s_barrier();
    // ph1: (0,1)
    READ_B(0,1); STAGE_B(t+1, 1);
    MFMAQ(0,1)
    __builtin_amdgcn_s_barrier();
    // ph2: (1,0)
    READ_A(0,1); STAGE_A(t+2, 0);
    MFMAQ(1,0)
    __builtin_amdgcn_s_barrier();
    // ph3: (1,1) ; counted wait covers tile t+1
    STAGE_A(t+2, 1);
    MFMAQ(1,1)
    if(it2==7) asm volatile("s_waitcnt vmcnt(0)" ::: "memory");
    else       asm volatile("s_waitcnt vmcnt(4)" ::: "memory");
    __builtin_amdgcn_s_barrier();
    // ph4: quadrant (0,0) of tile t+1 (slot1)
    READ_B(1,0); READ_A(1,0); STAGE_B(t+2, 0);
    MFMAQ(0,0)
    __builtin_amdgcn_s_barrier();
    // ph5: (0,1)
    READ_B(1,1); STAGE_B(t+2, 1);
    MFMAQ(0,1)
    __builtin_amdgcn_s_barrier();
    // ph6: (1,0)
    READ_A(1,1); STAGE_A(t+3, 0);
    MFMAQ(1,0)
    __builtin_amdgcn_s_barrier();
    // ph7: (1,1) ; counted wait covers tile t+2
    STAGE_A(t+3, 1);
    MFMAQ(1,1)
    if(it2==7) asm volatile("s_waitcnt vmcnt(0)" ::: "memory");
    else       asm volatile("s_waitcnt vmcnt(4)" ::: "memory");
    __builtin_amdgcn_s_barrier();
  }
  #undef MFMAQ

  // epilogue: gelu-pair, bf16 out, compact rows, ldo = 4096
  #pragma unroll
  for(int mg=0;mg<8;mg++){
    #pragma unroll
    for(int n=0;n<4;n++){
      int rowb = wr*128 + mg*16 + lg*4;
      int col = nt*256 + wc*64 + n*16 + l15;
      #pragma unroll
      for(int r=0;r<4;r++){
        float v = acc[mg][n][r];
        float other = __shfl_xor(v, 1);
        if((lane & 1) == 0){
          size_t ro = (size_t)(orow0 + rowb + r);
          outb[ro*4096 + (col>>1)] = f2b(geluf(v)*other);
        }
      }
    }
  }
}

// ---------------- flash attention ----------------
__global__ __launch_bounds__(256) void attn_k(const u16t* __restrict__ qb, const u16t* __restrict__ kswz,
                                              const u16t* __restrict__ vtswz, u16t* __restrict__ attnb){
  __shared__ __align__(16) u16t Ks[64*128];
  __shared__ __align__(16) u16t Vt[128*64];
  __shared__ __align__(16) u16t Ps[4*16*72];
  int bid = blockIdx.x;
  int qt = bid & 31, n = (bid>>5)&7, b = bid>>8;
  int tid = threadIdx.x, lane = tid&63, w = tid>>6, l15 = lane&15, lg = lane>>4;
  int q0 = qt*64 + w*16;

  s8b qf[4];
  const u16t* qrow = qb + ((size_t)(b*2048 + q0 + l15)*8 + n)*128;
  #pragma unroll
  for(int kc=0;kc<4;kc++) qf[kc] = *(const s8b*)(qrow + kc*32 + lg*8);

  float lsum[4];
  f4 oacc[8];
  #pragma unroll
  for(int r=0;r<4;r++) lsum[r] = 0.0f;
  #pragma unroll
  for(int db=0;db<8;db++){ f4 z = {0.0f,0.0f,0.0f,0.0f}; oacc[db]=z; }

  const u16t* kbase  = kswz  + (size_t)b*2048*128;
  const u16t* vtbase = vtswz + (size_t)b*128*2048;
  u16t* psw = Ps + w*1152;

  for(int st=0; st<32; ++st){
    const u16t* kt  = kbase  + (size_t)st*64*128;
    const u16t* vtb = vtbase + st*64;
    __syncthreads();
    #pragma unroll
    for(int it=0; it<4; ++it){
      int e = it*2048 + tid*8;
      __builtin_amdgcn_global_load_lds((const AS1 u32t*)(kt + e), (AS3 u32t*)&Ks[e], 16,0,0);
    }
    #pragma unroll
    for(int it=0; it<4; ++it){
      int e = it*2048 + tid*8;
      int d = e >> 6, ko = e & 63;
      __builtin_amdgcn_global_load_lds((const AS1 u32t*)(vtb + (size_t)d*2048 + ko), (AS3 u32t*)&Vt[e], 16,0,0);
    }
    __syncthreads();

    f4 sf[4];
    #pragma unroll
    for(int kb=0;kb<4;kb++){ f4 z = {0.0f,0.0f,0.0f,0.0f}; sf[kb]=z; }
    #pragma unroll
    for(int kb=0;kb<4;kb++){
      int key = kb*16 + l15;
      int swz = ((key&7)<<3) ^ (((key>>3)&3)<<4);
      #pragma unroll
      for(int kc=0;kc<4;kc++){
        s8b kf = *(const s8b*)&Ks[key*128 + ((kc*32 + lg*8) ^ swz)];
        sf[kb] = __builtin_amdgcn_mfma_f32_16x16x32_bf16(qf[kc], kf, sf[kb], 0,0,0);
      }
    }
    #pragma unroll
    for(int r=0;r<4;r++){
      int prow = lg*4 + r;
      #pragma unroll
      for(int kb=0;kb<4;kb++){
        float pv = __expf(softcapf(sf[kb][r]));
        lsum[r] += pv;
        psw[prow*72 + kb*16 + l15] = f2b(pv);
      }
    }
    #pragma unroll
    for(int kc2=0;kc2<2;kc2++){
      s8b pa = *(const s8b*)&psw[l15*72 + kc2*32 + lg*8];
      int koff = (kc2*32 + lg*8) ^ ((l15&7)<<3);
      #pragma unroll
      for(int db=0;db<8;db++){
        s8b vf = *(const s8b*)&Vt[(db*16 + l15)*64 + koff];
        oacc[db] = __builtin_amdgcn_mfma_f32_16x16x32_bf16(pa, vf, oacc[db], 0,0,0);
      }
    }
  }

  float linv[4];
  #pragma unroll
  for(int r=0;r<4;r++){
    float s = lsum[r];
    #pragma unroll
    for(int off=1; off<16; off<<=1) s += __shfl_xor(s, off);
    linv[r] = 1.0f / s;
  }

  #pragma unroll
  for(int db=0;db<8;db++){
    #pragma unroll
    for(int r=0;r<4;r++){
      int qrowi = q0 + lg*4 + r;
      int d = db*16 + l15;
      attnb[(size_t)(b*2048 + qrowi)*1024 + n*128 + d] = f2b(oacc[db][r] * linv[r]);
    }
  }
}

// ---------------- host launch ----------------
extern "C" void kernel_launch(void* const* d_in, const int* in_sizes, int n_in,
                              void* d_out, int out_size, void* d_ws, size_t ws_size,
                              hipStream_t stream){
  const float* x        = (const float*)d_in[0];
  const float* pre_attn = (const float*)d_in[4];
  const float* pre_ffw  = (const float*)d_in[5];
  const float* g_qw  = (const float*)d_in[6];
  const float* g_kvw = (const float*)d_in[7];
  const float* g_ow  = (const float*)d_in[8];
  const float* a_qw  = (const float*)d_in[9];
  const float* a_kvw = (const float*)d_in[10];
  const float* a_ow  = (const float*)d_in[11];
  const float* g_gate= (const float*)d_in[12];
  const float* g_lin = (const float*)d_in[13];
  const float* a_gate= (const float*)d_in[14];
  const float* a_lin = (const float*)d_in[15];
  float* out = (float*)d_out;
  (void)in_sizes; (void)n_in; (void)out_size; (void)ws_size;

  char* wsp = (char*)d_ws; size_t off = 0;
  auto alloc = [&](size_t b){ void* p = wsp + off; off += (b + 255) & ~(size_t)255; return p; };
  u16t* wqkv_g = (u16t*)alloc((size_t)1280*1024*2);
  u16t* wqkv_a = (u16t*)alloc((size_t)1280*1024*2);
  u16t* wo_g   = (u16t*)alloc((size_t)1024*1024*2);
  u16t* wo_a   = (u16t*)alloc((size_t)1024*1024*2);
  u16t* wg_g   = (u16t*)alloc((size_t)8192*1024*2);
  u16t* wg_a   = (u16t*)alloc((size_t)4096*1024*2);
  u16t* wl_g   = (u16t*)alloc((size_t)1024*4096*2);
  u16t* wl_a   = (u16t*)alloc((size_t)1024*2048*2);
  u16t* xn     = (u16t*)alloc((size_t)8192*1024*2);
  u16t* xn2    = xn;
  char* big    = (char*)alloc((size_t)7168*4096*2);
  float* qkv   = (float*)big;
  float* t1    = (float*)big;
  u16t* hid_g  = (u16t*)big;
  u16t* qb     = (u16t*)alloc((size_t)8192*1024*2);
  u16t* kswz   = (u16t*)alloc((size_t)4*2048*128*2);
  u16t* vrow   = (u16t*)alloc((size_t)4*2048*128*2);
  u16t* vtswz  = (u16t*)alloc((size_t)4*128*2048*2);
  u16t* attnb  = (u16t*)alloc((size_t)8192*1024*2);
  u16t* hid_a  = (u16t*)alloc((size_t)1024*2048*2);

  tpack_k<<<dim3(4,32,8),256,0,stream>>>(wqkv_g, g_qw, 128, 1024, 1, 0, 128, 131072);
  tpack_k<<<dim3(4,32,1),256,0,stream>>>(wqkv_g, g_kvw, 128, 1024, 1, 1024, 0, 0);
  tpack_k<<<dim3(4,32,1),256,0,stream>>>(wqkv_g, g_kvw + 131072, 128, 1024, 1, 1152, 0, 0);
  tpack_k<<<dim3(4,32,8),256,0,stream>>>(wqkv_a, a_qw, 128, 1024, 1, 0, 128, 131072);
  tpack_k<<<dim3(4,32,1),256,0,stream>>>(wqkv_a, a_kvw, 128, 1024, 1, 1024, 0, 0);
  tpack_k<<<dim3(4,32,1),256,0,stream>>>(wqkv_a, a_kvw + 131072, 128, 1024, 1, 1152, 0, 0);
  tpack_k<<<dim3(32,32,1),256,0,stream>>>(wo_g, g_ow, 1024, 1024, 1, 0, 0, 0);
  tpack_k<<<dim3(32,32,1),256,0,stream>>>(wo_a, a_ow, 1024, 1024, 1, 0, 0, 0);
  tpack_k<<<dim3(128,32,2),256,0,stream>>>(wg_g, g_gate, 4096, 1024, 2, 0, 1, (size_t)1024*4096);
  tpack_k<<<dim3(64,32,2),256,0,stream>>>(wg_a, a_gate, 2048, 1024, 2, 0, 1, (size_t)1024*2048);
  tpack_k<<<dim3(32,128,1),256,0,stream>>>(wl_g, g_lin, 1024, 4096, 1, 0, 0, 0);
  tpack_k<<<dim3(32,64,1),256,0,stream>>>(wl_a, a_lin, 1024, 2048, 1, 0, 0, 0);

  rmsnorm_k<<<8192,256,0,stream>>>(x, pre_attn, xn);

  { GemmArgs ga = {xn, 1024, wqkv_g, wqkv_a, 1024, 10, 0,0,0, 0, qkv, nullptr, 1280, nullptr};
    gemm_k<<<64*10,256,0,stream>>>(ga); }
  rope_k<<<8192,256,0,stream>>>(qkv, qb, kswz, vrow);
  vt_pack_k<<<128,256,0,stream>>>(vrow, vtswz);
  attn_k<<<1024,256,0,stream>>>(qb, kswz, vtswz, attnb);
  { GemmArgs ga = {attnb, 1024, wo_g, wo_a, 1024, 8, 0,0,0, 1, t1, nullptr, 1024, x};
    gemm_k<<<64*8,256,0,stream>>>(ga); }
  rmsnorm_k<<<8192,256,0,stream>>>(t1, pre_ffw, xn2);
  // gate-g: 256x256 8-phase kernel (28 x 32 tiles)
  gemm256_k<<<896,512,0,stream>>>(xn2, wg_g, hid_g);
  { GemmArgs ga = {xn2, 1024, wg_a, nullptr, 1024, 32, 2,1,0, 3, nullptr, hid_a, 2048, nullptr};
    gemm_k<<<8*32,256,0,stream>>>(ga); }
  { GemmArgs ga = {hid_g, 4096, wl_g, nullptr, 4096, 8, 1,0,1, 1, out, nullptr, 1024, x};
    gemm_k<<<56*8,256,0,stream>>>(ga); }
  { GemmArgs ga = {hid_a, 2048, wl_a, nullptr, 2048, 8, 2,0,1, 1, out, nullptr, 1024, x};
    gemm_k<<<8*8,256,0,stream>>>(ga); }
}

// Round 8
// 818.953 us; speedup vs baseline: 1.4473x; 1.0661x over previous
//
#include <hip/hip_runtime.h>
#include <hip/hip_bf16.h>
#include <stdint.h>

typedef short s8b __attribute__((ext_vector_type(8)));
typedef float f4 __attribute__((ext_vector_type(4)));
typedef unsigned short u16t;
typedef unsigned int u32t;

#define AS1 __attribute__((address_space(1)))
#define AS3 __attribute__((address_space(3)))
#define DEVFN static __device__ __forceinline__

DEVFN u16t f2b(float f){ union{ __hip_bfloat16 h; u16t u; } c; c.h = __float2bfloat16(f); return c.u; }

DEVFN float geluf(float x){
  float t = 0.7978845608028654f*(x + 0.044715f*x*x*x);
  t = fminf(fmaxf(t, -15.0f), 15.0f);
  float e = __expf(2.0f*t);
  return 0.5f*x*(1.0f + (e-1.0f)*__builtin_amdgcn_rcpf(e+1.0f));
}
DEVFN float softcapf(float x){
  float t = fminf(fmaxf(x*0.02f, -15.0f), 15.0f);
  float e = __expf(2.0f*t);
  return 50.0f*(e-1.0f)*__builtin_amdgcn_rcpf(e+1.0f);
}

// ---------------- generic LDS-tiled transpose-pack (fp32 -> bf16) ----------------
__global__ __launch_bounds__(256) void tpack_k(u16t* __restrict__ dst, const float* __restrict__ src,
                                               int ldsrc, int lddst, int rmul, int roff, int prow,
                                               size_t pstride){
  __shared__ float tile[32][33];
  int z = blockIdx.z;
  const float* s = src + (size_t)z*pstride;
  int f0 = blockIdx.x*32, d0 = blockIdx.y*32;
  int t = threadIdx.x, r = t>>5, c = t&31;
  #pragma unroll
  for(int i=0;i<4;i++)
    tile[r + i*8][c] = s[(size_t)(d0 + r + i*8)*ldsrc + f0 + c];
  __syncthreads();
  int rbase = roff + z*prow;
  #pragma unroll
  for(int i=0;i<4;i++){
    int f = f0 + r + i*8;
    dst[(size_t)(f*rmul + rbase)*lddst + d0 + c] = f2b(tile[c][r + i*8]);
  }
}

// ---------------- RMSNorm (one block per row of 1024) ----------------
__global__ __launch_bounds__(256) void rmsnorm_k(const float* __restrict__ x, const float* __restrict__ sc,
                                                 u16t* __restrict__ out){
  int row = blockIdx.x;
  int tid = threadIdx.x;
  const float* xr = x + (size_t)row*1024;
  float4 v = *(const float4*)(xr + tid*4);
  float s = v.x*v.x + v.y*v.y + v.z*v.z + v.w*v.w;
  #pragma unroll
  for(int off=32; off>=1; off>>=1) s += __shfl_down(s, off);
  __shared__ float ws4[4];
  if((tid & 63) == 0) ws4[tid>>6] = s;
  __syncthreads();
  float tot = ws4[0]+ws4[1]+ws4[2]+ws4[3];
  float r = rsqrtf(tot*(1.0f/1024.0f) + 1e-6f);
  float4 scv = *(const float4*)(sc + tid*4);
  u16t o0 = f2b(v.x*r*(1.0f+scv.x)), o1 = f2b(v.y*r*(1.0f+scv.y));
  u16t o2 = f2b(v.z*r*(1.0f+scv.z)), o3 = f2b(v.w*r*(1.0f+scv.w));
  uint2 pk; pk.x = (u32t)o0 | ((u32t)o1<<16); pk.y = (u32t)o2 | ((u32t)o3<<16);
  *(uint2*)(out + (size_t)row*1024 + tid*4) = pk;
}

// ---------------- RoPE + convert; K stored pre-swizzled, V row-major ----------------
__global__ __launch_bounds__(256) void rope_k(const float* __restrict__ qkv, u16t* __restrict__ qb,
                                              u16t* __restrict__ kswz, u16t* __restrict__ vrow){
  int row = blockIdx.x;
  int b = row >> 11, t = row & 2047;
  float pos = (float)(t + (t >= 1792 ? 1 : 0));
  const float* src = qkv + (size_t)row*1280;
  size_t kvbase = ((size_t)b*2048 + t)*128;
  int swz = ((t&7)<<3) ^ (((t>>3)&3)<<4);
  for(int idx = threadIdx.x; idx < 704; idx += 256){
    if(idx < 512){
      int n = idx >> 6, i = idx & 63;
      float inv = exp2f((float)i * -0.20762050593046f); // 10000^{-i/64}
      float sn, cs; sincosf(pos*inv, &sn, &cs);
      float x1 = src[n*128+i], x2 = src[n*128+i+64];
      const float qs = 0.08838834764831845f; // 1/sqrt(128)
      qb[(size_t)row*1024 + n*128 + i]      = f2b((x1*cs - x2*sn)*qs);
      qb[(size_t)row*1024 + n*128 + i + 64] = f2b((x2*cs + x1*sn)*qs);
    } else if(idx < 576){
      int i = idx - 512;
      float inv = exp2f((float)i * -0.20762050593046f);
      float sn, cs; sincosf(pos*inv, &sn, &cs);
      float x1 = src[1024+i], x2 = src[1024+i+64];
      kswz[kvbase + (i ^ swz)]        = f2b(x1*cs - x2*sn);
      kswz[kvbase + ((i+64) ^ swz)]   = f2b(x2*cs + x1*sn);
    } else {
      int h = idx - 576;
      vrow[kvbase + h] = f2b(src[1152+h]);
    }
  }
}

// ---------------- V transpose pack: vrow[b][t][h] -> vtswz[b][d][key ^ ((d&7)<<3)] ----
__global__ __launch_bounds__(256) void vt_pack_k(const u16t* __restrict__ vrow, u16t* __restrict__ vtswz){
  int blk = blockIdx.x;            // b*32 + kt
  int b = blk >> 5, kt = blk & 31;
  int tid = threadIdx.x;
  const u16t* src = vrow + ((size_t)b*2048 + kt*64)*128;
  #pragma unroll
  for(int it=0; it<4; ++it){
    int o = it*2048 + tid*8;
    int d = o >> 6, kg = o & 63;   // kg is a multiple of 8
    u16t tmp[8];
    #pragma unroll
    for(int j=0;j<8;j++) tmp[j] = src[(size_t)(kg+j)*128 + d];
    *(uint4*)&vtswz[((size_t)b*128 + d)*2048 + kt*64 + (kg ^ ((d&7)<<3))] = *(const uint4*)tmp;
  }
}

// ---------------- generic bf16 MFMA GEMM, 128x128 tile, BK=32, 4 waves ----------------
struct GemmArgs {
  const u16t* A; int lda;
  const u16t* Bg; const u16t* Ba;
  int K; int ntN; int mode; int amap; int omap; int ep;
  float* outf; u16t* outb; int ldo;
  const float* res;
};

__global__ __launch_bounds__(256) void gemm_k(GemmArgs g){
  __shared__ __align__(16) u16t As[2*128*32];
  __shared__ __align__(16) u16t Bs[2*128*32];
  int bid = blockIdx.x;
  int mt = bid / g.ntN, nt = bid % g.ntN;
  int c0 = mt*128, g0;
  const u16t* B;
  if(g.mode == 0){
    g0 = c0;
    B = ((mt & 15) < 14) ? g.Bg : g.Ba;   // t<1792 -> g weights
  } else if(g.mode == 1){                  // g-half compact rows: 14 tiles per batch
    int bb = mt/14, t = (mt - bb*14)*128;
    g0 = bb*2048 + t; B = g.Bg;
  } else {                                 // a-half compact rows: 2 tiles per batch
    int bb = mt>>1, t = 1792 + (mt&1)*128;
    g0 = bb*2048 + t; B = g.Bg;
  }
  int arow = g.amap ? g0 : c0;
  int orow = g.omap ? g0 : c0;
  int tid = threadIdx.x, lane = tid & 63, w = tid >> 6, l15 = lane & 15, lg = lane >> 4;
  int wr = w >> 1, wc = w & 1;

  int gsrc = ((tid&3) ^ ((tid>>3)&3))*8;
  const u16t* Ap = g.A + (size_t)(arow + (tid>>2))*g.lda + gsrc;
  const u16t* Bp = B   + (size_t)(nt*128 + (tid>>2))*g.K + gsrc;
  size_t lda64 = (size_t)64*g.lda, ldb64 = (size_t)64*g.K;
  u32t le = tid*8;

  int xr = (lg ^ ((l15>>1)&3))*8;
  int aoff[4], boff[4];
  #pragma unroll
  for(int mi=0;mi<4;mi++) aoff[mi] = (wr*64 + mi*16 + l15)*32 + xr;
  #pragma unroll
  for(int ni=0;ni<4;ni++) boff[ni] = (wc*64 + ni*16 + l15)*32 + xr;

  f4 acc[4][4];
  #pragma unroll
  for(int mi=0;mi<4;mi++)
    #pragma unroll
    for(int ni=0;ni<4;ni++){ f4 z = {0.0f,0.0f,0.0f,0.0f}; acc[mi][ni]=z; }

  auto stagef = [&](int buf, int k0){
    u16t* a = As + buf*4096;
    u16t* b = Bs + buf*4096;
    __builtin_amdgcn_global_load_lds((const AS1 u32t*)(Ap + k0),          (AS3 u32t*)&a[le],        16,0,0);
    __builtin_amdgcn_global_load_lds((const AS1 u32t*)(Ap + k0 + lda64),  (AS3 u32t*)&a[le + 2048], 16,0,0);
    __builtin_amdgcn_global_load_lds((const AS1 u32t*)(Bp + k0),          (AS3 u32t*)&b[le],        16,0,0);
    __builtin_amdgcn_global_load_lds((const AS1 u32t*)(Bp + k0 + ldb64),  (AS3 u32t*)&b[le + 2048], 16,0,0);
  };

  stagef(0, 0);
  __syncthreads();
  int cur = 0;
  for(int k0=0; k0 < g.K; k0 += 32){
    if(k0 + 32 < g.K) stagef(cur^1, k0+32);
    const u16t* as = As + cur*4096;
    const u16t* bs = Bs + cur*4096;
    s8b af[4], bf[4];
    #pragma unroll
    for(int mi=0;mi<4;mi++) af[mi] = *(const s8b*)&as[aoff[mi]];
    #pragma unroll
    for(int ni=0;ni<4;ni++) bf[ni] = *(const s8b*)&bs[boff[ni]];
    #pragma unroll
    for(int mi=0;mi<4;mi++)
      #pragma unroll
      for(int ni=0;ni<4;ni++)
        acc[mi][ni] = __builtin_amdgcn_mfma_f32_16x16x32_bf16(af[mi], bf[ni], acc[mi][ni], 0,0,0);
    __syncthreads();
    cur ^= 1;
  }

  #pragma unroll
  for(int mi=0;mi<4;mi++){
    #pragma unroll
    for(int ni=0;ni<4;ni++){
      int rowb = wr*64 + mi*16 + lg*4;
      int col = nt*128 + wc*64 + ni*16 + l15;
      #pragma unroll
      for(int r=0;r<4;r++){
        float v = acc[mi][ni][r];
        size_t ro = (size_t)(orow + rowb + r);
        if(g.ep == 0){
          g.outf[ro*(size_t)g.ldo + col] = v;
        } else if(g.ep == 1){
          g.outf[ro*(size_t)g.ldo + col] = v + g.res[ro*1024 + col];
        } else {
          float other = __shfl_xor(v, 1);
          if((lane & 1) == 0){
            g.outb[ro*(size_t)g.ldo + (col>>1)] = f2b(geluf(v)*other);
          }
        }
      }
    }
  }
}

// ---------------- 256x256 8-phase GEMM (T2+T3+T4+T5), gate-g specialized ----------------
__global__ __launch_bounds__(512, 2) void gemm256_k(const u16t* __restrict__ A,
                                                    const u16t* __restrict__ Bw,
                                                    u16t* __restrict__ outb){
  __shared__ __align__(16) u16t LDS[65536];   // A: slot*16384 ; B: 32768 + slot*16384
  int bid = blockIdx.x;
  int wg = (bid & 7)*112 + (bid >> 3);        // XCD swizzle, 896 blocks % 8 == 0
  int mt = wg >> 5, nt = wg & 31;             // 28 x 32 tiles
  int bb = mt / 7;
  int g0 = bb*2048 + (mt - bb*7)*256;         // A source rows (full index)
  int orow0 = mt*256;                          // output rows (compact)
  int tid = threadIdx.x, lane = tid & 63, w = tid >> 6, l15 = lane & 15, lg = lane >> 4;
  int wr = w >> 2, wc = w & 3;

  int cg = ((tid&7) ^ ((tid>>3)&7))*8;
  const u16t* aSrc = A  + (size_t)(g0 + (tid>>3))*1024 + cg;
  const u16t* bSrc = Bw + (size_t)(nt*256 + (tid>>3))*1024 + cg;
  u16t* ldsA = &LDS[w*512 + (lane&63)*8];
  u16t* ldsB = &LDS[32768 + w*512 + (lane&63)*8];

  auto STAGE_A = [&](int kt, int uh){
    if(kt >= 16) return;
    const u16t* s0 = aSrc + (size_t)(uh*128)*1024 + kt*64;
    u16t* d = ldsA + (kt&1)*16384 + uh*8192;
    __builtin_amdgcn_global_load_lds((const AS1 u32t*)s0,            (AS3 u32t*)d,          16,0,0);
    __builtin_amdgcn_global_load_lds((const AS1 u32t*)(s0 + 65536),  (AS3 u32t*)(d + 4096), 16,0,0);
  };
  auto STAGE_B = [&](int kt, int uh){
    if(kt >= 16) return;
    const u16t* s0 = bSrc + (size_t)(uh*128)*1024 + kt*64;
    u16t* d = ldsB + (kt&1)*16384 + uh*8192;
    __builtin_amdgcn_global_load_lds((const AS1 u32t*)s0,            (AS3 u32t*)d,          16,0,0);
    __builtin_amdgcn_global_load_lds((const AS1 u32t*)(s0 + 65536),  (AS3 u32t*)(d + 4096), 16,0,0);
  };

  int px0 = ((lg)     ^ (l15&7))*8;    // kk=0 phys granule offset (elems)
  int px1 = ((4 + lg) ^ (l15&7))*8;    // kk=1
  int aRow = (wr*128 + l15)*64;
  int bRow = (wc*64  + l15)*64;

  f4 acc[8][4];
  #pragma unroll
  for(int m=0;m<8;m++)
    #pragma unroll
    for(int n=0;n<4;n++){ f4 z = {0.0f,0.0f,0.0f,0.0f}; acc[m][n]=z; }
  s8b afr[4][2], bfr[4][2];

  auto READ_A = [&](int s, int mh){
    const u16t* base = &LDS[s*16384 + aRow + mh*4096];
    #pragma unroll
    for(int m=0;m<4;m++){
      afr[m][0] = *(const s8b*)(base + m*1024 + px0);
      afr[m][1] = *(const s8b*)(base + m*1024 + px1);
    }
  };
  auto READ_B = [&](int s, int nh){
    const u16t* base = &LDS[32768 + s*16384 + bRow + nh*2048];
    #pragma unroll
    for(int n=0;n<2;n++){
      bfr[nh*2+n][0] = *(const s8b*)(base + n*1024 + px0);
      bfr[nh*2+n][1] = *(const s8b*)(base + n*1024 + px1);
    }
  };

  #define MFMAQ(mh, nh)                                                              \
    __builtin_amdgcn_s_barrier();                                                    \
    asm volatile("s_waitcnt lgkmcnt(0)" ::: "memory");                               \
    __builtin_amdgcn_sched_barrier(0);                                               \
    __builtin_amdgcn_s_setprio(1);                                                   \
    _Pragma("unroll")                                                                \
    for(int m=0;m<4;m++)                                                             \
      _Pragma("unroll")                                                              \
      for(int n=0;n<2;n++)                                                           \
        _Pragma("unroll")                                                            \
        for(int kk=0;kk<2;kk++)                                                      \
          acc[(mh)*4+m][(nh)*2+n] = __builtin_amdgcn_mfma_f32_16x16x32_bf16(         \
              afr[m][kk], bfr[(nh)*2+n][kk], acc[(mh)*4+m][(nh)*2+n], 0,0,0);        \
    __builtin_amdgcn_s_setprio(0);                                                   \
    __builtin_amdgcn_sched_barrier(0);

  STAGE_A(0,0); STAGE_A(0,1); STAGE_B(0,0); STAGE_B(0,1);
  STAGE_A(1,0); STAGE_A(1,1);
  asm volatile("s_waitcnt vmcnt(4)" ::: "memory");
  __builtin_amdgcn_s_barrier();

  for(int it2=0; it2<8; ++it2){
    int t = it2*2;
    READ_B(0,0); READ_A(0,0); STAGE_B(t+1, 0);
    MFMAQ(0,0)
    __builtin_amdgcn_s_barrier();
    READ_B(0,1); STAGE_B(t+1, 1);
    MFMAQ(0,1)
    __builtin_amdgcn_s_barrier();
    READ_A(0,1); STAGE_A(t+2, 0);
    MFMAQ(1,0)
    __builtin_amdgcn_s_barrier();
    STAGE_A(t+2, 1);
    MFMAQ(1,1)
    if(it2==7) asm volatile("s_waitcnt vmcnt(0)" ::: "memory");
    else       asm volatile("s_waitcnt vmcnt(4)" ::: "memory");
    __builtin_amdgcn_s_barrier();
    READ_B(1,0); READ_A(1,0); STAGE_B(t+2, 0);
    MFMAQ(0,0)
    __builtin_amdgcn_s_barrier();
    READ_B(1,1); STAGE_B(t+2, 1);
    MFMAQ(0,1)
    __builtin_amdgcn_s_barrier();
    READ_A(1,1); STAGE_A(t+3, 0);
    MFMAQ(1,0)
    __builtin_amdgcn_s_barrier();
    STAGE_A(t+3, 1);
    MFMAQ(1,1)
    if(it2==7) asm volatile("s_waitcnt vmcnt(0)" ::: "memory");
    else       asm volatile("s_waitcnt vmcnt(4)" ::: "memory");
    __builtin_amdgcn_s_barrier();
  }
  #undef MFMAQ

  #pragma unroll
  for(int mg=0;mg<8;mg++){
    #pragma unroll
    for(int n=0;n<4;n++){
      int rowb = wr*128 + mg*16 + lg*4;
      int col = nt*256 + wc*64 + n*16 + l15;
      #pragma unroll
      for(int r=0;r<4;r++){
        float v = acc[mg][n][r];
        float other = __shfl_xor(v, 1);
        if((lane & 1) == 0){
          size_t ro = (size_t)(orow0 + rowb + r);
          outb[ro*4096 + (col>>1)] = f2b(geluf(v)*other);
        }
      }
    }
  }
}

// ---------------- flash attention: double-buffered K/V staging (T3 minimum pattern) ----
__global__ __launch_bounds__(256) void attn_k(const u16t* __restrict__ qb, const u16t* __restrict__ kswz,
                                              const u16t* __restrict__ vtswz, u16t* __restrict__ attnb){
  __shared__ __align__(16) u16t Ks[2*64*128];   // [buf][key][h ^ swz(key)]
  __shared__ __align__(16) u16t Vt[2*128*64];   // [buf][d][key-granule ^ ((d&7)<<3)]
  __shared__ __align__(16) u16t Ps[4*16*72];
  int bid = blockIdx.x;
  int qt = bid & 31, n = (bid>>5)&7, b = bid>>8;
  int tid = threadIdx.x, lane = tid&63, w = tid>>6, l15 = lane&15, lg = lane>>4;
  int q0 = qt*64 + w*16;

  s8b qf[4];
  const u16t* qrow = qb + ((size_t)(b*2048 + q0 + l15)*8 + n)*128;
  #pragma unroll
  for(int kc=0;kc<4;kc++) qf[kc] = *(const s8b*)(qrow + kc*32 + lg*8);

  float lsum[4];
  f4 oacc[8];
  #pragma unroll
  for(int r=0;r<4;r++) lsum[r] = 0.0f;
  #pragma unroll
  for(int db=0;db<8;db++){ f4 z = {0.0f,0.0f,0.0f,0.0f}; oacc[db]=z; }

  const u16t* kbase  = kswz  + (size_t)b*2048*128;
  const u16t* vtbase = vtswz + (size_t)b*128*2048;
  u16t* psw = Ps + w*1152;

  auto stage = [&](int buf, int st){
    const u16t* kt  = kbase  + (size_t)st*64*128;
    const u16t* vtb = vtbase + st*64;
    u16t* kd = Ks + buf*8192;
    u16t* vd = Vt + buf*8192;
    #pragma unroll
    for(int it=0; it<4; ++it){
      int e = it*2048 + tid*8;
      __builtin_amdgcn_global_load_lds((const AS1 u32t*)(kt + e), (AS3 u32t*)&kd[e], 16,0,0);
    }
    #pragma unroll
    for(int it=0; it<4; ++it){
      int e = it*2048 + tid*8;
      int d = e >> 6, ko = e & 63;
      __builtin_amdgcn_global_load_lds((const AS1 u32t*)(vtb + (size_t)d*2048 + ko), (AS3 u32t*)&vd[e], 16,0,0);
    }
  };

  stage(0, 0);
  __syncthreads();
  int cur = 0;
  for(int st=0; st<32; ++st){
    if(st < 31) stage(cur^1, st+1);   // in flight during compute; drained by end barrier
    const u16t* ks = Ks + cur*8192;
    const u16t* vs = Vt + cur*8192;

    // ---- QK^T ----
    f4 sf[4];
    #pragma unroll
    for(int kb=0;kb<4;kb++){ f4 z = {0.0f,0.0f,0.0f,0.0f}; sf[kb]=z; }
    #pragma unroll
    for(int kb=0;kb<4;kb++){
      int key = kb*16 + l15;
      int swz = ((key&7)<<3) ^ (((key>>3)&3)<<4);
      #pragma unroll
      for(int kc=0;kc<4;kc++){
        s8b kf = *(const s8b*)&ks[key*128 + ((kc*32 + lg*8) ^ swz)];
        sf[kb] = __builtin_amdgcn_mfma_f32_16x16x32_bf16(qf[kc], kf, sf[kb], 0,0,0);
      }
    }
    // ---- softcap + exp (static-max softmax), per-lane lsum ----
    #pragma unroll
    for(int r=0;r<4;r++){
      int prow = lg*4 + r;
      #pragma unroll
      for(int kb=0;kb<4;kb++){
        float pv = __expf(softcapf(sf[kb][r]));
        lsum[r] += pv;
        psw[prow*72 + kb*16 + l15] = f2b(pv);
      }
    }
    // ---- PV ----
    #pragma unroll
    for(int kc2=0;kc2<2;kc2++){
      s8b pa = *(const s8b*)&psw[l15*72 + kc2*32 + lg*8];
      int koff = (kc2*32 + lg*8) ^ ((l15&7)<<3);
      #pragma unroll
      for(int db=0;db<8;db++){
        s8b vf = *(const s8b*)&vs[(db*16 + l15)*64 + koff];
        oacc[db] = __builtin_amdgcn_mfma_f32_16x16x32_bf16(pa, vf, oacc[db], 0,0,0);
      }
    }
    __syncthreads();
    cur ^= 1;
  }

  float linv[4];
  #pragma unroll
  for(int r=0;r<4;r++){
    float s = lsum[r];
    #pragma unroll
    for(int off=1; off<16; off<<=1) s += __shfl_xor(s, off);
    linv[r] = 1.0f / s;
  }

  #pragma unroll
  for(int db=0;db<8;db++){
    #pragma unroll
    for(int r=0;r<4;r++){
      int qrowi = q0 + lg*4 + r;
      int d = db*16 + l15;
      attnb[(size_t)(b*2048 + qrowi)*1024 + n*128 + d] = f2b(oacc[db][r] * linv[r]);
    }
  }
}

// ---------------- host launch ----------------
extern "C" void kernel_launch(void* const* d_in, const int* in_sizes, int n_in,
                              void* d_out, int out_size, void* d_ws, size_t ws_size,
                              hipStream_t stream){
  const float* x        = (const float*)d_in[0];
  const float* pre_attn = (const float*)d_in[4];
  const float* pre_ffw  = (const float*)d_in[5];
  const float* g_qw  = (const float*)d_in[6];
  const float* g_kvw = (const float*)d_in[7];
  const float* g_ow  = (const float*)d_in[8];
  const float* a_qw  = (const float*)d_in[9];
  const float* a_kvw = (const float*)d_in[10];
  const float* a_ow  = (const float*)d_in[11];
  const float* g_gate= (const float*)d_in[12];
  const float* g_lin = (const float*)d_in[13];
  const float* a_gate= (const float*)d_in[14];
  const float* a_lin = (const float*)d_in[15];
  float* out = (float*)d_out;
  (void)in_sizes; (void)n_in; (void)out_size; (void)ws_size;

  char* wsp = (char*)d_ws; size_t off = 0;
  auto alloc = [&](size_t b){ void* p = wsp + off; off += (b + 255) & ~(size_t)255; return p; };
  u16t* wqkv_g = (u16t*)alloc((size_t)1280*1024*2);
  u16t* wqkv_a = (u16t*)alloc((size_t)1280*1024*2);
  u16t* wo_g   = (u16t*)alloc((size_t)1024*1024*2);
  u16t* wo_a   = (u16t*)alloc((size_t)1024*1024*2);
  u16t* wg_g   = (u16t*)alloc((size_t)8192*1024*2);
  u16t* wg_a   = (u16t*)alloc((size_t)4096*1024*2);
  u16t* wl_g   = (u16t*)alloc((size_t)1024*4096*2);
  u16t* wl_a   = (u16t*)alloc((size_t)1024*2048*2);
  u16t* xn     = (u16t*)alloc((size_t)8192*1024*2);
  u16t* xn2    = xn;
  char* big    = (char*)alloc((size_t)7168*4096*2);
  float* qkv   = (float*)big;
  float* t1    = (float*)big;
  u16t* hid_g  = (u16t*)big;
  u16t* qb     = (u16t*)alloc((size_t)8192*1024*2);
  u16t* kswz   = (u16t*)alloc((size_t)4*2048*128*2);
  u16t* vrow   = (u16t*)alloc((size_t)4*2048*128*2);
  u16t* vtswz  = (u16t*)alloc((size_t)4*128*2048*2);
  u16t* attnb  = (u16t*)alloc((size_t)8192*1024*2);
  u16t* hid_a  = (u16t*)alloc((size_t)1024*2048*2);

  tpack_k<<<dim3(4,32,8),256,0,stream>>>(wqkv_g, g_qw, 128, 1024, 1, 0, 128, 131072);
  tpack_k<<<dim3(4,32,1),256,0,stream>>>(wqkv_g, g_kvw, 128, 1024, 1, 1024, 0, 0);
  tpack_k<<<dim3(4,32,1),256,0,stream>>>(wqkv_g, g_kvw + 131072, 128, 1024, 1, 1152, 0, 0);
  tpack_k<<<dim3(4,32,8),256,0,stream>>>(wqkv_a, a_qw, 128, 1024, 1, 0, 128, 131072);
  tpack_k<<<dim3(4,32,1),256,0,stream>>>(wqkv_a, a_kvw, 128, 1024, 1, 1024, 0, 0);
  tpack_k<<<dim3(4,32,1),256,0,stream>>>(wqkv_a, a_kvw + 131072, 128, 1024, 1, 1152, 0, 0);
  tpack_k<<<dim3(32,32,1),256,0,stream>>>(wo_g, g_ow, 1024, 1024, 1, 0, 0, 0);
  tpack_k<<<dim3(32,32,1),256,0,stream>>>(wo_a, a_ow, 1024, 1024, 1, 0, 0, 0);
  tpack_k<<<dim3(128,32,2),256,0,stream>>>(wg_g, g_gate, 4096, 1024, 2, 0, 1, (size_t)1024*4096);
  tpack_k<<<dim3(64,32,2),256,0,stream>>>(wg_a, a_gate, 2048, 1024, 2, 0, 1, (size_t)1024*2048);
  tpack_k<<<dim3(32,128,1),256,0,stream>>>(wl_g, g_lin, 1024, 4096, 1, 0, 0, 0);
  tpack_k<<<dim3(32,64,1),256,0,stream>>>(wl_a, a_lin, 1024, 2048, 1, 0, 0, 0);

  rmsnorm_k<<<8192,256,0,stream>>>(x, pre_attn, xn);

  { GemmArgs ga = {xn, 1024, wqkv_g, wqkv_a, 1024, 10, 0,0,0, 0, qkv, nullptr, 1280, nullptr};
    gemm_k<<<64*10,256,0,stream>>>(ga); }
  rope_k<<<8192,256,0,stream>>>(qkv, qb, kswz, vrow);
  vt_pack_k<<<128,256,0,stream>>>(vrow, vtswz);
  attn_k<<<1024,256,0,stream>>>(qb, kswz, vtswz, attnb);
  { GemmArgs ga = {attnb, 1024, wo_g, wo_a, 1024, 8, 0,0,0, 1, t1, nullptr, 1024, x};
    gemm_k<<<64*8,256,0,stream>>>(ga); }
  rmsnorm_k<<<8192,256,0,stream>>>(t1, pre_ffw, xn2);
  gemm256_k<<<896,512,0,stream>>>(xn2, wg_g, hid_g);
  { GemmArgs ga = {xn2, 1024, wg_a, nullptr, 1024, 32, 2,1,0, 3, nullptr, hid_a, 2048, nullptr};
    gemm_k<<<8*32,256,0,stream>>>(ga); }
  { GemmArgs ga = {hid_g, 4096, wl_g, nullptr, 4096, 8, 1,0,1, 1, out, nullptr, 1024, x};
    gemm_k<<<56*8,256,0,stream>>>(ga); }
  { GemmArgs ga = {hid_a, 2048, wl_a, nullptr, 2048, 8, 2,0,1, 1, out, nullptr, 1024, x};
    gemm_k<<<8*8,256,0,stream>>>(ga); }
}

// Round 9
// 813.211 us; speedup vs baseline: 1.4575x; 1.0071x over previous
//
#include <hip/hip_runtime.h>
#include <hip/hip_bf16.h>
#include <stdint.h>

typedef short s8b __attribute__((ext_vector_type(8)));
typedef float f4 __attribute__((ext_vector_type(4)));
typedef unsigned short u16t;
typedef unsigned int u32t;

#define AS1 __attribute__((address_space(1)))
#define AS3 __attribute__((address_space(3)))
#define DEVFN static __device__ __forceinline__

DEVFN u16t f2b(float f){ union{ __hip_bfloat16 h; u16t u; } c; c.h = __float2bfloat16(f); return c.u; }

DEVFN float geluf(float x){
  float t = 0.7978845608028654f*(x + 0.044715f*x*x*x);
  t = fminf(fmaxf(t, -15.0f), 15.0f);
  float e = __expf(2.0f*t);
  return 0.5f*x*(1.0f + (e-1.0f)*__builtin_amdgcn_rcpf(e+1.0f));
}
DEVFN float softcapf(float x){
  float t = fminf(fmaxf(x*0.02f, -15.0f), 15.0f);
  float e = __expf(2.0f*t);
  return 50.0f*(e-1.0f)*__builtin_amdgcn_rcpf(e+1.0f);
}

// ---------------- generic LDS-tiled transpose-pack (fp32 -> bf16) ----------------
__global__ __launch_bounds__(256) void tpack_k(u16t* __restrict__ dst, const float* __restrict__ src,
                                               int ldsrc, int lddst, int rmul, int roff, int prow,
                                               size_t pstride){
  __shared__ float tile[32][33];
  int z = blockIdx.z;
  const float* s = src + (size_t)z*pstride;
  int f0 = blockIdx.x*32, d0 = blockIdx.y*32;
  int t = threadIdx.x, r = t>>5, c = t&31;
  #pragma unroll
  for(int i=0;i<4;i++)
    tile[r + i*8][c] = s[(size_t)(d0 + r + i*8)*ldsrc + f0 + c];
  __syncthreads();
  int rbase = roff + z*prow;
  #pragma unroll
  for(int i=0;i<4;i++){
    int f = f0 + r + i*8;
    dst[(size_t)(f*rmul + rbase)*lddst + d0 + c] = f2b(tile[c][r + i*8]);
  }
}

// ---------------- RMSNorm (one block per row of 1024) ----------------
__global__ __launch_bounds__(256) void rmsnorm_k(const float* __restrict__ x, const float* __restrict__ sc,
                                                 u16t* __restrict__ out){
  int row = blockIdx.x;
  int tid = threadIdx.x;
  const float* xr = x + (size_t)row*1024;
  float4 v = *(const float4*)(xr + tid*4);
  float s = v.x*v.x + v.y*v.y + v.z*v.z + v.w*v.w;
  #pragma unroll
  for(int off=32; off>=1; off>>=1) s += __shfl_down(s, off);
  __shared__ float ws4[4];
  if((tid & 63) == 0) ws4[tid>>6] = s;
  __syncthreads();
  float tot = ws4[0]+ws4[1]+ws4[2]+ws4[3];
  float r = rsqrtf(tot*(1.0f/1024.0f) + 1e-6f);
  float4 scv = *(const float4*)(sc + tid*4);
  u16t o0 = f2b(v.x*r*(1.0f+scv.x)), o1 = f2b(v.y*r*(1.0f+scv.y));
  u16t o2 = f2b(v.z*r*(1.0f+scv.z)), o3 = f2b(v.w*r*(1.0f+scv.w));
  uint2 pk; pk.x = (u32t)o0 | ((u32t)o1<<16); pk.y = (u32t)o2 | ((u32t)o3<<16);
  *(uint2*)(out + (size_t)row*1024 + tid*4) = pk;
}

// ---------------- RoPE + convert; K stored pre-swizzled, V row-major ----------------
__global__ __launch_bounds__(256) void rope_k(const float* __restrict__ qkv, u16t* __restrict__ qb,
                                              u16t* __restrict__ kswz, u16t* __restrict__ vrow){
  int row = blockIdx.x;
  int b = row >> 11, t = row & 2047;
  float pos = (float)(t + (t >= 1792 ? 1 : 0));
  const float* src = qkv + (size_t)row*1280;
  size_t kvbase = ((size_t)b*2048 + t)*128;
  int swz = ((t&7)<<3) ^ (((t>>3)&3)<<4);
  for(int idx = threadIdx.x; idx < 704; idx += 256){
    if(idx < 512){
      int n = idx >> 6, i = idx & 63;
      float inv = exp2f((float)i * -0.20762050593046f); // 10000^{-i/64}
      float sn, cs; sincosf(pos*inv, &sn, &cs);
      float x1 = src[n*128+i], x2 = src[n*128+i+64];
      const float qs = 0.08838834764831845f; // 1/sqrt(128)
      qb[(size_t)row*1024 + n*128 + i]      = f2b((x1*cs - x2*sn)*qs);
      qb[(size_t)row*1024 + n*128 + i + 64] = f2b((x2*cs + x1*sn)*qs);
    } else if(idx < 576){
      int i = idx - 512;
      float inv = exp2f((float)i * -0.20762050593046f);
      float sn, cs; sincosf(pos*inv, &sn, &cs);
      float x1 = src[1024+i], x2 = src[1024+i+64];
      kswz[kvbase + (i ^ swz)]        = f2b(x1*cs - x2*sn);
      kswz[kvbase + ((i+64) ^ swz)]   = f2b(x2*cs + x1*sn);
    } else {
      int h = idx - 576;
      vrow[kvbase + h] = f2b(src[1152+h]);
    }
  }
}

// ---------------- V transpose pack: vrow[b][t][h] -> vtswz[b][d][key ^ ((d&7)<<3)] ----
__global__ __launch_bounds__(256) void vt_pack_k(const u16t* __restrict__ vrow, u16t* __restrict__ vtswz){
  int blk = blockIdx.x;            // b*32 + kt
  int b = blk >> 5, kt = blk & 31;
  int tid = threadIdx.x;
  const u16t* src = vrow + ((size_t)b*2048 + kt*64)*128;
  #pragma unroll
  for(int it=0; it<4; ++it){
    int o = it*2048 + tid*8;
    int d = o >> 6, kg = o & 63;   // kg is a multiple of 8
    u16t tmp[8];
    #pragma unroll
    for(int j=0;j<8;j++) tmp[j] = src[(size_t)(kg+j)*128 + d];
    *(uint4*)&vtswz[((size_t)b*128 + d)*2048 + kt*64 + (kg ^ ((d&7)<<3))] = *(const uint4*)tmp;
  }
}

// ---------------- generic bf16 MFMA GEMM, 128x128 tile, BK=32, 4 waves ----------------
struct GemmArgs {
  const u16t* A; int lda;
  const u16t* Bg; const u16t* Ba;
  int K; int ntN; int mode; int amap; int omap; int ep;
  float* outf; u16t* outb; int ldo;
  const float* res;
};

__global__ __launch_bounds__(256) void gemm_k(GemmArgs g){
  __shared__ __align__(16) u16t As[2*128*32];
  __shared__ __align__(16) u16t Bs[2*128*32];
  int bid = blockIdx.x;
  int mt = bid / g.ntN, nt = bid % g.ntN;
  int c0 = mt*128, g0;
  const u16t* B;
  if(g.mode == 0){
    g0 = c0;
    B = ((mt & 15) < 14) ? g.Bg : g.Ba;   // t<1792 -> g weights
  } else if(g.mode == 1){                  // g-half compact rows: 14 tiles per batch
    int bb = mt/14, t = (mt - bb*14)*128;
    g0 = bb*2048 + t; B = g.Bg;
  } else {                                 // a-half compact rows: 2 tiles per batch
    int bb = mt>>1, t = 1792 + (mt&1)*128;
    g0 = bb*2048 + t; B = g.Bg;
  }
  int arow = g.amap ? g0 : c0;
  int orow = g.omap ? g0 : c0;
  int tid = threadIdx.x, lane = tid & 63, w = tid >> 6, l15 = lane & 15, lg = lane >> 4;
  int wr = w >> 1, wc = w & 1;

  int gsrc = ((tid&3) ^ ((tid>>3)&3))*8;
  const u16t* Ap = g.A + (size_t)(arow + (tid>>2))*g.lda + gsrc;
  const u16t* Bp = B   + (size_t)(nt*128 + (tid>>2))*g.K + gsrc;
  size_t lda64 = (size_t)64*g.lda, ldb64 = (size_t)64*g.K;
  u32t le = tid*8;

  int xr = (lg ^ ((l15>>1)&3))*8;
  int aoff[4], boff[4];
  #pragma unroll
  for(int mi=0;mi<4;mi++) aoff[mi] = (wr*64 + mi*16 + l15)*32 + xr;
  #pragma unroll
  for(int ni=0;ni<4;ni++) boff[ni] = (wc*64 + ni*16 + l15)*32 + xr;

  f4 acc[4][4];
  #pragma unroll
  for(int mi=0;mi<4;mi++)
    #pragma unroll
    for(int ni=0;ni<4;ni++){ f4 z = {0.0f,0.0f,0.0f,0.0f}; acc[mi][ni]=z; }

  auto stagef = [&](int buf, int k0){
    u16t* a = As + buf*4096;
    u16t* b = Bs + buf*4096;
    __builtin_amdgcn_global_load_lds((const AS1 u32t*)(Ap + k0),          (AS3 u32t*)&a[le],        16,0,0);
    __builtin_amdgcn_global_load_lds((const AS1 u32t*)(Ap + k0 + lda64),  (AS3 u32t*)&a[le + 2048], 16,0,0);
    __builtin_amdgcn_global_load_lds((const AS1 u32t*)(Bp + k0),          (AS3 u32t*)&b[le],        16,0,0);
    __builtin_amdgcn_global_load_lds((const AS1 u32t*)(Bp + k0 + ldb64),  (AS3 u32t*)&b[le + 2048], 16,0,0);
  };

  stagef(0, 0);
  __syncthreads();
  int cur = 0;
  for(int k0=0; k0 < g.K; k0 += 32){
    if(k0 + 32 < g.K) stagef(cur^1, k0+32);
    const u16t* as = As + cur*4096;
    const u16t* bs = Bs + cur*4096;
    s8b af[4], bf[4];
    #pragma unroll
    for(int mi=0;mi<4;mi++) af[mi] = *(const s8b*)&as[aoff[mi]];
    #pragma unroll
    for(int ni=0;ni<4;ni++) bf[ni] = *(const s8b*)&bs[boff[ni]];
    #pragma unroll
    for(int mi=0;mi<4;mi++)
      #pragma unroll
      for(int ni=0;ni<4;ni++)
        acc[mi][ni] = __builtin_amdgcn_mfma_f32_16x16x32_bf16(af[mi], bf[ni], acc[mi][ni], 0,0,0);
    __syncthreads();
    cur ^= 1;
  }

  #pragma unroll
  for(int mi=0;mi<4;mi++){
    #pragma unroll
    for(int ni=0;ni<4;ni++){
      int rowb = wr*64 + mi*16 + lg*4;
      int col = nt*128 + wc*64 + ni*16 + l15;
      #pragma unroll
      for(int r=0;r<4;r++){
        float v = acc[mi][ni][r];
        size_t ro = (size_t)(orow + rowb + r);
        if(g.ep == 0){
          g.outf[ro*(size_t)g.ldo + col] = v;
        } else if(g.ep == 1){
          g.outf[ro*(size_t)g.ldo + col] = v + g.res[ro*1024 + col];
        } else {
          float other = __shfl_xor(v, 1);
          if((lane & 1) == 0){
            g.outb[ro*(size_t)g.ldo + (col>>1)] = f2b(geluf(v)*other);
          }
        }
      }
    }
  }
}

// ---------------- 256x256 8-phase GEMM (T2+T3+T4+T5), gate-g specialized ----------------
// L2-aware mapping: XCD k (= bid&7) owns nt in [4k,4k+4); mt walks the inner dim.
// Concurrent ~32 blocks/XCD cover an 8mt x 4nt window: 4MB A (streamed) + 2MB B (hot).
__global__ __launch_bounds__(512, 2) void gemm256_k(const u16t* __restrict__ A,
                                                    const u16t* __restrict__ Bw,
                                                    u16t* __restrict__ outb){
  __shared__ __align__(16) u16t LDS[65536];   // A: slot*16384 ; B: 32768 + slot*16384
  int bid = blockIdx.x;
  int j = bid >> 3;
  int nt = (bid & 7)*4 + (j & 3);             // XCD-owned B column group
  int mt = j >> 2;                            // 28 x 32 tiles
  int bb = mt / 7;
  int g0 = bb*2048 + (mt - bb*7)*256;         // A source rows (full index)
  int orow0 = mt*256;                          // output rows (compact)
  int tid = threadIdx.x, lane = tid & 63, w = tid >> 6, l15 = lane & 15, lg = lane >> 4;
  int wr = w >> 2, wc = w & 3;

  int cg = ((tid&7) ^ ((tid>>3)&7))*8;
  const u16t* aSrc = A  + (size_t)(g0 + (tid>>3))*1024 + cg;
  const u16t* bSrc = Bw + (size_t)(nt*256 + (tid>>3))*1024 + cg;
  u16t* ldsA = &LDS[w*512 + (lane&63)*8];
  u16t* ldsB = &LDS[32768 + w*512 + (lane&63)*8];

  auto STAGE_A = [&](int kt, int uh){
    if(kt >= 16) return;
    const u16t* s0 = aSrc + (size_t)(uh*128)*1024 + kt*64;
    u16t* d = ldsA + (kt&1)*16384 + uh*8192;
    __builtin_amdgcn_global_load_lds((const AS1 u32t*)s0,            (AS3 u32t*)d,          16,0,0);
    __builtin_amdgcn_global_load_lds((const AS1 u32t*)(s0 + 65536),  (AS3 u32t*)(d + 4096), 16,0,0);
  };
  auto STAGE_B = [&](int kt, int uh){
    if(kt >= 16) return;
    const u16t* s0 = bSrc + (size_t)(uh*128)*1024 + kt*64;
    u16t* d = ldsB + (kt&1)*16384 + uh*8192;
    __builtin_amdgcn_global_load_lds((const AS1 u32t*)s0,            (AS3 u32t*)d,          16,0,0);
    __builtin_amdgcn_global_load_lds((const AS1 u32t*)(s0 + 65536),  (AS3 u32t*)(d + 4096), 16,0,0);
  };

  int px0 = ((lg)     ^ (l15&7))*8;    // kk=0 phys granule offset (elems)
  int px1 = ((4 + lg) ^ (l15&7))*8;    // kk=1
  int aRow = (wr*128 + l15)*64;
  int bRow = (wc*64  + l15)*64;

  f4 acc[8][4];
  #pragma unroll
  for(int m=0;m<8;m++)
    #pragma unroll
    for(int n=0;n<4;n++){ f4 z = {0.0f,0.0f,0.0f,0.0f}; acc[m][n]=z; }
  s8b afr[4][2], bfr[4][2];

  auto READ_A = [&](int s, int mh){
    const u16t* base = &LDS[s*16384 + aRow + mh*4096];
    #pragma unroll
    for(int m=0;m<4;m++){
      afr[m][0] = *(const s8b*)(base + m*1024 + px0);
      afr[m][1] = *(const s8b*)(base + m*1024 + px1);
    }
  };
  auto READ_B = [&](int s, int nh){
    const u16t* base = &LDS[32768 + s*16384 + bRow + nh*2048];
    #pragma unroll
    for(int n=0;n<2;n++){
      bfr[nh*2+n][0] = *(const s8b*)(base + n*1024 + px0);
      bfr[nh*2+n][1] = *(const s8b*)(base + n*1024 + px1);
    }
  };

  #define MFMAQ(mh, nh)                                                              \
    __builtin_amdgcn_s_barrier();                                                    \
    asm volatile("s_waitcnt lgkmcnt(0)" ::: "memory");                               \
    __builtin_amdgcn_sched_barrier(0);                                               \
    __builtin_amdgcn_s_setprio(1);                                                   \
    _Pragma("unroll")                                                                \
    for(int m=0;m<4;m++)                                                             \
      _Pragma("unroll")                                                              \
      for(int n=0;n<2;n++)                                                           \
        _Pragma("unroll")                                                            \
        for(int kk=0;kk<2;kk++)                                                      \
          acc[(mh)*4+m][(nh)*2+n] = __builtin_amdgcn_mfma_f32_16x16x32_bf16(         \
              afr[m][kk], bfr[(nh)*2+n][kk], acc[(mh)*4+m][(nh)*2+n], 0,0,0);        \
    __builtin_amdgcn_s_setprio(0);                                                   \
    __builtin_amdgcn_sched_barrier(0);

  STAGE_A(0,0); STAGE_A(0,1); STAGE_B(0,0); STAGE_B(0,1);
  STAGE_A(1,0); STAGE_A(1,1);
  asm volatile("s_waitcnt vmcnt(4)" ::: "memory");
  __builtin_amdgcn_s_barrier();

  for(int it2=0; it2<8; ++it2){
    int t = it2*2;
    READ_B(0,0); READ_A(0,0); STAGE_B(t+1, 0);
    MFMAQ(0,0)
    __builtin_amdgcn_s_barrier();
    READ_B(0,1); STAGE_B(t+1, 1);
    MFMAQ(0,1)
    __builtin_amdgcn_s_barrier();
    READ_A(0,1); STAGE_A(t+2, 0);
    MFMAQ(1,0)
    __builtin_amdgcn_s_barrier();
    STAGE_A(t+2, 1);
    MFMAQ(1,1)
    if(it2==7) asm volatile("s_waitcnt vmcnt(0)" ::: "memory");
    else       asm volatile("s_waitcnt vmcnt(4)" ::: "memory");
    __builtin_amdgcn_s_barrier();
    READ_B(1,0); READ_A(1,0); STAGE_B(t+2, 0);
    MFMAQ(0,0)
    __builtin_amdgcn_s_barrier();
    READ_B(1,1); STAGE_B(t+2, 1);
    MFMAQ(0,1)
    __builtin_amdgcn_s_barrier();
    READ_A(1,1); STAGE_A(t+3, 0);
    MFMAQ(1,0)
    __builtin_amdgcn_s_barrier();
    STAGE_A(t+3, 1);
    MFMAQ(1,1)
    if(it2==7) asm volatile("s_waitcnt vmcnt(0)" ::: "memory");
    else       asm volatile("s_waitcnt vmcnt(4)" ::: "memory");
    __builtin_amdgcn_s_barrier();
  }
  #undef MFMAQ

  #pragma unroll
  for(int mg=0;mg<8;mg++){
    #pragma unroll
    for(int n=0;n<4;n++){
      int rowb = wr*128 + mg*16 + lg*4;
      int col = nt*256 + wc*64 + n*16 + l15;
      #pragma unroll
      for(int r=0;r<4;r++){
        float v = acc[mg][n][r];
        float other = __shfl_xor(v, 1);
        if((lane & 1) == 0){
          size_t ro = (size_t)(orow0 + rowb + r);
          outb[ro*4096 + (col>>1)] = f2b(geluf(v)*other);
        }
      }
    }
  }
}

// ---------------- flash attention: double-buffered K/V staging (T3 minimum pattern) ----
__global__ __launch_bounds__(256) void attn_k(const u16t* __restrict__ qb, const u16t* __restrict__ kswz,
                                              const u16t* __restrict__ vtswz, u16t* __restrict__ attnb){
  __shared__ __align__(16) u16t Ks[2*64*128];   // [buf][key][h ^ swz(key)]
  __shared__ __align__(16) u16t Vt[2*128*64];   // [buf][d][key-granule ^ ((d&7)<<3)]
  __shared__ __align__(16) u16t Ps[4*16*72];
  int bid = blockIdx.x;
  int qt = bid & 31, n = (bid>>5)&7, b = bid>>8;
  int tid = threadIdx.x, lane = tid&63, w = tid>>6, l15 = lane&15, lg = lane>>4;
  int q0 = qt*64 + w*16;

  s8b qf[4];
  const u16t* qrow = qb + ((size_t)(b*2048 + q0 + l15)*8 + n)*128;
  #pragma unroll
  for(int kc=0;kc<4;kc++) qf[kc] = *(const s8b*)(qrow + kc*32 + lg*8);

  float lsum[4];
  f4 oacc[8];
  #pragma unroll
  for(int r=0;r<4;r++) lsum[r] = 0.0f;
  #pragma unroll
  for(int db=0;db<8;db++){ f4 z = {0.0f,0.0f,0.0f,0.0f}; oacc[db]=z; }

  const u16t* kbase  = kswz  + (size_t)b*2048*128;
  const u16t* vtbase = vtswz + (size_t)b*128*2048;
  u16t* psw = Ps + w*1152;

  auto stage = [&](int buf, int st){
    const u16t* kt  = kbase  + (size_t)st*64*128;
    const u16t* vtb = vtbase + st*64;
    u16t* kd = Ks + buf*8192;
    u16t* vd = Vt + buf*8192;
    #pragma unroll
    for(int it=0; it<4; ++it){
      int e = it*2048 + tid*8;
      __builtin_amdgcn_global_load_lds((const AS1 u32t*)(kt + e), (AS3 u32t*)&kd[e], 16,0,0);
    }
    #pragma unroll
    for(int it=0; it<4; ++it){
      int e = it*2048 + tid*8;
      int d = e >> 6, ko = e & 63;
      __builtin_amdgcn_global_load_lds((const AS1 u32t*)(vtb + (size_t)d*2048 + ko), (AS3 u32t*)&vd[e], 16,0,0);
    }
  };

  stage(0, 0);
  __syncthreads();
  int cur = 0;
  for(int st=0; st<32; ++st){
    if(st < 31) stage(cur^1, st+1);   // in flight during compute; drained by end barrier
    const u16t* ks = Ks + cur*8192;
    const u16t* vs = Vt + cur*8192;

    // ---- QK^T ----
    f4 sf[4];
    #pragma unroll
    for(int kb=0;kb<4;kb++){ f4 z = {0.0f,0.0f,0.0f,0.0f}; sf[kb]=z; }
    #pragma unroll
    for(int kb=0;kb<4;kb++){
      int key = kb*16 + l15;
      int swz = ((key&7)<<3) ^ (((key>>3)&3)<<4);
      #pragma unroll
      for(int kc=0;kc<4;kc++){
        s8b kf = *(const s8b*)&ks[key*128 + ((kc*32 + lg*8) ^ swz)];
        sf[kb] = __builtin_amdgcn_mfma_f32_16x16x32_bf16(qf[kc], kf, sf[kb], 0,0,0);
      }
    }
    // ---- softcap + exp (static-max softmax), per-lane lsum ----
    #pragma unroll
    for(int r=0;r<4;r++){
      int prow = lg*4 + r;
      #pragma unroll
      for(int kb=0;kb<4;kb++){
        float pv = __expf(softcapf(sf[kb][r]));
        lsum[r] += pv;
        psw[prow*72 + kb*16 + l15] = f2b(pv);
      }
    }
    // ---- PV ----
    #pragma unroll
    for(int kc2=0;kc2<2;kc2++){
      s8b pa = *(const s8b*)&psw[l15*72 + kc2*32 + lg*8];
      int koff = (kc2*32 + lg*8) ^ ((l15&7)<<3);
      #pragma unroll
      for(int db=0;db<8;db++){
        s8b vf = *(const s8b*)&vs[(db*16 + l15)*64 + koff];
        oacc[db] = __builtin_amdgcn_mfma_f32_16x16x32_bf16(pa, vf, oacc[db], 0,0,0);
      }
    }
    __syncthreads();
    cur ^= 1;
  }

  float linv[4];
  #pragma unroll
  for(int r=0;r<4;r++){
    float s = lsum[r];
    #pragma unroll
    for(int off=1; off<16; off<<=1) s += __shfl_xor(s, off);
    linv[r] = 1.0f / s;
  }

  #pragma unroll
  for(int db=0;db<8;db++){
    #pragma unroll
    for(int r=0;r<4;r++){
      int qrowi = q0 + lg*4 + r;
      int d = db*16 + l15;
      attnb[(size_t)(b*2048 + qrowi)*1024 + n*128 + d] = f2b(oacc[db][r] * linv[r]);
    }
  }
}

// ---------------- host launch ----------------
extern "C" void kernel_launch(void* const* d_in, const int* in_sizes, int n_in,
                              void* d_out, int out_size, void* d_ws, size_t ws_size,
                              hipStream_t stream){
  const float* x        = (const float*)d_in[0];
  const float* pre_attn = (const float*)d_in[4];
  const float* pre_ffw  = (const float*)d_in[5];
  const float* g_qw  = (const float*)d_in[6];
  const float* g_kvw = (const float*)d_in[7];
  const float* g_ow  = (const float*)d_in[8];
  const float* a_qw  = (const float*)d_in[9];
  const float* a_kvw = (const float*)d_in[10];
  const float* a_ow  = (const float*)d_in[11];
  const float* g_gate= (const float*)d_in[12];
  const float* g_lin = (const float*)d_in[13];
  const float* a_gate= (const float*)d_in[14];
  const float* a_lin = (const float*)d_in[15];
  float* out = (float*)d_out;
  (void)in_sizes; (void)n_in; (void)out_size; (void)ws_size;

  char* wsp = (char*)d_ws; size_t off = 0;
  auto alloc = [&](size_t b){ void* p = wsp + off; off += (b + 255) & ~(size_t)255; return p; };
  u16t* wqkv_g = (u16t*)alloc((size_t)1280*1024*2);
  u16t* wqkv_a = (u16t*)alloc((size_t)1280*1024*2);
  u16t* wo_g   = (u16t*)alloc((size_t)1024*1024*2);
  u16t* wo_a   = (u16t*)alloc((size_t)1024*1024*2);
  u16t* wg_g   = (u16t*)alloc((size_t)8192*1024*2);
  u16t* wg_a   = (u16t*)alloc((size_t)4096*1024*2);
  u16t* wl_g   = (u16t*)alloc((size_t)1024*4096*2);
  u16t* wl_a   = (u16t*)alloc((size_t)1024*2048*2);
  u16t* xn     = (u16t*)alloc((size_t)8192*1024*2);
  u16t* xn2    = xn;
  char* big    = (char*)alloc((size_t)7168*4096*2);
  float* qkv   = (float*)big;
  float* t1    = (float*)big;
  u16t* hid_g  = (u16t*)big;
  u16t* qb     = (u16t*)alloc((size_t)8192*1024*2);
  u16t* kswz   = (u16t*)alloc((size_t)4*2048*128*2);
  u16t* vrow   = (u16t*)alloc((size_t)4*2048*128*2);
  u16t* vtswz  = (u16t*)alloc((size_t)4*128*2048*2);
  u16t* attnb  = (u16t*)alloc((size_t)8192*1024*2);
  u16t* hid_a  = (u16t*)alloc((size_t)1024*2048*2);

  tpack_k<<<dim3(4,32,8),256,0,stream>>>(wqkv_g, g_qw, 128, 1024, 1, 0, 128, 131072);
  tpack_k<<<dim3(4,32,1),256,0,stream>>>(wqkv_g, g_kvw, 128, 1024, 1, 1024, 0, 0);
  tpack_k<<<dim3(4,32,1),256,0,stream>>>(wqkv_g, g_kvw + 131072, 128, 1024, 1, 1152, 0, 0);
  tpack_k<<<dim3(4,32,8),256,0,stream>>>(wqkv_a, a_qw, 128, 1024, 1, 0, 128, 131072);
  tpack_k<<<dim3(4,32,1),256,0,stream>>>(wqkv_a, a_kvw, 128, 1024, 1, 1024, 0, 0);
  tpack_k<<<dim3(4,32,1),256,0,stream>>>(wqkv_a, a_kvw + 131072, 128, 1024, 1, 1152, 0, 0);
  tpack_k<<<dim3(32,32,1),256,0,stream>>>(wo_g, g_ow, 1024, 1024, 1, 0, 0, 0);
  tpack_k<<<dim3(32,32,1),256,0,stream>>>(wo_a, a_ow, 1024, 1024, 1, 0, 0, 0);
  tpack_k<<<dim3(128,32,2),256,0,stream>>>(wg_g, g_gate, 4096, 1024, 2, 0, 1, (size_t)1024*4096);
  tpack_k<<<dim3(64,32,2),256,0,stream>>>(wg_a, a_gate, 2048, 1024, 2, 0, 1, (size_t)1024*2048);
  tpack_k<<<dim3(32,128,1),256,0,stream>>>(wl_g, g_lin, 1024, 4096, 1, 0, 0, 0);
  tpack_k<<<dim3(32,64,1),256,0,stream>>>(wl_a, a_lin, 1024, 2048, 1, 0, 0, 0);

  rmsnorm_k<<<8192,256,0,stream>>>(x, pre_attn, xn);

  { GemmArgs ga = {xn, 1024, wqkv_g, wqkv_a, 1024, 10, 0,0,0, 0, qkv, nullptr, 1280, nullptr};
    gemm_k<<<64*10,256,0,stream>>>(ga); }
  rope_k<<<8192,256,0,stream>>>(qkv, qb, kswz, vrow);
  vt_pack_k<<<128,256,0,stream>>>(vrow, vtswz);
  attn_k<<<1024,256,0,stream>>>(qb, kswz, vtswz, attnb);
  { GemmArgs ga = {attnb, 1024, wo_g, wo_a, 1024, 8, 0,0,0, 1, t1, nullptr, 1024, x};
    gemm_k<<<64*8,256,0,stream>>>(ga); }
  rmsnorm_k<<<8192,256,0,stream>>>(t1, pre_ffw, xn2);
  gemm256_k<<<896,512,0,stream>>>(xn2, wg_g, hid_g);
  { GemmArgs ga = {xn2, 1024, wg_a, nullptr, 1024, 32, 2,1,0, 3, nullptr, hid_a, 2048, nullptr};
    gemm_k<<<8*32,256,0,stream>>>(ga); }
  { GemmArgs ga = {hid_g, 4096, wl_g, nullptr, 4096, 8, 1,0,1, 1, out, nullptr, 1024, x};
    gemm_k<<<56*8,256,0,stream>>>(ga); }
  { GemmArgs ga = {hid_a, 2048, wl_a, nullptr, 2048, 8, 2,0,1, 1, out, nullptr, 1024, x};
    gemm_k<<<8*8,256,0,stream>>>(ga); }
}

// Round 10
// 780.800 us; speedup vs baseline: 1.5180x; 1.0415x over previous
//
#include <hip/hip_runtime.h>
#include <hip/hip_bf16.h>
#include <stdint.h>

typedef short s8b __attribute__((ext_vector_type(8)));
typedef float f4 __attribute__((ext_vector_type(4)));
typedef unsigned short u16t;
typedef unsigned int u32t;

#define AS1 __attribute__((address_space(1)))
#define AS3 __attribute__((address_space(3)))
#define DEVFN static __device__ __forceinline__

DEVFN u16t f2b(float f){ union{ __hip_bfloat16 h; u16t u; } c; c.h = __float2bfloat16(f); return c.u; }

// gelu(x) = 0.5x(1+tanh(u)), u = sqrt(2/pi)(x+0.044715x^3); tanh via exp2+rcp, self-saturating.
DEVFN float geluf(float x){
  float u = x*(0.7978845608028654f + 0.03567740813636141f*x*x);
  float e = __builtin_amdgcn_exp2f(u*2.8853900817779268f);   // exp(2u)
  float th = 1.0f - 2.0f*__builtin_amdgcn_rcpf(e + 1.0f);
  return 0.5f*x*(1.0f + th);
}
// exp(50*tanh(0.02*s)) fused: no clamps (IEEE inf/0 give the softcap limits).
DEVFN float softexpf(float s){
  float e = __builtin_amdgcn_exp2f(s*0.05770780163555853f);  // exp(0.04*s)
  float th = 1.0f - 2.0f*__builtin_amdgcn_rcpf(e + 1.0f);
  return __builtin_amdgcn_exp2f(th*72.13475204444817f);      // exp(50*th)
}

// ---------------- generic LDS-tiled transpose-pack (fp32 -> bf16) ----------------
__global__ __launch_bounds__(256) void tpack_k(u16t* __restrict__ dst, const float* __restrict__ src,
                                               int ldsrc, int lddst, int rmul, int roff, int prow,
                                               size_t pstride){
  __shared__ float tile[32][33];
  int z = blockIdx.z;
  const float* s = src + (size_t)z*pstride;
  int f0 = blockIdx.x*32, d0 = blockIdx.y*32;
  int t = threadIdx.x, r = t>>5, c = t&31;
  #pragma unroll
  for(int i=0;i<4;i++)
    tile[r + i*8][c] = s[(size_t)(d0 + r + i*8)*ldsrc + f0 + c];
  __syncthreads();
  int rbase = roff + z*prow;
  #pragma unroll
  for(int i=0;i<4;i++){
    int f = f0 + r + i*8;
    dst[(size_t)(f*rmul + rbase)*lddst + d0 + c] = f2b(tile[c][r + i*8]);
  }
}

// ---------------- RMSNorm (one block per row of 1024) ----------------
__global__ __launch_bounds__(256) void rmsnorm_k(const float* __restrict__ x, const float* __restrict__ sc,
                                                 u16t* __restrict__ out){
  int row = blockIdx.x;
  int tid = threadIdx.x;
  const float* xr = x + (size_t)row*1024;
  float4 v = *(const float4*)(xr + tid*4);
  float s = v.x*v.x + v.y*v.y + v.z*v.z + v.w*v.w;
  #pragma unroll
  for(int off=32; off>=1; off>>=1) s += __shfl_down(s, off);
  __shared__ float ws4[4];
  if((tid & 63) == 0) ws4[tid>>6] = s;
  __syncthreads();
  float tot = ws4[0]+ws4[1]+ws4[2]+ws4[3];
  float r = rsqrtf(tot*(1.0f/1024.0f) + 1e-6f);
  float4 scv = *(const float4*)(sc + tid*4);
  u16t o0 = f2b(v.x*r*(1.0f+scv.x)), o1 = f2b(v.y*r*(1.0f+scv.y));
  u16t o2 = f2b(v.z*r*(1.0f+scv.z)), o3 = f2b(v.w*r*(1.0f+scv.w));
  uint2 pk; pk.x = (u32t)o0 | ((u32t)o1<<16); pk.y = (u32t)o2 | ((u32t)o3<<16);
  *(uint2*)(out + (size_t)row*1024 + tid*4) = pk;
}

// ---------------- RoPE + convert; K stored pre-swizzled, V row-major ----------------
__global__ __launch_bounds__(256) void rope_k(const float* __restrict__ qkv, u16t* __restrict__ qb,
                                              u16t* __restrict__ kswz, u16t* __restrict__ vrow){
  int row = blockIdx.x;
  int b = row >> 11, t = row & 2047;
  float pos = (float)(t + (t >= 1792 ? 1 : 0));
  const float* src = qkv + (size_t)row*1280;
  size_t kvbase = ((size_t)b*2048 + t)*128;
  int swz = ((t&7)<<3) ^ (((t>>3)&3)<<4);
  for(int idx = threadIdx.x; idx < 704; idx += 256){
    if(idx < 512){
      int n = idx >> 6, i = idx & 63;
      float inv = exp2f((float)i * -0.20762050593046f); // 10000^{-i/64}
      float sn, cs; sincosf(pos*inv, &sn, &cs);
      float x1 = src[n*128+i], x2 = src[n*128+i+64];
      const float qs = 0.08838834764831845f; // 1/sqrt(128)
      qb[(size_t)row*1024 + n*128 + i]      = f2b((x1*cs - x2*sn)*qs);
      qb[(size_t)row*1024 + n*128 + i + 64] = f2b((x2*cs + x1*sn)*qs);
    } else if(idx < 576){
      int i = idx - 512;
      float inv = exp2f((float)i * -0.20762050593046f);
      float sn, cs; sincosf(pos*inv, &sn, &cs);
      float x1 = src[1024+i], x2 = src[1024+i+64];
      kswz[kvbase + (i ^ swz)]        = f2b(x1*cs - x2*sn);
      kswz[kvbase + ((i+64) ^ swz)]   = f2b(x2*cs + x1*sn);
    } else {
      int h = idx - 576;
      vrow[kvbase + h] = f2b(src[1152+h]);
    }
  }
}

// ---------------- V transpose pack: vrow[b][t][h] -> vtswz[b][d][key ^ ((d&7)<<3)] ----
__global__ __launch_bounds__(256) void vt_pack_k(const u16t* __restrict__ vrow, u16t* __restrict__ vtswz){
  int blk = blockIdx.x;            // b*32 + kt
  int b = blk >> 5, kt = blk & 31;
  int tid = threadIdx.x;
  const u16t* src = vrow + ((size_t)b*2048 + kt*64)*128;
  #pragma unroll
  for(int it=0; it<4; ++it){
    int o = it*2048 + tid*8;
    int d = o >> 6, kg = o & 63;   // kg is a multiple of 8
    u16t tmp[8];
    #pragma unroll
    for(int j=0;j<8;j++) tmp[j] = src[(size_t)(kg+j)*128 + d];
    *(uint4*)&vtswz[((size_t)b*128 + d)*2048 + kt*64 + (kg ^ ((d&7)<<3))] = *(const uint4*)tmp;
  }
}

// ---------------- generic bf16 MFMA GEMM, 128x128 tile, BK=32, 4 waves ----------------
struct GemmArgs {
  const u16t* A; int lda;
  const u16t* Bg; const u16t* Ba;
  int K; int ntN; int mode; int amap; int omap; int ep;
  float* outf; u16t* outb; int ldo;
  const float* res;
};

__global__ __launch_bounds__(256) void gemm_k(GemmArgs g){
  __shared__ __align__(16) u16t As[2*128*32];
  __shared__ __align__(16) u16t Bs[2*128*32];
  int bid = blockIdx.x;
  int mt = bid / g.ntN, nt = bid % g.ntN;
  int c0 = mt*128, g0;
  const u16t* B;
  if(g.mode == 0){
    g0 = c0;
    B = ((mt & 15) < 14) ? g.Bg : g.Ba;   // t<1792 -> g weights
  } else if(g.mode == 1){                  // g-half compact rows: 14 tiles per batch
    int bb = mt/14, t = (mt - bb*14)*128;
    g0 = bb*2048 + t; B = g.Bg;
  } else {                                 // a-half compact rows: 2 tiles per batch
    int bb = mt>>1, t = 1792 + (mt&1)*128;
    g0 = bb*2048 + t; B = g.Bg;
  }
  int arow = g.amap ? g0 : c0;
  int orow = g.omap ? g0 : c0;
  int tid = threadIdx.x, lane = tid & 63, w = tid >> 6, l15 = lane & 15, lg = lane >> 4;
  int wr = w >> 1, wc = w & 1;

  int gsrc = ((tid&3) ^ ((tid>>3)&3))*8;
  const u16t* Ap = g.A + (size_t)(arow + (tid>>2))*g.lda + gsrc;
  const u16t* Bp = B   + (size_t)(nt*128 + (tid>>2))*g.K + gsrc;
  size_t lda64 = (size_t)64*g.lda, ldb64 = (size_t)64*g.K;
  u32t le = tid*8;

  int xr = (lg ^ ((l15>>1)&3))*8;
  int aoff[4], boff[4];
  #pragma unroll
  for(int mi=0;mi<4;mi++) aoff[mi] = (wr*64 + mi*16 + l15)*32 + xr;
  #pragma unroll
  for(int ni=0;ni<4;ni++) boff[ni] = (wc*64 + ni*16 + l15)*32 + xr;

  f4 acc[4][4];
  #pragma unroll
  for(int mi=0;mi<4;mi++)
    #pragma unroll
    for(int ni=0;ni<4;ni++){ f4 z = {0.0f,0.0f,0.0f,0.0f}; acc[mi][ni]=z; }

  auto stagef = [&](int buf, int k0){
    u16t* a = As + buf*4096;
    u16t* b = Bs + buf*4096;
    __builtin_amdgcn_global_load_lds((const AS1 u32t*)(Ap + k0),          (AS3 u32t*)&a[le],        16,0,0);
    __builtin_amdgcn_global_load_lds((const AS1 u32t*)(Ap + k0 + lda64),  (AS3 u32t*)&a[le + 2048], 16,0,0);
    __builtin_amdgcn_global_load_lds((const AS1 u32t*)(Bp + k0),          (AS3 u32t*)&b[le],        16,0,0);
    __builtin_amdgcn_global_load_lds((const AS1 u32t*)(Bp + k0 + ldb64),  (AS3 u32t*)&b[le + 2048], 16,0,0);
  };

  stagef(0, 0);
  __syncthreads();
  int cur = 0;
  for(int k0=0; k0 < g.K; k0 += 32){
    if(k0 + 32 < g.K) stagef(cur^1, k0+32);
    const u16t* as = As + cur*4096;
    const u16t* bs = Bs + cur*4096;
    s8b af[4], bf[4];
    #pragma unroll
    for(int mi=0;mi<4;mi++) af[mi] = *(const s8b*)&as[aoff[mi]];
    #pragma unroll
    for(int ni=0;ni<4;ni++) bf[ni] = *(const s8b*)&bs[boff[ni]];
    #pragma unroll
    for(int mi=0;mi<4;mi++)
      #pragma unroll
      for(int ni=0;ni<4;ni++)
        acc[mi][ni] = __builtin_amdgcn_mfma_f32_16x16x32_bf16(af[mi], bf[ni], acc[mi][ni], 0,0,0);
    __syncthreads();
    cur ^= 1;
  }

  #pragma unroll
  for(int mi=0;mi<4;mi++){
    #pragma unroll
    for(int ni=0;ni<4;ni++){
      int rowb = wr*64 + mi*16 + lg*4;
      int col = nt*128 + wc*64 + ni*16 + l15;
      #pragma unroll
      for(int r=0;r<4;r++){
        float v = acc[mi][ni][r];
        size_t ro = (size_t)(orow + rowb + r);
        if(g.ep == 0){
          g.outf[ro*(size_t)g.ldo + col] = v;
        } else if(g.ep == 1){
          g.outf[ro*(size_t)g.ldo + col] = v + g.res[ro*1024 + col];
        } else {
          float other = __shfl_xor(v, 1);
          if((lane & 1) == 0){
            g.outb[ro*(size_t)g.ldo + (col>>1)] = f2b(geluf(v)*other);
          }
        }
      }
    }
  }
}

// ---------------- 256x256 8-phase GEMM (T2+T3+T4+T5): gate-g (896 blocks) + gate-a (64) --
__global__ __launch_bounds__(512, 2) void gemm256_k(const u16t* __restrict__ A,
                                                    const u16t* __restrict__ Bg,
                                                    const u16t* __restrict__ Ba,
                                                    u16t* __restrict__ outg,
                                                    u16t* __restrict__ outa){
  __shared__ __align__(16) u16t LDS[65536];   // A: slot*16384 ; B: 32768 + slot*16384
  int bid = blockIdx.x;
  int mt, nt, g0, orow0, ldo;
  const u16t* Bw; u16t* outb;
  if(bid < 896){
    int j = bid >> 3;
    nt = (bid & 7)*4 + (j & 3);               // XCD-owned B column group
    mt = j >> 2;                              // 28 x 32 tiles
    int bb = mt / 7;
    g0 = bb*2048 + (mt - bb*7)*256;
    orow0 = mt*256; Bw = Bg; outb = outg; ldo = 4096;
  } else {                                    // gate-a: 4 mt (1/batch) x 16 nt
    int idx = bid - 896;
    mt = idx >> 4; nt = idx & 15;
    g0 = mt*2048 + 1792;
    orow0 = mt*256; Bw = Ba; outb = outa; ldo = 2048;
  }
  int tid = threadIdx.x, lane = tid & 63, w = tid >> 6, l15 = lane & 15, lg = lane >> 4;
  int wr = w >> 2, wc = w & 3;

  int cg = ((tid&7) ^ ((tid>>3)&7))*8;
  const u16t* aSrc = A  + (size_t)(g0 + (tid>>3))*1024 + cg;
  const u16t* bSrc = Bw + (size_t)(nt*256 + (tid>>3))*1024 + cg;
  u16t* ldsA = &LDS[w*512 + (lane&63)*8];
  u16t* ldsB = &LDS[32768 + w*512 + (lane&63)*8];

  auto STAGE_A = [&](int kt, int uh){
    if(kt >= 16) return;
    const u16t* s0 = aSrc + (size_t)(uh*128)*1024 + kt*64;
    u16t* d = ldsA + (kt&1)*16384 + uh*8192;
    __builtin_amdgcn_global_load_lds((const AS1 u32t*)s0,            (AS3 u32t*)d,          16,0,0);
    __builtin_amdgcn_global_load_lds((const AS1 u32t*)(s0 + 65536),  (AS3 u32t*)(d + 4096), 16,0,0);
  };
  auto STAGE_B = [&](int kt, int uh){
    if(kt >= 16) return;
    const u16t* s0 = bSrc + (size_t)(uh*128)*1024 + kt*64;
    u16t* d = ldsB + (kt&1)*16384 + uh*8192;
    __builtin_amdgcn_global_load_lds((const AS1 u32t*)s0,            (AS3 u32t*)d,          16,0,0);
    __builtin_amdgcn_global_load_lds((const AS1 u32t*)(s0 + 65536),  (AS3 u32t*)(d + 4096), 16,0,0);
  };

  int px0 = ((lg)     ^ (l15&7))*8;
  int px1 = ((4 + lg) ^ (l15&7))*8;
  int aRow = (wr*128 + l15)*64;
  int bRow = (wc*64  + l15)*64;

  f4 acc[8][4];
  #pragma unroll
  for(int m=0;m<8;m++)
    #pragma unroll
    for(int n=0;n<4;n++){ f4 z = {0.0f,0.0f,0.0f,0.0f}; acc[m][n]=z; }
  s8b afr[4][2], bfr[4][2];

  auto READ_A = [&](int s, int mh){
    const u16t* base = &LDS[s*16384 + aRow + mh*4096];
    #pragma unroll
    for(int m=0;m<4;m++){
      afr[m][0] = *(const s8b*)(base + m*1024 + px0);
      afr[m][1] = *(const s8b*)(base + m*1024 + px1);
    }
  };
  auto READ_B = [&](int s, int nh){
    const u16t* base = &LDS[32768 + s*16384 + bRow + nh*2048];
    #pragma unroll
    for(int n=0;n<2;n++){
      bfr[nh*2+n][0] = *(const s8b*)(base + n*1024 + px0);
      bfr[nh*2+n][1] = *(const s8b*)(base + n*1024 + px1);
    }
  };

  #define MFMAQ(mh, nh)                                                              \
    __builtin_amdgcn_s_barrier();                                                    \
    asm volatile("s_waitcnt lgkmcnt(0)" ::: "memory");                               \
    __builtin_amdgcn_sched_barrier(0);                                               \
    __builtin_amdgcn_s_setprio(1);                                                   \
    _Pragma("unroll")                                                                \
    for(int m=0;m<4;m++)                                                             \
      _Pragma("unroll")                                                              \
      for(int n=0;n<2;n++)                                                           \
        _Pragma("unroll")                                                            \
        for(int kk=0;kk<2;kk++)                                                      \
          acc[(mh)*4+m][(nh)*2+n] = __builtin_amdgcn_mfma_f32_16x16x32_bf16(         \
              afr[m][kk], bfr[(nh)*2+n][kk], acc[(mh)*4+m][(nh)*2+n], 0,0,0);        \
    __builtin_amdgcn_s_setprio(0);                                                   \
    __builtin_amdgcn_sched_barrier(0);

  STAGE_A(0,0); STAGE_A(0,1); STAGE_B(0,0); STAGE_B(0,1);
  STAGE_A(1,0); STAGE_A(1,1);
  asm volatile("s_waitcnt vmcnt(4)" ::: "memory");
  __builtin_amdgcn_s_barrier();

  for(int it2=0; it2<8; ++it2){
    int t = it2*2;
    READ_B(0,0); READ_A(0,0); STAGE_B(t+1, 0);
    MFMAQ(0,0)
    __builtin_amdgcn_s_barrier();
    READ_B(0,1); STAGE_B(t+1, 1);
    MFMAQ(0,1)
    __builtin_amdgcn_s_barrier();
    READ_A(0,1); STAGE_A(t+2, 0);
    MFMAQ(1,0)
    __builtin_amdgcn_s_barrier();
    STAGE_A(t+2, 1);
    MFMAQ(1,1)
    if(it2==7) asm volatile("s_waitcnt vmcnt(0)" ::: "memory");
    else       asm volatile("s_waitcnt vmcnt(4)" ::: "memory");
    __builtin_amdgcn_s_barrier();
    READ_B(1,0); READ_A(1,0); STAGE_B(t+2, 0);
    MFMAQ(0,0)
    __builtin_amdgcn_s_barrier();
    READ_B(1,1); STAGE_B(t+2, 1);
    MFMAQ(0,1)
    __builtin_amdgcn_s_barrier();
    READ_A(1,1); STAGE_A(t+3, 0);
    MFMAQ(1,0)
    __builtin_amdgcn_s_barrier();
    STAGE_A(t+3, 1);
    MFMAQ(1,1)
    if(it2==7) asm volatile("s_waitcnt vmcnt(0)" ::: "memory");
    else       asm volatile("s_waitcnt vmcnt(4)" ::: "memory");
    __builtin_amdgcn_s_barrier();
  }
  #undef MFMAQ

  #pragma unroll
  for(int mg=0;mg<8;mg++){
    #pragma unroll
    for(int n=0;n<4;n++){
      int rowb = wr*128 + mg*16 + lg*4;
      int col = nt*256 + wc*64 + n*16 + l15;
      #pragma unroll
      for(int r=0;r<4;r++){
        float v = acc[mg][n][r];
        float other = __shfl_xor(v, 1);
        if((lane & 1) == 0){
          size_t ro = (size_t)(orow0 + rowb + r);
          outb[ro*(size_t)ldo + (col>>1)] = f2b(geluf(v)*other);
        }
      }
    }
  }
}

// ---------------- flash attention: double-buffered K/V staging, fused softcap-exp ----
__global__ __launch_bounds__(256) void attn_k(const u16t* __restrict__ qb, const u16t* __restrict__ kswz,
                                              const u16t* __restrict__ vtswz, u16t* __restrict__ attnb){
  __shared__ __align__(16) u16t Ks[2*64*128];   // [buf][key][h ^ swz(key)]
  __shared__ __align__(16) u16t Vt[2*128*64];   // [buf][d][key-granule ^ ((d&7)<<3)]
  __shared__ __align__(16) u16t Ps[4*16*72];
  int bid = blockIdx.x;
  int qt = bid & 31, n = (bid>>5)&7, b = bid>>8;
  int tid = threadIdx.x, lane = tid&63, w = tid>>6, l15 = lane&15, lg = lane>>4;
  int q0 = qt*64 + w*16;

  s8b qf[4];
  const u16t* qrow = qb + ((size_t)(b*2048 + q0 + l15)*8 + n)*128;
  #pragma unroll
  for(int kc=0;kc<4;kc++) qf[kc] = *(const s8b*)(qrow + kc*32 + lg*8);

  float lsum[4];
  f4 oacc[8];
  #pragma unroll
  for(int r=0;r<4;r++) lsum[r] = 0.0f;
  #pragma unroll
  for(int db=0;db<8;db++){ f4 z = {0.0f,0.0f,0.0f,0.0f}; oacc[db]=z; }

  const u16t* kbase  = kswz  + (size_t)b*2048*128;
  const u16t* vtbase = vtswz + (size_t)b*128*2048;
  u16t* psw = Ps + w*1152;

  auto stage = [&](int buf, int st){
    const u16t* kt  = kbase  + (size_t)st*64*128;
    const u16t* vtb = vtbase + st*64;
    u16t* kd = Ks + buf*8192;
    u16t* vd = Vt + buf*8192;
    #pragma unroll
    for(int it=0; it<4; ++it){
      int e = it*2048 + tid*8;
      __builtin_amdgcn_global_load_lds((const AS1 u32t*)(kt + e), (AS3 u32t*)&kd[e], 16,0,0);
    }
    #pragma unroll
    for(int it=0; it<4; ++it){
      int e = it*2048 + tid*8;
      int d = e >> 6, ko = e & 63;
      __builtin_amdgcn_global_load_lds((const AS1 u32t*)(vtb + (size_t)d*2048 + ko), (AS3 u32t*)&vd[e], 16,0,0);
    }
  };

  stage(0, 0);
  __syncthreads();
  int cur = 0;
  for(int st=0; st<32; ++st){
    if(st < 31) stage(cur^1, st+1);
    const u16t* ks = Ks + cur*8192;
    const u16t* vs = Vt + cur*8192;

    // ---- QK^T ----
    f4 sf[4];
    #pragma unroll
    for(int kb=0;kb<4;kb++){ f4 z = {0.0f,0.0f,0.0f,0.0f}; sf[kb]=z; }
    #pragma unroll
    for(int kb=0;kb<4;kb++){
      int key = kb*16 + l15;
      int swz = ((key&7)<<3) ^ (((key>>3)&3)<<4);
      #pragma unroll
      for(int kc=0;kc<4;kc++){
        s8b kf = *(const s8b*)&ks[key*128 + ((kc*32 + lg*8) ^ swz)];
        sf[kb] = __builtin_amdgcn_mfma_f32_16x16x32_bf16(qf[kc], kf, sf[kb], 0,0,0);
      }
    }
    // ---- fused softcap-exp (static-max softmax), per-lane lsum ----
    #pragma unroll
    for(int r=0;r<4;r++){
      int prow = lg*4 + r;
      #pragma unroll
      for(int kb=0;kb<4;kb++){
        float pv = softexpf(sf[kb][r]);
        lsum[r] += pv;
        psw[prow*72 + kb*16 + l15] = f2b(pv);
      }
    }
    // ---- PV ----
    #pragma unroll
    for(int kc2=0;kc2<2;kc2++){
      s8b pa = *(const s8b*)&psw[l15*72 + kc2*32 + lg*8];
      int koff = (kc2*32 + lg*8) ^ ((l15&7)<<3);
      #pragma unroll
      for(int db=0;db<8;db++){
        s8b vf = *(const s8b*)&vs[(db*16 + l15)*64 + koff];
        oacc[db] = __builtin_amdgcn_mfma_f32_16x16x32_bf16(pa, vf, oacc[db], 0,0,0);
      }
    }
    __syncthreads();
    cur ^= 1;
  }

  float linv[4];
  #pragma unroll
  for(int r=0;r<4;r++){
    float s = lsum[r];
    #pragma unroll
    for(int off=1; off<16; off<<=1) s += __shfl_xor(s, off);
    linv[r] = 1.0f / s;
  }

  #pragma unroll
  for(int db=0;db<8;db++){
    #pragma unroll
    for(int r=0;r<4;r++){
      int qrowi = q0 + lg*4 + r;
      int d = db*16 + l15;
      attnb[(size_t)(b*2048 + qrowi)*1024 + n*128 + d] = f2b(oacc[db][r] * linv[r]);
    }
  }
}

// ---------------- host launch ----------------
extern "C" void kernel_launch(void* const* d_in, const int* in_sizes, int n_in,
                              void* d_out, int out_size, void* d_ws, size_t ws_size,
                              hipStream_t stream){
  const float* x        = (const float*)d_in[0];
  const float* pre_attn = (const float*)d_in[4];
  const float* pre_ffw  = (const float*)d_in[5];
  const float* g_qw  = (const float*)d_in[6];
  const float* g_kvw = (const float*)d_in[7];
  const float* g_ow  = (const float*)d_in[8];
  const float* a_qw  = (const float*)d_in[9];
  const float* a_kvw = (const float*)d_in[10];
  const float* a_ow  = (const float*)d_in[11];
  const float* g_gate= (const float*)d_in[12];
  const float* g_lin = (const float*)d_in[13];
  const float* a_gate= (const float*)d_in[14];
  const float* a_lin = (const float*)d_in[15];
  float* out = (float*)d_out;
  (void)in_sizes; (void)n_in; (void)out_size; (void)ws_size;

  char* wsp = (char*)d_ws; size_t off = 0;
  auto alloc = [&](size_t b){ void* p = wsp + off; off += (b + 255) & ~(size_t)255; return p; };
  u16t* wqkv_g = (u16t*)alloc((size_t)1280*1024*2);
  u16t* wqkv_a = (u16t*)alloc((size_t)1280*1024*2);
  u16t* wo_g   = (u16t*)alloc((size_t)1024*1024*2);
  u16t* wo_a   = (u16t*)alloc((size_t)1024*1024*2);
  u16t* wg_g   = (u16t*)alloc((size_t)8192*1024*2);
  u16t* wg_a   = (u16t*)alloc((size_t)4096*1024*2);
  u16t* wl_g   = (u16t*)alloc((size_t)1024*4096*2);
  u16t* wl_a   = (u16t*)alloc((size_t)1024*2048*2);
  u16t* xn     = (u16t*)alloc((size_t)8192*1024*2);
  u16t* xn2    = xn;
  char* big    = (char*)alloc((size_t)7168*4096*2);
  float* qkv   = (float*)big;
  float* t1    = (float*)big;
  u16t* hid_g  = (u16t*)big;
  u16t* qb     = (u16t*)alloc((size_t)8192*1024*2);
  u16t* kswz   = (u16t*)alloc((size_t)4*2048*128*2);
  u16t* vrow   = (u16t*)alloc((size_t)4*2048*128*2);
  u16t* vtswz  = (u16t*)alloc((size_t)4*128*2048*2);
  u16t* attnb  = (u16t*)alloc((size_t)8192*1024*2);
  u16t* hid_a  = (u16t*)alloc((size_t)1024*2048*2);

  tpack_k<<<dim3(4,32,8),256,0,stream>>>(wqkv_g, g_qw, 128, 1024, 1, 0, 128, 131072);
  tpack_k<<<dim3(4,32,1),256,0,stream>>>(wqkv_g, g_kvw, 128, 1024, 1, 1024, 0, 0);
  tpack_k<<<dim3(4,32,1),256,0,stream>>>(wqkv_g, g_kvw + 131072, 128, 1024, 1, 1152, 0, 0);
  tpack_k<<<dim3(4,32,8),256,0,stream>>>(wqkv_a, a_qw, 128, 1024, 1, 0, 128, 131072);
  tpack_k<<<dim3(4,32,1),256,0,stream>>>(wqkv_a, a_kvw, 128, 1024, 1, 1024, 0, 0);
  tpack_k<<<dim3(4,32,1),256,0,stream>>>(wqkv_a, a_kvw + 131072, 128, 1024, 1, 1152, 0, 0);
  tpack_k<<<dim3(32,32,1),256,0,stream>>>(wo_g, g_ow, 1024, 1024, 1, 0, 0, 0);
  tpack_k<<<dim3(32,32,1),256,0,stream>>>(wo_a, a_ow, 1024, 1024, 1, 0, 0, 0);
  tpack_k<<<dim3(128,32,2),256,0,stream>>>(wg_g, g_gate, 4096, 1024, 2, 0, 1, (size_t)1024*4096);
  tpack_k<<<dim3(64,32,2),256,0,stream>>>(wg_a, a_gate, 2048, 1024, 2, 0, 1, (size_t)1024*2048);
  tpack_k<<<dim3(32,128,1),256,0,stream>>>(wl_g, g_lin, 1024, 4096, 1, 0, 0, 0);
  tpack_k<<<dim3(32,64,1),256,0,stream>>>(wl_a, a_lin, 1024, 2048, 1, 0, 0, 0);

  rmsnorm_k<<<8192,256,0,stream>>>(x, pre_attn, xn);

  { GemmArgs ga = {xn, 1024, wqkv_g, wqkv_a, 1024, 10, 0,0,0, 0, qkv, nullptr, 1280, nullptr};
    gemm_k<<<64*10,256,0,stream>>>(ga); }
  rope_k<<<8192,256,0,stream>>>(qkv, qb, kswz, vrow);
  vt_pack_k<<<128,256,0,stream>>>(vrow, vtswz);
  attn_k<<<1024,256,0,stream>>>(qb, kswz, vtswz, attnb);
  { GemmArgs ga = {attnb, 1024, wo_g, wo_a, 1024, 8, 0,0,0, 1, t1, nullptr, 1024, x};
    gemm_k<<<64*8,256,0,stream>>>(ga); }
  rmsnorm_k<<<8192,256,0,stream>>>(t1, pre_ffw, xn2);
  // gate-g (896 blocks) + gate-a (64 blocks) fused
  gemm256_k<<<960,512,0,stream>>>(xn2, wg_g, wg_a, hid_g, hid_a);
  { GemmArgs ga = {hid_g, 4096, wl_g, nullptr, 4096, 8, 1,0,1, 1, out, nullptr, 1024, x};
    gemm_k<<<56*8,256,0,stream>>>(ga); }
  { GemmArgs ga = {hid_a, 2048, wl_a, nullptr, 2048, 8, 2,0,1, 1, out, nullptr, 1024, x};
    gemm_k<<<8*8,256,0,stream>>>(ga); }
}